// Round 13
// baseline (439.794 us; speedup 1.0000x reference)
//
#include <hip/hip_runtime.h>
#include <math.h>

#define Bb 2
#define Tt 2048
#define Cc 1024
#define Hh 16
#define BT 4096
#define FFNd 4096
#define CH 16
#define CL 128
#define WU 32
#define BIGN 3456
#define BIGK 2048
#define LORAK 320
#define BIGW 4096
// big-B column layout: r@0 k@1024 v@2048 w@3072 a@3136 vl@3200 g@3232 (end 3392, pad->3456)
// dwdavg column layout: dw@0 da@1024 dv@2048 g@3072  (ld 4096)

typedef __attribute__((ext_vector_type(8))) short bf16x8;
typedef __attribute__((ext_vector_type(4))) float f32x4;
typedef unsigned short u16;

__device__ __forceinline__ float sgm(float x){ return 1.0f/(1.0f+expf(-x)); }

template<int MAXM>
__device__ __forceinline__ float redgrp(float v){
  #pragma unroll
  for (int m=1; m<=MAXM; m<<=1) v += __shfl_xor(v, m, 64);
  return v;
}

template<int CTRL>
__device__ __forceinline__ float dppadd(float v){
  union { float f; int i; } u, r;
  u.f = v;
  r.i = __builtin_amdgcn_update_dpp(u.i, u.i, CTRL, 0xf, 0xf, true);
  return v + r.f;
}
__device__ __forceinline__ float red16(float v){
  v = dppadd<0xB1>(v);
  v = dppadd<0x4E>(v);
  v = dppadd<0x141>(v);
  v = dppadd<0x140>(v);
  return v;
}

__device__ __forceinline__ unsigned pack_bf16(float a, float b){
  unsigned ua = __builtin_bit_cast(unsigned, a);
  unsigned ub = __builtin_bit_cast(unsigned, b);
  ua = (ua + 0x7FFFu + ((ua>>16)&1u)) >> 16;
  ub = (ub + 0x7FFFu + ((ub>>16)&1u)) >> 16;
  return ua | (ub<<16);
}
__device__ __forceinline__ u16 bf16_1(float a){
  unsigned ua = __builtin_bit_cast(unsigned, a);
  return (u16)((ua + 0x7FFFu + ((ua>>16)&1u)) >> 16);
}

__device__ __forceinline__ void gload16(const void* g, void* l){
  __builtin_amdgcn_global_load_lds(
    (const __attribute__((address_space(1))) unsigned int*)g,
    (__attribute__((address_space(3))) unsigned int*)l, 16, 0, 0);
}

// ---------------- f32 -> bf16 convert (weights) -------------------------------
__global__ __launch_bounds__(256) void cvt_kernel(const float* __restrict__ in,
    u16* __restrict__ out) {
  size_t i = (size_t)blockIdx.x*256 + threadIdx.x;
  float4 a = ((const float4*)in)[2*i];
  float4 b = ((const float4*)in)[2*i+1];
  uint4 o = {pack_bf16(a.x,a.y), pack_bf16(a.z,a.w),
             pack_bf16(b.x,b.y), pack_bf16(b.z,b.w)};
  ((uint4*)out)[i] = o;
}

// ---------------- pack square weights into BigB rows: [W | diag(mix)W] -------
__global__ __launch_bounds__(256) void packW_kernel(const float* __restrict__ Wr,
    const float* __restrict__ Wk, const float* __restrict__ Wv,
    const float* __restrict__ xr, const float* __restrict__ xk,
    const float* __restrict__ xv, u16* __restrict__ out) {
  int which = blockIdx.y;
  const float* W   = which==0 ? Wr : (which==1 ? Wk : Wv);
  const float* mix = which==0 ? xr : (which==1 ? xk : xv);
  u16* o = out + (size_t)which*1024*BIGK;
  int n = blockIdx.x;             // 0..1023
  int c0 = threadIdx.x*8;         // 0..2040
  int ks = c0 & 1023;
  const float* src = W + (size_t)n*Cc + ks;
  float4 a = *(const float4*)src;
  float4 b = *(const float4*)(src+4);
  if (c0 >= 1024){
    float4 m0 = *(const float4*)(mix + ks);
    float4 m1 = *(const float4*)(mix + ks + 4);
    a.x*=m0.x; a.y*=m0.y; a.z*=m0.z; a.w*=m0.w;
    b.x*=m1.x; b.y*=m1.y; b.z*=m1.z; b.w*=m1.w;
  }
  uint4 ov = {pack_bf16(a.x,a.y), pack_bf16(a.z,a.w),
              pack_bf16(b.x,b.y), pack_bf16(b.z,b.w)};
  *(uint4*)(o + (size_t)n*BIGK + c0) = ov;
}

// ---------------- pack lora W1[C,D] (transposed) into BigB rows --------------
__global__ __launch_bounds__(256) void packL_kernel(const float* __restrict__ w1,
    const float* __restrict__ a1, const float* __restrict__ v1,
    const float* __restrict__ g1, const float* __restrict__ x_w,
    const float* __restrict__ x_a, const float* __restrict__ x_v,
    const float* __restrict__ x_g, u16* __restrict__ out) {
  int bid = blockIdx.x;           // 0..319
  const float* W1; const float* mix; int D, d, nbase;
  if (bid < 64)       { W1=w1; mix=x_w; D=64;  d=bid;     nbase=3072; }
  else if (bid < 128) { W1=a1; mix=x_a; D=64;  d=bid-64;  nbase=3136; }
  else if (bid < 160) { W1=v1; mix=x_v; D=32;  d=bid-128; nbase=3200; }
  else                { W1=g1; mix=x_g; D=160; d=bid-160; nbase=3232; }
  int k0 = threadIdx.x*8;
  float v[8];
  #pragma unroll
  for (int q=0;q<8;++q){
    int kk = k0+q;
    int ks = kk & 1023;
    float t = W1[(size_t)ks*D + d];
    if (kk >= 1024) t *= mix[ks];
    v[q] = t;
  }
  uint4 o = {pack_bf16(v[0],v[1]), pack_bf16(v[2],v[3]),
             pack_bf16(v[4],v[5]), pack_bf16(v[6],v[7])};
  *(uint4*)(out + (size_t)(nbase+d)*BIGK + k0) = o;
}

// --------- pack block-diagonal W2: out[n][k] bf16, n in [0,4096) k in [0,320)
__global__ __launch_bounds__(320) void packW2_kernel(const float* __restrict__ w2,
    const float* __restrict__ a2, const float* __restrict__ v2,
    const float* __restrict__ g2, u16* __restrict__ out) {
  int n = blockIdx.x; int k = threadIdx.x;
  int which = n >> 10, col = n & 1023;
  float v = 0.f;
  if (which==0)      { if (k < 64)              v = w2[(size_t)k*Cc + col]; }
  else if (which==1) { if (k >= 64 && k < 128)  v = a2[(size_t)(k-64)*Cc + col]; }
  else if (which==2) { if (k >= 128 && k < 160) v = v2[(size_t)(k-128)*Cc + col]; }
  else               { if (k >= 160)            v = g2[(size_t)(k-160)*Cc + col]; }
  out[(size_t)n*LORAK + k] = bf16_1(v);
}

// ---------------- fused LN1 -> bigA = [xn | xx] bf16 -------------------------
__global__ __launch_bounds__(256) void lnmix1_kernel(const float* __restrict__ x,
    const float* __restrict__ w, const float* __restrict__ b,
    u16* __restrict__ bigA) {
  int rowg = blockIdx.x; int t = rowg & (Tt-1);
  int tid = threadIdx.x;
  size_t off = (size_t)rowg*Cc + tid*4;
  float4 vc = *(const float4*)(x + off);
  float4 vp = {0.f,0.f,0.f,0.f};
  if (t) vp = *(const float4*)(x + off - Cc);
  float sc = vc.x+vc.y+vc.z+vc.w;
  float qc = vc.x*vc.x+vc.y*vc.y+vc.z*vc.z+vc.w*vc.w;
  float sp = vp.x+vp.y+vp.z+vp.w;
  float qp = vp.x*vp.x+vp.y*vp.y+vp.z*vp.z+vp.w*vp.w;
  sc = redgrp<32>(sc); qc = redgrp<32>(qc);
  sp = redgrp<32>(sp); qp = redgrp<32>(qp);
  __shared__ float rbuf[4][4];
  int lane = tid & 63, wv = tid >> 6;
  if (lane==0){ rbuf[wv][0]=sc; rbuf[wv][1]=qc; rbuf[wv][2]=sp; rbuf[wv][3]=qp; }
  __syncthreads();
  sc = rbuf[0][0]+rbuf[1][0]+rbuf[2][0]+rbuf[3][0];
  qc = rbuf[0][1]+rbuf[1][1]+rbuf[2][1]+rbuf[3][1];
  sp = rbuf[0][2]+rbuf[1][2]+rbuf[2][2]+rbuf[3][2];
  qp = rbuf[0][3]+rbuf[1][3]+rbuf[2][3]+rbuf[3][3];
  float muc = sc*(1.0f/Cc), mup = sp*(1.0f/Cc);
  float rnc = rsqrtf(qc*(1.0f/Cc) - muc*muc + 1e-5f);
  float rnp = rsqrtf(qp*(1.0f/Cc) - mup*mup + 1e-5f);
  float4 w4 = *(const float4*)(w + tid*4);
  float4 b4 = *(const float4*)(b + tid*4);
  float vcl[4]={vc.x,vc.y,vc.z,vc.w};
  float vpl[4]={vp.x,vp.y,vp.z,vp.w};
  float wl[4]={w4.x,w4.y,w4.z,w4.w};
  float bl[4]={b4.x,b4.y,b4.z,b4.w};
  float xnc[4], xx[4];
  #pragma unroll
  for (int q=0;q<4;++q){
    xnc[q] = (vcl[q]-muc)*rnc*wl[q] + bl[q];
    float xnp = t ? ((vpl[q]-mup)*rnp*wl[q] + bl[q]) : 0.0f;
    xx[q] = xnp - xnc[q];
  }
  size_t ab = (size_t)rowg*BIGK + tid*4;
  uint2 p0 = {pack_bf16(xnc[0],xnc[1]), pack_bf16(xnc[2],xnc[3])};
  uint2 p1 = {pack_bf16(xx[0],xx[1]),   pack_bf16(xx[2],xx[3])};
  *(uint2*)(bigA + ab) = p0;
  *(uint2*)(bigA + ab + 1024) = p1;
}

// ---------------- fused LN2 + cmix -> bf16 -----------------------------------
__global__ __launch_bounds__(256) void lnmix2_kernel(const float* __restrict__ x,
    const float* __restrict__ w, const float* __restrict__ b,
    const float* __restrict__ mixk, u16* __restrict__ outb) {
  int rowg = blockIdx.x; int t = rowg & (Tt-1);
  int tid = threadIdx.x;
  size_t off = (size_t)rowg*Cc + tid*4;
  float4 vc = *(const float4*)(x + off);
  float4 vp = {0.f,0.f,0.f,0.f};
  if (t) vp = *(const float4*)(x + off - Cc);
  float sc = vc.x+vc.y+vc.z+vc.w;
  float qc = vc.x*vc.x+vc.y*vc.y+vc.z*vc.z+vc.w*vc.w;
  float sp = vp.x+vp.y+vp.z+vp.w;
  float qp = vp.x*vp.x+vp.y*vp.y+vp.z*vp.z+vp.w*vp.w;
  sc = redgrp<32>(sc); qc = redgrp<32>(qc);
  sp = redgrp<32>(sp); qp = redgrp<32>(qp);
  __shared__ float rbuf[4][4];
  int lane = tid & 63, wv = tid >> 6;
  if (lane==0){ rbuf[wv][0]=sc; rbuf[wv][1]=qc; rbuf[wv][2]=sp; rbuf[wv][3]=qp; }
  __syncthreads();
  sc = rbuf[0][0]+rbuf[1][0]+rbuf[2][0]+rbuf[3][0];
  qc = rbuf[0][1]+rbuf[1][1]+rbuf[2][1]+rbuf[3][1];
  sp = rbuf[0][2]+rbuf[1][2]+rbuf[2][2]+rbuf[3][2];
  qp = rbuf[0][3]+rbuf[1][3]+rbuf[2][3]+rbuf[3][3];
  float muc = sc*(1.0f/Cc), mup = sp*(1.0f/Cc);
  float rnc = rsqrtf(qc*(1.0f/Cc) - muc*muc + 1e-5f);
  float rnp = rsqrtf(qp*(1.0f/Cc) - mup*mup + 1e-5f);
  float4 w4 = *(const float4*)(w + tid*4);
  float4 b4 = *(const float4*)(b + tid*4);
  float4 m = *(const float4*)(mixk + tid*4);
  float vcl[4]={vc.x,vc.y,vc.z,vc.w};
  float vpl[4]={vp.x,vp.y,vp.z,vp.w};
  float wl[4]={w4.x,w4.y,w4.z,w4.w};
  float bl[4]={b4.x,b4.y,b4.z,b4.w};
  float ml[4]={m.x,m.y,m.z,m.w};
  float o[4];
  #pragma unroll
  for (int q=0;q<4;++q){
    float xnc = (vcl[q]-muc)*rnc*wl[q] + bl[q];
    float xnp = t ? ((vpl[q]-mup)*rnp*wl[q] + bl[q]) : 0.0f;
    o[q] = xnc + (xnp - xnc)*ml[q];
  }
  uint2 p = {pack_bf16(o[0],o[1]), pack_bf16(o[2],o[3])};
  *(uint2*)(outb + off) = p;
}

// ================= bf16 GEMM (m97 structure, 128x128 tile) ===================
// out = A[M,K] @ W[N,K]^T.
// MODE 0: f32   1: f32 res+acc   2: bf16 relu(acc)^2
// MODE 3: f32 for gc<3072; gc in [3072,3392) -> activated bf16 into lora[].
// T1 bijective XCD swizzle; T4 counted vmcnt(8); T2 both-sides XOR swizzle.
template<int MODE>
__global__ __launch_bounds__(256) void gemm_bf16(const u16* __restrict__ A,
    const u16* __restrict__ W, void* __restrict__ outv,
    const float* __restrict__ res, u16* __restrict__ lora,
    int M, int N, int K) {
  __shared__ u16 As[2][128*64];
  __shared__ u16 Bs[2][128*64];
  int tid = threadIdx.x;
  int nwg = gridDim.x;
  int q8 = nwg >> 3;
  int id = (blockIdx.x & 7)*q8 + (blockIdx.x >> 3);   // bijective (nwg%8==0)
  int nbx = N >> 7;
  int bm = id / nbx, bn = id - bm*nbx;                // bn fastest: A-panel per XCD
  int wave = tid >> 6, lane = tid & 63;
  int wm = wave >> 1, wn = wave & 1;
  int srow = wave*32 + (lane>>3);
  int scol = (((lane&7) ^ ((lane>>3)&7)))*8;          // T2 source pre-swizzle
  const u16* Ag = A + (size_t)(bm*128 + srow)*K + scol;
  const u16* Wg = W + (size_t)(bn*128 + srow)*K + scol;
  int nt = K >> 6;
  f32x4 acc[4][4];
  f32x4 zero = {0.f,0.f,0.f,0.f};
  #pragma unroll
  for (int i=0;i<4;++i)
    #pragma unroll
    for (int j=0;j<4;++j) acc[i][j] = zero;

  #define STAGE(buf, t) { \
    const u16* Ag2 = Ag + (size_t)(t)*64; \
    const u16* Wg2 = Wg + (size_t)(t)*64; \
    _Pragma("unroll") \
    for (int i_=0;i_<4;++i_){ \
      gload16(Ag2 + (size_t)i_*8*K, &As[buf][(wave*32+i_*8)*64]); \
      gload16(Wg2 + (size_t)i_*8*K, &Bs[buf][(wave*32+i_*8)*64]); \
    } }

  STAGE(0, 0);
  int lrow = lane & 15, lk8 = lane >> 4;
  int r7 = lrow & 7;
  for (int t = 0; t < nt; ++t) {
    int cur = t & 1;
    if (t+1 < nt) {
      STAGE(cur^1, t+1);
      asm volatile("s_waitcnt vmcnt(8)\n\ts_barrier" ::: "memory");
    } else {
      asm volatile("s_waitcnt vmcnt(0)\n\ts_barrier" ::: "memory");
    }
    #pragma unroll
    for (int kk2 = 0; kk2 < 2; ++kk2) {
      int sl = ((kk2*4 + lk8) ^ r7) * 8;
      bf16x8 af[4], bfr[4];
      #pragma unroll
      for (int i=0;i<4;++i)
        af[i] = *(const bf16x8*)&As[cur][(wm*64 + i*16 + lrow)*64 + sl];
      #pragma unroll
      for (int j=0;j<4;++j)
        bfr[j] = *(const bf16x8*)&Bs[cur][(wn*64 + j*16 + lrow)*64 + sl];
      #pragma unroll
      for (int i=0;i<4;++i)
        #pragma unroll
        for (int j=0;j<4;++j)
          acc[i][j] = __builtin_amdgcn_mfma_f32_16x16x32_bf16(af[i], bfr[j], acc[i][j], 0, 0, 0);
    }
    asm volatile("s_barrier" ::: "memory");
  }
  #undef STAGE
  float* outf = (float*)outv;
  u16* outb = (u16*)outv;
  int crow4 = (lane>>4)*4, ccol = lane & 15;
  #pragma unroll
  for (int i=0;i<4;++i){
    #pragma unroll
    for (int j=0;j<4;++j){
      int gr = bm*128 + wm*64 + i*16 + crow4;
      int gc = bn*128 + wn*64 + j*16 + ccol;
      #pragma unroll
      for (int q=0;q<4;++q){
        float v = acc[i][j][q];
        size_t o = (size_t)(gr+q)*N + gc;
        if (MODE==1) { v += res[o]; outf[o] = v; }
        else if (MODE==2) { v = fmaxf(v, 0.f); outb[o] = bf16_1(v*v); }
        else if (MODE==3) {
          if (gc < 3072) outf[o] = v;
          else if (gc < 3392) {
            int cc = gc - 3072;
            float a = v;
            if (cc < 64) a = tanhf(a);
            else if (cc >= 160) a = sgm(a);
            lora[(size_t)(gr+q)*LORAK + cc] = bf16_1(a);
          }
        }
        else outf[o] = v;
      }
    }
  }
}

// ---------------- prep: dw/da/dv from dwdavg (ld 4096), k/v from bigOut ------
__global__ __launch_bounds__(256) void prep_kernel(
    const float* __restrict__ kraw, const float* __restrict__ dw,
    const float* __restrict__ da, const float* __restrict__ dv,
    const float* __restrict__ vraw, const float* __restrict__ vfirst,
    const float* __restrict__ w0, const float* __restrict__ a0,
    const float* __restrict__ v0, const float* __restrict__ k_k,
    const float* __restrict__ k_a,
    float* __restrict__ decay, float* __restrict__ kfin, float* __restrict__ vfin,
    float* __restrict__ Ak, float* __restrict__ Bk) {
  int row = blockIdx.x; int tid = threadIdx.x; int c = tid*4;
  size_t off = (size_t)row*Cc + c;
  size_t offw = (size_t)row*BIGN + c;
  size_t offd = (size_t)row*BIGW + c;
  float4 kr = *(const float4*)(kraw+offw);
  float4 vr = *(const float4*)(vraw+offw);
  float4 w4 = *(const float4*)(dw+offd);
  float4 A4 = *(const float4*)(da+offd);
  float4 V4 = *(const float4*)(dv+offd);
  float4 vf = *(const float4*)(vfirst+off);
  float4 w04 = *(const float4*)(w0+c);
  float4 a04 = *(const float4*)(a0+c);
  float4 v04 = *(const float4*)(v0+c);
  float4 kk4 = *(const float4*)(k_k+c);
  float4 ka4 = *(const float4*)(k_a+c);
  float krl[4]={kr.x,kr.y,kr.z,kr.w};
  float dwl[4]={w4.x,w4.y,w4.z,w4.w};
  float dal[4]={A4.x,A4.y,A4.z,A4.w};
  float dvl[4]={V4.x,V4.y,V4.z,V4.w};
  float vrl[4]={vr.x,vr.y,vr.z,vr.w};
  float vfl[4]={vf.x,vf.y,vf.z,vf.w};
  float w0l[4]={w04.x,w04.y,w04.z,w04.w};
  float a0l[4]={a04.x,a04.y,a04.z,a04.w};
  float v0l[4]={v04.x,v04.y,v04.z,v04.w};
  float kkl[4]={kk4.x,kk4.y,kk4.z,kk4.w};
  float kal[4]={ka4.x,ka4.y,ka4.z,ka4.w};
  float av[4], dec[4], vv[4], kp[4], kf[4];
  float ss = 0.f;
  #pragma unroll
  for (int q=0;q<4;++q){
    av[q] = sgm(a0l[q] + dal[q]);
    dec[q] = 0.60653065971263342f * sgm(w0l[q] + dwl[q]);   // exp(-softplus(-u)-0.5)
    float sv = sgm(v0l[q] + dvl[q]);
    vv[q] = vrl[q] + (vfl[q]-vrl[q])*sv;
    kp[q] = krl[q]*kkl[q];
    ss += kp[q]*kp[q];
    kf[q] = krl[q]*(1.0f + (av[q]-1.0f)*kal[q]);
  }
  ss = redgrp<8>(ss);
  float inv = 1.0f / fmaxf(sqrtf(ss), 1e-12f);
  float4 o;
  o.x=dec[0];o.y=dec[1];o.z=dec[2];o.w=dec[3];  *(float4*)(decay+off)=o;
  o.x=kf[0]; o.y=kf[1]; o.z=kf[2]; o.w=kf[3];   *(float4*)(kfin+off)=o;
  o.x=vv[0]; o.y=vv[1]; o.z=vv[2]; o.w=vv[3];   *(float4*)(vfin+off)=o;
  o.x=-kp[0]*inv; o.y=-kp[1]*inv; o.z=-kp[2]*inv; o.w=-kp[3]*inv; *(float4*)(Ak+off)=o;
  o.x=kp[0]*inv*av[0]; o.y=kp[1]*inv*av[1]; o.z=kp[2]*inv*av[2]; o.w=kp[3]*inv*av[3];
  *(float4*)(Bk+off)=o;
}

// ===== WKV-7 warmup-chunked scan (decay<=e^-0.5 => 32-step influence ~1e-7)
// 512 blocks (32 bh x 16 chunks), 256 thr = 4 waves; thread owns 4 rows x 4
// cols. 4 waves (not 8) halves the duplicated per-step LDS broadcast reads.
__global__ __launch_bounds__(256) void wkv_kernel(
    const float* __restrict__ decay, const float* __restrict__ Ak,
    const float* __restrict__ Bk, const float* __restrict__ kfin,
    const float* __restrict__ r_, const float* __restrict__ vfin,
    const float* __restrict__ S0, float* __restrict__ y) {
  __shared__ float lds[2][6][CH][64];
  int bid = blockIdx.x;
  int bh = bid & 31, c = bid >> 5;
  int bb = bh >> 4, h = bh & 15;
  int tid = threadIdx.x;
  int wave = tid >> 6, lane = tid & 63;
  int rg = tid >> 4;                  // 0..15
  int bj = tid & 15, j0 = bj*4;
  float S0r[4], S1r[4], S2r[4], S3r[4];
  #pragma unroll
  for (int q=0;q<4;++q){ S0r[q]=0.f; S1r[q]=0.f; S2r[q]=0.f; S3r[q]=0.f; }
  if (c == 0) {
    float4 t0 = *(const float4*)(S0 + (size_t)bh*4096 + (rg+ 0)*64 + j0);
    float4 t1 = *(const float4*)(S0 + (size_t)bh*4096 + (rg+16)*64 + j0);
    float4 t2 = *(const float4*)(S0 + (size_t)bh*4096 + (rg+32)*64 + j0);
    float4 t3 = *(const float4*)(S0 + (size_t)bh*4096 + (rg+48)*64 + j0);
    S0r[0]=t0.x; S0r[1]=t0.y; S0r[2]=t0.z; S0r[3]=t0.w;
    S1r[0]=t1.x; S1r[1]=t1.y; S1r[2]=t1.z; S1r[3]=t1.w;
    S2r[0]=t2.x; S2r[1]=t2.y; S2r[2]=t2.z; S2r[3]=t2.w;
    S3r[0]=t3.x; S3r[1]=t3.y; S3r[2]=t3.z; S3r[3]=t3.w;
  }
  size_t seqb = (size_t)bb*Tt;
  int t0g = (c==0) ? 0 : (c*CL - WU);
  int NPH = (c==0) ? (CL/CH) : ((CL+WU)/CH);
  int phE = (c==0) ? 0 : (WU/CH);
  int lhi = lane >> 4, llo4 = (lane & 15)*4;

  #define WST1(buf, stepb, arr, base, ldv) { \
    const float* gp_ = (base) + (size_t)(seqb + (size_t)(stepb) + lhi)*(ldv) + h*64 + llo4; \
    _Pragma("unroll") \
    for (int p_=0; p_<4; ++p_) \
      gload16(gp_ + (size_t)p_*4*(ldv), &lds[buf][arr][p_*4][0]); }
  #define WSTAGE(buf, stepb) { \
    if (wave==0)      { WST1(buf, stepb, 0, decay, Cc) WST1(buf, stepb, 1, Ak, Cc) } \
    else if (wave==1) { WST1(buf, stepb, 2, Bk, Cc)   WST1(buf, stepb, 3, kfin, Cc) } \
    else if (wave==2) { WST1(buf, stepb, 4, r_, BIGN) } \
    else              { WST1(buf, stepb, 5, vfin, Cc) } }

  WSTAGE(0, t0g);
  for (int ph = 0; ph < NPH; ++ph) {
    int cur = ph & 1;
    if (ph+1 < NPH) {
      WSTAGE(cur^1, t0g + (ph+1)*CH);
      // counted per-wave: waves 0-1 carry 8 loads/phase, waves 2-3 carry 4
      if (wave < 2) asm volatile("s_waitcnt vmcnt(8)" ::: "memory");
      else          asm volatile("s_waitcnt vmcnt(4)" ::: "memory");
      asm volatile("s_barrier" ::: "memory");
    } else {
      asm volatile("s_waitcnt vmcnt(0)\n\ts_barrier" ::: "memory");
    }
    bool emit = (ph >= phE);
    const float* L0 = &lds[cur][0][0][0];
    #pragma unroll
    for (int s = 0; s < CH; ++s) {
      const float* bp = L0 + s*64;
      float4 d4 = *(const float4*)(bp + 0*CH*64 + j0);
      float4 a4 = *(const float4*)(bp + 1*CH*64 + j0);
      float4 b4 = *(const float4*)(bp + 2*CH*64 + j0);
      float4 k4 = *(const float4*)(bp + 3*CH*64 + j0);
      float4 r4 = *(const float4*)(bp + 4*CH*64 + j0);
      float v0 = bp[5*CH*64 + rg];
      float v1 = bp[5*CH*64 + rg+16];
      float v2 = bp[5*CH*64 + rg+32];
      float v3 = bp[5*CH*64 + rg+48];
      S0r[0]*=d4.x; S0r[1]*=d4.y; S0r[2]*=d4.z; S0r[3]*=d4.w;
      S1r[0]*=d4.x; S1r[1]*=d4.y; S1r[2]*=d4.z; S1r[3]*=d4.w;
      S2r[0]*=d4.x; S2r[1]*=d4.y; S2r[2]*=d4.z; S2r[3]*=d4.w;
      S3r[0]*=d4.x; S3r[1]*=d4.y; S3r[2]*=d4.z; S3r[3]*=d4.w;
      float sa0 = fmaf(S0r[0],a4.x, S0r[1]*a4.y) + fmaf(S0r[2],a4.z, S0r[3]*a4.w);
      float sa1 = fmaf(S1r[0],a4.x, S1r[1]*a4.y) + fmaf(S1r[2],a4.z, S1r[3]*a4.w);
      float sa2 = fmaf(S2r[0],a4.x, S2r[1]*a4.y) + fmaf(S2r[2],a4.z, S2r[3]*a4.w);
      float sa3 = fmaf(S3r[0],a4.x, S3r[1]*a4.y) + fmaf(S3r[2],a4.z, S3r[3]*a4.w);
      sa0 = red16(sa0); sa1 = red16(sa1); sa2 = red16(sa2); sa3 = red16(sa3);
      S0r[0]=fmaf(v0,k4.x,S0r[0]); S0r[1]=fmaf(v0,k4.y,S0r[1]);
      S0r[2]=fmaf(v0,k4.z,S0r[2]); S0r[3]=fmaf(v0,k4.w,S0r[3]);
      S0r[0]=fmaf(sa0,b4.x,S0r[0]); S0r[1]=fmaf(sa0,b4.y,S0r[1]);
      S0r[2]=fmaf(sa0,b4.z,S0r[2]); S0r[3]=fmaf(sa0,b4.w,S0r[3]);
      S1r[0]=fmaf(v1,k4.x,S1r[0]); S1r[1]=fmaf(v1,k4.y,S1r[1]);
      S1r[2]=fmaf(v1,k4.z,S1r[2]); S1r[3]=fmaf(v1,k4.w,S1r[3]);
      S1r[0]=fmaf(sa1,b4.x,S1r[0]); S1r[1]=fmaf(sa1,b4.y,S1r[1]);
      S1r[2]=fmaf(sa1,b4.z,S1r[2]); S1r[3]=fmaf(sa1,b4.w,S1r[3]);
      S2r[0]=fmaf(v2,k4.x,S2r[0]); S2r[1]=fmaf(v2,k4.y,S2r[1]);
      S2r[2]=fmaf(v2,k4.z,S2r[2]); S2r[3]=fmaf(v2,k4.w,S2r[3]);
      S2r[0]=fmaf(sa2,b4.x,S2r[0]); S2r[1]=fmaf(sa2,b4.y,S2r[1]);
      S2r[2]=fmaf(sa2,b4.z,S2r[2]); S2r[3]=fmaf(sa2,b4.w,S2r[3]);
      S3r[0]=fmaf(v3,k4.x,S3r[0]); S3r[1]=fmaf(v3,k4.y,S3r[1]);
      S3r[2]=fmaf(v3,k4.z,S3r[2]); S3r[3]=fmaf(v3,k4.w,S3r[3]);
      S3r[0]=fmaf(sa3,b4.x,S3r[0]); S3r[1]=fmaf(sa3,b4.y,S3r[1]);
      S3r[2]=fmaf(sa3,b4.z,S3r[2]); S3r[3]=fmaf(sa3,b4.w,S3r[3]);
      if (emit) {
        float y0 = fmaf(S0r[0],r4.x, S0r[1]*r4.y) + fmaf(S0r[2],r4.z, S0r[3]*r4.w);
        float y1 = fmaf(S1r[0],r4.x, S1r[1]*r4.y) + fmaf(S1r[2],r4.z, S1r[3]*r4.w);
        float y2 = fmaf(S2r[0],r4.x, S2r[1]*r4.y) + fmaf(S2r[2],r4.z, S2r[3]*r4.w);
        float y3 = fmaf(S3r[0],r4.x, S3r[1]*r4.y) + fmaf(S3r[2],r4.z, S3r[3]*r4.w);
        y0 = red16(y0); y1 = red16(y1); y2 = red16(y2); y3 = red16(y3);
        if (bj == 0) {
          size_t yo = (seqb + (size_t)t0g + ph*CH + s)*Cc + h*64;
          y[yo + rg     ] = y0;
          y[yo + rg + 16] = y1;
          y[yo + rg + 32] = y2;
          y[yo + rg + 48] = y3;
        }
      }
    }
    asm volatile("s_barrier" ::: "memory");
  }
  #undef WSTAGE
  #undef WST1
}

// ---------------- GroupNorm(head) + r.k.r_k bonus + *g -> bf16 ---------------
__global__ __launch_bounds__(256) void gn_kernel(
    const float* __restrict__ y, const float* __restrict__ r_,
    const float* __restrict__ kfin, const float* __restrict__ vfin,
    const float* __restrict__ g_, const float* __restrict__ lnxw,
    const float* __restrict__ lnxb, const float* __restrict__ r_k,
    u16* __restrict__ Ao) {
  int row = blockIdx.x; int tid = threadIdx.x; int c = tid*4;
  size_t off = (size_t)row*Cc + c;
  float4 y4 = *(const float4*)(y+off);
  float s = y4.x+y4.y+y4.z+y4.w;
  float q = y4.x*y4.x+y4.y*y4.y+y4.z*y4.z+y4.w*y4.w;
  s = redgrp<8>(s); q = redgrp<8>(q);
  float mu = s*(1.0f/64.0f);
  float var = q*(1.0f/64.0f) - mu*mu;
  float rn = rsqrtf(var + 64e-5f);
  float4 rr = *(const float4*)(r_ + (size_t)row*BIGN + c);
  float4 kk = *(const float4*)(kfin+off);
  float4 vv = *(const float4*)(vfin+off);
  float4 gg = *(const float4*)(g_ + (size_t)row*BIGW + c);
  int h = tid >> 4; int hs = (tid & 15)*4;
  float4 rk = *(const float4*)(r_k + h*64 + hs);
  float dp = rr.x*kk.x*rk.x + rr.y*kk.y*rk.y + rr.z*kk.z*rk.z + rr.w*kk.w*rk.w;
  dp = redgrp<8>(dp);
  float4 w4 = *(const float4*)(lnxw+c);
  float4 b4 = *(const float4*)(lnxb+c);
  float o0 = (((y4.x-mu)*rn)*w4.x + b4.x + dp*vv.x) * gg.x;
  float o1 = (((y4.y-mu)*rn)*w4.y + b4.y + dp*vv.y) * gg.y;
  float o2 = (((y4.z-mu)*rn)*w4.z + b4.z + dp*vv.z) * gg.z;
  float o3 = (((y4.w-mu)*rn)*w4.w + b4.w + dp*vv.w) * gg.w;
  uint2 p = {pack_bf16(o0,o1), pack_bf16(o2,o3)};
  *(uint2*)(Ao + off) = p;
}

__global__ __launch_bounds__(256) void copy_kernel(const float* __restrict__ src,
                                                   float* __restrict__ dst) {
  size_t i = ((size_t)blockIdx.x*256 + threadIdx.x)*4;
  *(float4*)(dst+i) = *(const float4*)(src+i);
}

extern "C" void kernel_launch(void* const* d_in, const int* in_sizes, int n_in,
                              void* d_out, int out_size, void* d_ws, size_t ws_size,
                              hipStream_t stream) {
  const float* x      = (const float*)d_in[0];
  const float* vfirst = (const float*)d_in[1];
  const float* S0     = (const float*)d_in[2];
  const float* ln1w   = (const float*)d_in[3];
  const float* ln1b   = (const float*)d_in[4];
  const float* ln2w   = (const float*)d_in[5];
  const float* ln2b   = (const float*)d_in[6];
  const float* x_r    = (const float*)d_in[7];
  const float* x_w    = (const float*)d_in[8];
  const float* x_k    = (const float*)d_in[9];
  const float* x_v    = (const float*)d_in[10];
  const float* x_a    = (const float*)d_in[11];
  const float* x_g    = (const float*)d_in[12];
  const float* w0     = (const float*)d_in[13];
  const float* w1     = (const float*)d_in[14];
  const float* w2     = (const float*)d_in[15];
  const float* a0     = (const float*)d_in[16];
  const float* a1     = (const float*)d_in[17];
  const float* a2     = (const float*)d_in[18];
  const float* v0     = (const float*)d_in[19];
  const float* v1     = (const float*)d_in[20];
  const float* v2     = (const float*)d_in[21];
  const float* g1     = (const float*)d_in[22];
  const float* g2     = (const float*)d_in[23];
  const float* k_k    = (const float*)d_in[24];
  const float* k_a    = (const float*)d_in[25];
  const float* r_k    = (const float*)d_in[26];
  const float* W_r    = (const float*)d_in[27];
  const float* W_k    = (const float*)d_in[28];
  const float* W_v    = (const float*)d_in[29];
  const float* W_o    = (const float*)d_in[30];
  const float* lnxw   = (const float*)d_in[31];
  const float* lnxb   = (const float*)d_in[32];
  const float* mixk   = (const float*)d_in[33];
  const float* Wkey   = (const float*)d_in[34];
  const float* Wval   = (const float*)d_in[35];
  float* out = (float*)d_out;
  float* ws  = (float*)d_ws;
  const size_t U = (size_t)BT * Cc;
  float* u[14];
  for (int i=0;i<14;++i) u[i] = ws + i*U;

  u16* bigA   = (u16*)u[0];
  u16* BigB   = (u16*)u[1];
  float* bigOut = u[2];     // [4096][3456] f32 (u2..u5)
  float* dwdavg = u[6];     // [4096][4096] f32 (u6..u9)
  u16* W2blk  = (u16*)u[10];
  u16* loraAct= (u16*)u[11];
  float* Bk   = u[0];
  float* y_   = u[1];
  u16* gnb    = (u16*)u[10];
  u16* Wob    = (u16*)u[13];
  float* xo   = u[0];
  u16* Wkeyb  = (u16*)u[6];
  u16* cmb    = (u16*)u[7];
  u16* Wvalb  = (u16*)u[8];
  u16* midb   = (u16*)u[2];

  dim3 b256(256);
  packW_kernel<<<dim3(Cc,3), b256, 0, stream>>>(W_r, W_k, W_v, x_r, x_k, x_v, BigB);
  packL_kernel<<<320, b256, 0, stream>>>(w1, a1, v1, g1, x_w, x_a, x_v, x_g, BigB);
  packW2_kernel<<<BIGW, dim3(320), 0, stream>>>(w2, a2, v2, g2, W2blk);
  lnmix1_kernel<<<BT, b256, 0, stream>>>(x, ln1w, ln1b, bigA);
  // big GEMM: r|k|v cols -> f32 bigOut; lora cols -> activated bf16 loraAct
  gemm_bf16<3><<<(BT/128)*(BIGN/128), b256, 0, stream>>>(bigA, BigB, bigOut, nullptr, loraAct, BT, BIGN, BIGK);
  gemm_bf16<0><<<(BT/128)*(BIGW/128), b256, 0, stream>>>(loraAct, W2blk, dwdavg, nullptr, nullptr, BT, BIGW, LORAK);
  prep_kernel<<<BT, b256, 0, stream>>>(bigOut+1024, dwdavg, dwdavg+1024, dwdavg+2048,
      bigOut+2048, vfirst, w0, a0, v0, k_k, k_a, u[10], u[11], u[12], u[13], Bk);
  wkv_kernel<<<32*(Tt/CL), b256, 0, stream>>>(u[10], u[13], Bk, u[11], bigOut, u[12], S0, y_);
  cvt_kernel<<<Cc*Cc/2048, b256, 0, stream>>>(W_o, Wob);
  gn_kernel<<<BT, b256, 0, stream>>>(y_, bigOut, u[11], u[12], dwdavg+3072, lnxw, lnxb, r_k, gnb);
  gemm_bf16<1><<<(BT/128)*(Cc/128), b256, 0, stream>>>(gnb, Wob, xo, x, nullptr, BT, Cc, Cc);
  lnmix2_kernel<<<BT, b256, 0, stream>>>(xo, ln2w, ln2b, mixk, cmb);
  cvt_kernel<<<FFNd*Cc/2048, b256, 0, stream>>>(Wkey, Wkeyb);
  gemm_bf16<2><<<(BT/128)*(FFNd/128), b256, 0, stream>>>(cmb, Wkeyb, midb, nullptr, nullptr, BT, FFNd, Cc);
  cvt_kernel<<<Cc*FFNd/2048, b256, 0, stream>>>(Wval, Wvalb);
  gemm_bf16<1><<<(BT/128)*(Cc/128), b256, 0, stream>>>(midb, Wvalb, out, xo, nullptr, BT, Cc, FFNd);
  copy_kernel<<<BT*Cc/1024, b256, 0, stream>>>(vfirst, out + (size_t)BT*Cc);
}

// Round 14
// 419.080 us; speedup vs baseline: 1.0494x; 1.0494x over previous
//
#include <hip/hip_runtime.h>
#include <math.h>

#define Bb 2
#define Tt 2048
#define Cc 1024
#define Hh 16
#define BT 4096
#define FFNd 4096
#define CH 16
#define CL 128
#define WU 32
#define BIGN 3456
#define BIGK 2048
#define LORAK 320
#define BIGW 4096
// big-B column layout: r@0 k@1024 v@2048 w@3072 a@3136 vl@3200 g@3232 (end 3392, pad->3456)
// dwdavg column layout: dw@0 da@1024 dv@2048 g@3072  (ld 4096)

typedef __attribute__((ext_vector_type(8))) short bf16x8;
typedef __attribute__((ext_vector_type(4))) float f32x4;
typedef unsigned short u16;

__device__ __forceinline__ float sgm(float x){ return 1.0f/(1.0f+expf(-x)); }

template<int MAXM>
__device__ __forceinline__ float redgrp(float v){
  #pragma unroll
  for (int m=1; m<=MAXM; m<<=1) v += __shfl_xor(v, m, 64);
  return v;
}

template<int CTRL>
__device__ __forceinline__ float dppadd(float v){
  union { float f; int i; } u, r;
  u.f = v;
  r.i = __builtin_amdgcn_update_dpp(u.i, u.i, CTRL, 0xf, 0xf, true);
  return v + r.f;
}
__device__ __forceinline__ float red16(float v){
  v = dppadd<0xB1>(v);
  v = dppadd<0x4E>(v);
  v = dppadd<0x141>(v);
  v = dppadd<0x140>(v);
  return v;
}

__device__ __forceinline__ unsigned pack_bf16(float a, float b){
  unsigned ua = __builtin_bit_cast(unsigned, a);
  unsigned ub = __builtin_bit_cast(unsigned, b);
  ua = (ua + 0x7FFFu + ((ua>>16)&1u)) >> 16;
  ub = (ub + 0x7FFFu + ((ub>>16)&1u)) >> 16;
  return ua | (ub<<16);
}
__device__ __forceinline__ u16 bf16_1(float a){
  unsigned ua = __builtin_bit_cast(unsigned, a);
  return (u16)((ua + 0x7FFFu + ((ua>>16)&1u)) >> 16);
}

__device__ __forceinline__ void gload16(const void* g, void* l){
  __builtin_amdgcn_global_load_lds(
    (const __attribute__((address_space(1))) unsigned int*)g,
    (__attribute__((address_space(3))) unsigned int*)l, 16, 0, 0);
}

// ---------------- fused f32 -> bf16 convert of all three weights -------------
__device__ __forceinline__ void cvt8(const float* __restrict__ in,
    u16* __restrict__ out, size_t i){
  float4 a = ((const float4*)in)[2*i];
  float4 b = ((const float4*)in)[2*i+1];
  uint4 o = {pack_bf16(a.x,a.y), pack_bf16(a.z,a.w),
             pack_bf16(b.x,b.y), pack_bf16(b.z,b.w)};
  ((uint4*)out)[i] = o;
}
__global__ __launch_bounds__(256) void cvtall_kernel(
    const float* __restrict__ wo, u16* __restrict__ wob,
    const float* __restrict__ wk, u16* __restrict__ wkb,
    const float* __restrict__ wv, u16* __restrict__ wvb) {
  size_t i = (size_t)blockIdx.x*256 + threadIdx.x;
  const size_t NA = (size_t)Cc*Cc/8;       // 131072
  const size_t NB = (size_t)FFNd*Cc/8;     // 524288
  if (i < NA) cvt8(wo, wob, i);
  else if (i < NA+NB) cvt8(wk, wkb, i-NA);
  else cvt8(wv, wvb, i-NA-NB);
}

// ---------------- pack square weights into BigB rows: [W | diag(mix)W] -------
__global__ __launch_bounds__(256) void packW_kernel(const float* __restrict__ Wr,
    const float* __restrict__ Wk, const float* __restrict__ Wv,
    const float* __restrict__ xr, const float* __restrict__ xk,
    const float* __restrict__ xv, u16* __restrict__ out) {
  int which = blockIdx.y;
  const float* W   = which==0 ? Wr : (which==1 ? Wk : Wv);
  const float* mix = which==0 ? xr : (which==1 ? xk : xv);
  u16* o = out + (size_t)which*1024*BIGK;
  int n = blockIdx.x;             // 0..1023
  int c0 = threadIdx.x*8;         // 0..2040
  int ks = c0 & 1023;
  const float* src = W + (size_t)n*Cc + ks;
  float4 a = *(const float4*)src;
  float4 b = *(const float4*)(src+4);
  if (c0 >= 1024){
    float4 m0 = *(const float4*)(mix + ks);
    float4 m1 = *(const float4*)(mix + ks + 4);
    a.x*=m0.x; a.y*=m0.y; a.z*=m0.z; a.w*=m0.w;
    b.x*=m1.x; b.y*=m1.y; b.z*=m1.z; b.w*=m1.w;
  }
  uint4 ov = {pack_bf16(a.x,a.y), pack_bf16(a.z,a.w),
              pack_bf16(b.x,b.y), pack_bf16(b.z,b.w)};
  *(uint4*)(o + (size_t)n*BIGK + c0) = ov;
}

// ---------------- pack lora W1[C,D] (transposed) into BigB rows --------------
__global__ __launch_bounds__(256) void packL_kernel(const float* __restrict__ w1,
    const float* __restrict__ a1, const float* __restrict__ v1,
    const float* __restrict__ g1, const float* __restrict__ x_w,
    const float* __restrict__ x_a, const float* __restrict__ x_v,
    const float* __restrict__ x_g, u16* __restrict__ out) {
  int bid = blockIdx.x;           // 0..319
  const float* W1; const float* mix; int D, d, nbase;
  if (bid < 64)       { W1=w1; mix=x_w; D=64;  d=bid;     nbase=3072; }
  else if (bid < 128) { W1=a1; mix=x_a; D=64;  d=bid-64;  nbase=3136; }
  else if (bid < 160) { W1=v1; mix=x_v; D=32;  d=bid-128; nbase=3200; }
  else                { W1=g1; mix=x_g; D=160; d=bid-160; nbase=3232; }
  int k0 = threadIdx.x*8;
  float v[8];
  #pragma unroll
  for (int q=0;q<8;++q){
    int kk = k0+q;
    int ks = kk & 1023;
    float t = W1[(size_t)ks*D + d];
    if (kk >= 1024) t *= mix[ks];
    v[q] = t;
  }
  uint4 o = {pack_bf16(v[0],v[1]), pack_bf16(v[2],v[3]),
             pack_bf16(v[4],v[5]), pack_bf16(v[6],v[7])};
  *(uint4*)(out + (size_t)(nbase+d)*BIGK + k0) = o;
}

// --------- pack block-diagonal W2: out[n][k] bf16, n in [0,4096) k in [0,320)
__global__ __launch_bounds__(320) void packW2_kernel(const float* __restrict__ w2,
    const float* __restrict__ a2, const float* __restrict__ v2,
    const float* __restrict__ g2, u16* __restrict__ out) {
  int n = blockIdx.x; int k = threadIdx.x;
  int which = n >> 10, col = n & 1023;
  float v = 0.f;
  if (which==0)      { if (k < 64)              v = w2[(size_t)k*Cc + col]; }
  else if (which==1) { if (k >= 64 && k < 128)  v = a2[(size_t)(k-64)*Cc + col]; }
  else if (which==2) { if (k >= 128 && k < 160) v = v2[(size_t)(k-128)*Cc + col]; }
  else               { if (k >= 160)            v = g2[(size_t)(k-160)*Cc + col]; }
  out[(size_t)n*LORAK + k] = bf16_1(v);
}

// --------- act + cvt lora columns of bigOut -> loraAct bf16 [4096][320] ------
__global__ __launch_bounds__(320) void actcvt_kernel(const float* __restrict__ m,
    u16* __restrict__ loraAct) {
  int i = blockIdx.x; int cc = threadIdx.x;
  float v = m[(size_t)i*BIGN + 3072 + cc];
  if (cc < 64) v = tanhf(v);
  else if (cc >= 160) v = sgm(v);
  loraAct[(size_t)i*LORAK + cc] = bf16_1(v);
}

// ---------------- fused LN1 -> bigA = [xn | xx] bf16 -------------------------
__global__ __launch_bounds__(256) void lnmix1_kernel(const float* __restrict__ x,
    const float* __restrict__ w, const float* __restrict__ b,
    u16* __restrict__ bigA) {
  int rowg = blockIdx.x; int t = rowg & (Tt-1);
  int tid = threadIdx.x;
  size_t off = (size_t)rowg*Cc + tid*4;
  float4 vc = *(const float4*)(x + off);
  float4 vp = {0.f,0.f,0.f,0.f};
  if (t) vp = *(const float4*)(x + off - Cc);
  float sc = vc.x+vc.y+vc.z+vc.w;
  float qc = vc.x*vc.x+vc.y*vc.y+vc.z*vc.z+vc.w*vc.w;
  float sp = vp.x+vp.y+vp.z+vp.w;
  float qp = vp.x*vp.x+vp.y*vp.y+vp.z*vp.z+vp.w*vp.w;
  sc = redgrp<32>(sc); qc = redgrp<32>(qc);
  sp = redgrp<32>(sp); qp = redgrp<32>(qp);
  __shared__ float rbuf[4][4];
  int lane = tid & 63, wv = tid >> 6;
  if (lane==0){ rbuf[wv][0]=sc; rbuf[wv][1]=qc; rbuf[wv][2]=sp; rbuf[wv][3]=qp; }
  __syncthreads();
  sc = rbuf[0][0]+rbuf[1][0]+rbuf[2][0]+rbuf[3][0];
  qc = rbuf[0][1]+rbuf[1][1]+rbuf[2][1]+rbuf[3][1];
  sp = rbuf[0][2]+rbuf[1][2]+rbuf[2][2]+rbuf[3][2];
  qp = rbuf[0][3]+rbuf[1][3]+rbuf[2][3]+rbuf[3][3];
  float muc = sc*(1.0f/Cc), mup = sp*(1.0f/Cc);
  float rnc = rsqrtf(qc*(1.0f/Cc) - muc*muc + 1e-5f);
  float rnp = rsqrtf(qp*(1.0f/Cc) - mup*mup + 1e-5f);
  float4 w4 = *(const float4*)(w + tid*4);
  float4 b4 = *(const float4*)(b + tid*4);
  float vcl[4]={vc.x,vc.y,vc.z,vc.w};
  float vpl[4]={vp.x,vp.y,vp.z,vp.w};
  float wl[4]={w4.x,w4.y,w4.z,w4.w};
  float bl[4]={b4.x,b4.y,b4.z,b4.w};
  float xnc[4], xx[4];
  #pragma unroll
  for (int q=0;q<4;++q){
    xnc[q] = (vcl[q]-muc)*rnc*wl[q] + bl[q];
    float xnp = t ? ((vpl[q]-mup)*rnp*wl[q] + bl[q]) : 0.0f;
    xx[q] = xnp - xnc[q];
  }
  size_t ab = (size_t)rowg*BIGK + tid*4;
  uint2 p0 = {pack_bf16(xnc[0],xnc[1]), pack_bf16(xnc[2],xnc[3])};
  uint2 p1 = {pack_bf16(xx[0],xx[1]),   pack_bf16(xx[2],xx[3])};
  *(uint2*)(bigA + ab) = p0;
  *(uint2*)(bigA + ab + 1024) = p1;
}

// ---------------- fused LN2 + cmix -> bf16 -----------------------------------
__global__ __launch_bounds__(256) void lnmix2_kernel(const float* __restrict__ x,
    const float* __restrict__ w, const float* __restrict__ b,
    const float* __restrict__ mixk, u16* __restrict__ outb) {
  int rowg = blockIdx.x; int t = rowg & (Tt-1);
  int tid = threadIdx.x;
  size_t off = (size_t)rowg*Cc + tid*4;
  float4 vc = *(const float4*)(x + off);
  float4 vp = {0.f,0.f,0.f,0.f};
  if (t) vp = *(const float4*)(x + off - Cc);
  float sc = vc.x+vc.y+vc.z+vc.w;
  float qc = vc.x*vc.x+vc.y*vc.y+vc.z*vc.z+vc.w*vc.w;
  float sp = vp.x+vp.y+vp.z+vp.w;
  float qp = vp.x*vp.x+vp.y*vp.y+vp.z*vp.z+vp.w*vp.w;
  sc = redgrp<32>(sc); qc = redgrp<32>(qc);
  sp = redgrp<32>(sp); qp = redgrp<32>(qp);
  __shared__ float rbuf[4][4];
  int lane = tid & 63, wv = tid >> 6;
  if (lane==0){ rbuf[wv][0]=sc; rbuf[wv][1]=qc; rbuf[wv][2]=sp; rbuf[wv][3]=qp; }
  __syncthreads();
  sc = rbuf[0][0]+rbuf[1][0]+rbuf[2][0]+rbuf[3][0];
  qc = rbuf[0][1]+rbuf[1][1]+rbuf[2][1]+rbuf[3][1];
  sp = rbuf[0][2]+rbuf[1][2]+rbuf[2][2]+rbuf[3][2];
  qp = rbuf[0][3]+rbuf[1][3]+rbuf[2][3]+rbuf[3][3];
  float muc = sc*(1.0f/Cc), mup = sp*(1.0f/Cc);
  float rnc = rsqrtf(qc*(1.0f/Cc) - muc*muc + 1e-5f);
  float rnp = rsqrtf(qp*(1.0f/Cc) - mup*mup + 1e-5f);
  float4 w4 = *(const float4*)(w + tid*4);
  float4 b4 = *(const float4*)(b + tid*4);
  float4 m = *(const float4*)(mixk + tid*4);
  float vcl[4]={vc.x,vc.y,vc.z,vc.w};
  float vpl[4]={vp.x,vp.y,vp.z,vp.w};
  float wl[4]={w4.x,w4.y,w4.z,w4.w};
  float bl[4]={b4.x,b4.y,b4.z,b4.w};
  float ml[4]={m.x,m.y,m.z,m.w};
  float o[4];
  #pragma unroll
  for (int q=0;q<4;++q){
    float xnc = (vcl[q]-muc)*rnc*wl[q] + bl[q];
    float xnp = t ? ((vpl[q]-mup)*rnp*wl[q] + bl[q]) : 0.0f;
    o[q] = xnc + (xnp - xnc)*ml[q];
  }
  uint2 p = {pack_bf16(o[0],o[1]), pack_bf16(o[2],o[3])};
  *(uint2*)(outb + off) = p;
}

// ================= bf16 GEMM (m97 structure, 128x128 tile) ===================
// out = A[M,K] @ W[N,K]^T.  MODE 0: f32   1: f32 res+acc   2: bf16 relu(acc)^2
// T1 bijective XCD swizzle; T4 counted vmcnt(8); T2 both-sides XOR swizzle.
template<int MODE>
__global__ __launch_bounds__(256) void gemm_bf16(const u16* __restrict__ A,
    const u16* __restrict__ W, void* __restrict__ outv,
    const float* __restrict__ res, int M, int N, int K) {
  __shared__ u16 As[2][128*64];
  __shared__ u16 Bs[2][128*64];
  int tid = threadIdx.x;
  int nwg = gridDim.x;
  int q8 = nwg >> 3;
  int id = (blockIdx.x & 7)*q8 + (blockIdx.x >> 3);   // bijective (nwg%8==0)
  int nbx = N >> 7;
  int bm = id / nbx, bn = id - bm*nbx;                // bn fastest: A-panel per XCD
  int wave = tid >> 6, lane = tid & 63;
  int wm = wave >> 1, wn = wave & 1;
  int srow = wave*32 + (lane>>3);
  int scol = (((lane&7) ^ ((lane>>3)&7)))*8;          // T2 source pre-swizzle
  const u16* Ag = A + (size_t)(bm*128 + srow)*K + scol;
  const u16* Wg = W + (size_t)(bn*128 + srow)*K + scol;
  int nt = K >> 6;
  f32x4 acc[4][4];
  f32x4 zero = {0.f,0.f,0.f,0.f};
  #pragma unroll
  for (int i=0;i<4;++i)
    #pragma unroll
    for (int j=0;j<4;++j) acc[i][j] = zero;

  #define STAGE(buf, t) { \
    const u16* Ag2 = Ag + (size_t)(t)*64; \
    const u16* Wg2 = Wg + (size_t)(t)*64; \
    _Pragma("unroll") \
    for (int i_=0;i_<4;++i_){ \
      gload16(Ag2 + (size_t)i_*8*K, &As[buf][(wave*32+i_*8)*64]); \
      gload16(Wg2 + (size_t)i_*8*K, &Bs[buf][(wave*32+i_*8)*64]); \
    } }

  STAGE(0, 0);
  int lrow = lane & 15, lk8 = lane >> 4;
  int r7 = lrow & 7;
  for (int t = 0; t < nt; ++t) {
    int cur = t & 1;
    if (t+1 < nt) {
      STAGE(cur^1, t+1);
      asm volatile("s_waitcnt vmcnt(8)\n\ts_barrier" ::: "memory");
    } else {
      asm volatile("s_waitcnt vmcnt(0)\n\ts_barrier" ::: "memory");
    }
    #pragma unroll
    for (int kk2 = 0; kk2 < 2; ++kk2) {
      int sl = ((kk2*4 + lk8) ^ r7) * 8;
      bf16x8 af[4], bfr[4];
      #pragma unroll
      for (int i=0;i<4;++i)
        af[i] = *(const bf16x8*)&As[cur][(wm*64 + i*16 + lrow)*64 + sl];
      #pragma unroll
      for (int j=0;j<4;++j)
        bfr[j] = *(const bf16x8*)&Bs[cur][(wn*64 + j*16 + lrow)*64 + sl];
      #pragma unroll
      for (int i=0;i<4;++i)
        #pragma unroll
        for (int j=0;j<4;++j)
          acc[i][j] = __builtin_amdgcn_mfma_f32_16x16x32_bf16(af[i], bfr[j], acc[i][j], 0, 0, 0);
    }
    asm volatile("s_barrier" ::: "memory");
  }
  #undef STAGE
  float* outf = (float*)outv;
  u16* outb = (u16*)outv;
  int crow4 = (lane>>4)*4, ccol = lane & 15;
  #pragma unroll
  for (int i=0;i<4;++i){
    #pragma unroll
    for (int j=0;j<4;++j){
      int gr = bm*128 + wm*64 + i*16 + crow4;
      int gc = bn*128 + wn*64 + j*16 + ccol;
      #pragma unroll
      for (int q=0;q<4;++q){
        float v = acc[i][j][q];
        size_t o = (size_t)(gr+q)*N + gc;
        if (MODE==1) { v += res[o]; outf[o] = v; }
        else if (MODE==2) { v = fmaxf(v, 0.f); outb[o] = bf16_1(v*v); }
        else outf[o] = v;
      }
    }
  }
}

// ---------------- prep: dw/da/dv from dwdavg (ld 4096), k/v from bigOut ------
__global__ __launch_bounds__(256) void prep_kernel(
    const float* __restrict__ kraw, const float* __restrict__ dw,
    const float* __restrict__ da, const float* __restrict__ dv,
    const float* __restrict__ vraw, const float* __restrict__ vfirst,
    const float* __restrict__ w0, const float* __restrict__ a0,
    const float* __restrict__ v0, const float* __restrict__ k_k,
    const float* __restrict__ k_a,
    float* __restrict__ decay, float* __restrict__ kfin, float* __restrict__ vfin,
    float* __restrict__ Ak, float* __restrict__ Bk) {
  int row = blockIdx.x; int tid = threadIdx.x; int c = tid*4;
  size_t off = (size_t)row*Cc + c;
  size_t offw = (size_t)row*BIGN + c;
  size_t offd = (size_t)row*BIGW + c;
  float4 kr = *(const float4*)(kraw+offw);
  float4 vr = *(const float4*)(vraw+offw);
  float4 w4 = *(const float4*)(dw+offd);
  float4 A4 = *(const float4*)(da+offd);
  float4 V4 = *(const float4*)(dv+offd);
  float4 vf = *(const float4*)(vfirst+off);
  float4 w04 = *(const float4*)(w0+c);
  float4 a04 = *(const float4*)(a0+c);
  float4 v04 = *(const float4*)(v0+c);
  float4 kk4 = *(const float4*)(k_k+c);
  float4 ka4 = *(const float4*)(k_a+c);
  float krl[4]={kr.x,kr.y,kr.z,kr.w};
  float dwl[4]={w4.x,w4.y,w4.z,w4.w};
  float dal[4]={A4.x,A4.y,A4.z,A4.w};
  float dvl[4]={V4.x,V4.y,V4.z,V4.w};
  float vrl[4]={vr.x,vr.y,vr.z,vr.w};
  float vfl[4]={vf.x,vf.y,vf.z,vf.w};
  float w0l[4]={w04.x,w04.y,w04.z,w04.w};
  float a0l[4]={a04.x,a04.y,a04.z,a04.w};
  float v0l[4]={v04.x,v04.y,v04.z,v04.w};
  float kkl[4]={kk4.x,kk4.y,kk4.z,kk4.w};
  float kal[4]={ka4.x,ka4.y,ka4.z,ka4.w};
  float av[4], dec[4], vv[4], kp[4], kf[4];
  float ss = 0.f;
  #pragma unroll
  for (int q=0;q<4;++q){
    av[q] = sgm(a0l[q] + dal[q]);
    dec[q] = 0.60653065971263342f * sgm(w0l[q] + dwl[q]);   // exp(-softplus(-u)-0.5)
    float sv = sgm(v0l[q] + dvl[q]);
    vv[q] = vrl[q] + (vfl[q]-vrl[q])*sv;
    kp[q] = krl[q]*kkl[q];
    ss += kp[q]*kp[q];
    kf[q] = krl[q]*(1.0f + (av[q]-1.0f)*kal[q]);
  }
  ss = redgrp<8>(ss);
  float inv = 1.0f / fmaxf(sqrtf(ss), 1e-12f);
  float4 o;
  o.x=dec[0];o.y=dec[1];o.z=dec[2];o.w=dec[3];  *(float4*)(decay+off)=o;
  o.x=kf[0]; o.y=kf[1]; o.z=kf[2]; o.w=kf[3];   *(float4*)(kfin+off)=o;
  o.x=vv[0]; o.y=vv[1]; o.z=vv[2]; o.w=vv[3];   *(float4*)(vfin+off)=o;
  o.x=-kp[0]*inv; o.y=-kp[1]*inv; o.z=-kp[2]*inv; o.w=-kp[3]*inv; *(float4*)(Ak+off)=o;
  o.x=kp[0]*inv*av[0]; o.y=kp[1]*inv*av[1]; o.z=kp[2]*inv*av[2]; o.w=kp[3]*inv*av[3];
  *(float4*)(Bk+off)=o;
}

// ===== WKV-7 warmup-chunked scan (decay<=e^-0.5 => 32-step influence ~1e-7)
// 512 blocks (32 bh x 16 chunks), 256 thr = 4 waves; thread owns 4 rows x 4
// cols. 4 waves (not 8) halves the duplicated per-step LDS broadcast reads.
__global__ __launch_bounds__(256) void wkv_kernel(
    const float* __restrict__ decay, const float* __restrict__ Ak,
    const float* __restrict__ Bk, const float* __restrict__ kfin,
    const float* __restrict__ r_, const float* __restrict__ vfin,
    const float* __restrict__ S0, float* __restrict__ y) {
  __shared__ float lds[2][6][CH][64];
  int bid = blockIdx.x;
  int bh = bid & 31, c = bid >> 5;
  int bb = bh >> 4, h = bh & 15;
  int tid = threadIdx.x;
  int wave = tid >> 6, lane = tid & 63;
  int rg = tid >> 4;                  // 0..15
  int bj = tid & 15, j0 = bj*4;
  float S0r[4], S1r[4], S2r[4], S3r[4];
  #pragma unroll
  for (int q=0;q<4;++q){ S0r[q]=0.f; S1r[q]=0.f; S2r[q]=0.f; S3r[q]=0.f; }
  if (c == 0) {
    float4 t0 = *(const float4*)(S0 + (size_t)bh*4096 + (rg+ 0)*64 + j0);
    float4 t1 = *(const float4*)(S0 + (size_t)bh*4096 + (rg+16)*64 + j0);
    float4 t2 = *(const float4*)(S0 + (size_t)bh*4096 + (rg+32)*64 + j0);
    float4 t3 = *(const float4*)(S0 + (size_t)bh*4096 + (rg+48)*64 + j0);
    S0r[0]=t0.x; S0r[1]=t0.y; S0r[2]=t0.z; S0r[3]=t0.w;
    S1r[0]=t1.x; S1r[1]=t1.y; S1r[2]=t1.z; S1r[3]=t1.w;
    S2r[0]=t2.x; S2r[1]=t2.y; S2r[2]=t2.z; S2r[3]=t2.w;
    S3r[0]=t3.x; S3r[1]=t3.y; S3r[2]=t3.z; S3r[3]=t3.w;
  }
  size_t seqb = (size_t)bb*Tt;
  int t0g = (c==0) ? 0 : (c*CL - WU);
  int NPH = (c==0) ? (CL/CH) : ((CL+WU)/CH);
  int phE = (c==0) ? 0 : (WU/CH);
  int lhi = lane >> 4, llo4 = (lane & 15)*4;

  #define WST1(buf, stepb, arr, base, ldv) { \
    const float* gp_ = (base) + (size_t)(seqb + (size_t)(stepb) + lhi)*(ldv) + h*64 + llo4; \
    _Pragma("unroll") \
    for (int p_=0; p_<4; ++p_) \
      gload16(gp_ + (size_t)p_*4*(ldv), &lds[buf][arr][p_*4][0]); }
  #define WSTAGE(buf, stepb) { \
    if (wave==0)      { WST1(buf, stepb, 0, decay, Cc) WST1(buf, stepb, 1, Ak, Cc) } \
    else if (wave==1) { WST1(buf, stepb, 2, Bk, Cc)   WST1(buf, stepb, 3, kfin, Cc) } \
    else if (wave==2) { WST1(buf, stepb, 4, r_, BIGN) } \
    else              { WST1(buf, stepb, 5, vfin, Cc) } }

  WSTAGE(0, t0g);
  for (int ph = 0; ph < NPH; ++ph) {
    int cur = ph & 1;
    if (ph+1 < NPH) {
      WSTAGE(cur^1, t0g + (ph+1)*CH);
      if (wave < 2) asm volatile("s_waitcnt vmcnt(8)" ::: "memory");
      else          asm volatile("s_waitcnt vmcnt(4)" ::: "memory");
      asm volatile("s_barrier" ::: "memory");
    } else {
      asm volatile("s_waitcnt vmcnt(0)\n\ts_barrier" ::: "memory");
    }
    bool emit = (ph >= phE);
    const float* L0 = &lds[cur][0][0][0];
    #pragma unroll
    for (int s = 0; s < CH; ++s) {
      const float* bp = L0 + s*64;
      float4 d4 = *(const float4*)(bp + 0*CH*64 + j0);
      float4 a4 = *(const float4*)(bp + 1*CH*64 + j0);
      float4 b4 = *(const float4*)(bp + 2*CH*64 + j0);
      float4 k4 = *(const float4*)(bp + 3*CH*64 + j0);
      float4 r4 = *(const float4*)(bp + 4*CH*64 + j0);
      float v0 = bp[5*CH*64 + rg];
      float v1 = bp[5*CH*64 + rg+16];
      float v2 = bp[5*CH*64 + rg+32];
      float v3 = bp[5*CH*64 + rg+48];
      S0r[0]*=d4.x; S0r[1]*=d4.y; S0r[2]*=d4.z; S0r[3]*=d4.w;
      S1r[0]*=d4.x; S1r[1]*=d4.y; S1r[2]*=d4.z; S1r[3]*=d4.w;
      S2r[0]*=d4.x; S2r[1]*=d4.y; S2r[2]*=d4.z; S2r[3]*=d4.w;
      S3r[0]*=d4.x; S3r[1]*=d4.y; S3r[2]*=d4.z; S3r[3]*=d4.w;
      float sa0 = fmaf(S0r[0],a4.x, S0r[1]*a4.y) + fmaf(S0r[2],a4.z, S0r[3]*a4.w);
      float sa1 = fmaf(S1r[0],a4.x, S1r[1]*a4.y) + fmaf(S1r[2],a4.z, S1r[3]*a4.w);
      float sa2 = fmaf(S2r[0],a4.x, S2r[1]*a4.y) + fmaf(S2r[2],a4.z, S2r[3]*a4.w);
      float sa3 = fmaf(S3r[0],a4.x, S3r[1]*a4.y) + fmaf(S3r[2],a4.z, S3r[3]*a4.w);
      sa0 = red16(sa0); sa1 = red16(sa1); sa2 = red16(sa2); sa3 = red16(sa3);
      S0r[0]=fmaf(v0,k4.x,S0r[0]); S0r[1]=fmaf(v0,k4.y,S0r[1]);
      S0r[2]=fmaf(v0,k4.z,S0r[2]); S0r[3]=fmaf(v0,k4.w,S0r[3]);
      S0r[0]=fmaf(sa0,b4.x,S0r[0]); S0r[1]=fmaf(sa0,b4.y,S0r[1]);
      S0r[2]=fmaf(sa0,b4.z,S0r[2]); S0r[3]=fmaf(sa0,b4.w,S0r[3]);
      S1r[0]=fmaf(v1,k4.x,S1r[0]); S1r[1]=fmaf(v1,k4.y,S1r[1]);
      S1r[2]=fmaf(v1,k4.z,S1r[2]); S1r[3]=fmaf(v1,k4.w,S1r[3]);
      S1r[0]=fmaf(sa1,b4.x,S1r[0]); S1r[1]=fmaf(sa1,b4.y,S1r[1]);
      S1r[2]=fmaf(sa1,b4.z,S1r[2]); S1r[3]=fmaf(sa1,b4.w,S1r[3]);
      S2r[0]=fmaf(v2,k4.x,S2r[0]); S2r[1]=fmaf(v2,k4.y,S2r[1]);
      S2r[2]=fmaf(v2,k4.z,S2r[2]); S2r[3]=fmaf(v2,k4.w,S2r[3]);
      S2r[0]=fmaf(sa2,b4.x,S2r[0]); S2r[1]=fmaf(sa2,b4.y,S2r[1]);
      S2r[2]=fmaf(sa2,b4.z,S2r[2]); S2r[3]=fmaf(sa2,b4.w,S2r[3]);
      S3r[0]=fmaf(v3,k4.x,S3r[0]); S3r[1]=fmaf(v3,k4.y,S3r[1]);
      S3r[2]=fmaf(v3,k4.z,S3r[2]); S3r[3]=fmaf(v3,k4.w,S3r[3]);
      S3r[0]=fmaf(sa3,b4.x,S3r[0]); S3r[1]=fmaf(sa3,b4.y,S3r[1]);
      S3r[2]=fmaf(sa3,b4.z,S3r[2]); S3r[3]=fmaf(sa3,b4.w,S3r[3]);
      if (emit) {
        float y0 = fmaf(S0r[0],r4.x, S0r[1]*r4.y) + fmaf(S0r[2],r4.z, S0r[3]*r4.w);
        float y1 = fmaf(S1r[0],r4.x, S1r[1]*r4.y) + fmaf(S1r[2],r4.z, S1r[3]*r4.w);
        float y2 = fmaf(S2r[0],r4.x, S2r[1]*r4.y) + fmaf(S2r[2],r4.z, S2r[3]*r4.w);
        float y3 = fmaf(S3r[0],r4.x, S3r[1]*r4.y) + fmaf(S3r[2],r4.z, S3r[3]*r4.w);
        y0 = red16(y0); y1 = red16(y1); y2 = red16(y2); y3 = red16(y3);
        if (bj == 0) {
          size_t yo = (seqb + (size_t)t0g + ph*CH + s)*Cc + h*64;
          y[yo + rg     ] = y0;
          y[yo + rg + 16] = y1;
          y[yo + rg + 32] = y2;
          y[yo + rg + 48] = y3;
        }
      }
    }
    asm volatile("s_barrier" ::: "memory");
  }
  #undef WSTAGE
  #undef WST1
}

// ---------------- GroupNorm(head) + r.k.r_k bonus + *g -> bf16 ---------------
__global__ __launch_bounds__(256) void gn_kernel(
    const float* __restrict__ y, const float* __restrict__ r_,
    const float* __restrict__ kfin, const float* __restrict__ vfin,
    const float* __restrict__ g_, const float* __restrict__ lnxw,
    const float* __restrict__ lnxb, const float* __restrict__ r_k,
    u16* __restrict__ Ao) {
  int row = blockIdx.x; int tid = threadIdx.x; int c = tid*4;
  size_t off = (size_t)row*Cc + c;
  float4 y4 = *(const float4*)(y+off);
  float s = y4.x+y4.y+y4.z+y4.w;
  float q = y4.x*y4.x+y4.y*y4.y+y4.z*y4.z+y4.w*y4.w;
  s = redgrp<8>(s); q = redgrp<8>(q);
  float mu = s*(1.0f/64.0f);
  float var = q*(1.0f/64.0f) - mu*mu;
  float rn = rsqrtf(var + 64e-5f);
  float4 rr = *(const float4*)(r_ + (size_t)row*BIGN + c);
  float4 kk = *(const float4*)(kfin+off);
  float4 vv = *(const float4*)(vfin+off);
  float4 gg = *(const float4*)(g_ + (size_t)row*BIGW + c);
  int h = tid >> 4; int hs = (tid & 15)*4;
  float4 rk = *(const float4*)(r_k + h*64 + hs);
  float dp = rr.x*kk.x*rk.x + rr.y*kk.y*rk.y + rr.z*kk.z*rk.z + rr.w*kk.w*rk.w;
  dp = redgrp<8>(dp);
  float4 w4 = *(const float4*)(lnxw+c);
  float4 b4 = *(const float4*)(lnxb+c);
  float o0 = (((y4.x-mu)*rn)*w4.x + b4.x + dp*vv.x) * gg.x;
  float o1 = (((y4.y-mu)*rn)*w4.y + b4.y + dp*vv.y) * gg.y;
  float o2 = (((y4.z-mu)*rn)*w4.z + b4.z + dp*vv.z) * gg.z;
  float o3 = (((y4.w-mu)*rn)*w4.w + b4.w + dp*vv.w) * gg.w;
  uint2 p = {pack_bf16(o0,o1), pack_bf16(o2,o3)};
  *(uint2*)(Ao + off) = p;
}

__global__ __launch_bounds__(256) void copy_kernel(const float* __restrict__ src,
                                                   float* __restrict__ dst) {
  size_t i = ((size_t)blockIdx.x*256 + threadIdx.x)*4;
  *(float4*)(dst+i) = *(const float4*)(src+i);
}

extern "C" void kernel_launch(void* const* d_in, const int* in_sizes, int n_in,
                              void* d_out, int out_size, void* d_ws, size_t ws_size,
                              hipStream_t stream) {
  const float* x      = (const float*)d_in[0];
  const float* vfirst = (const float*)d_in[1];
  const float* S0     = (const float*)d_in[2];
  const float* ln1w   = (const float*)d_in[3];
  const float* ln1b   = (const float*)d_in[4];
  const float* ln2w   = (const float*)d_in[5];
  const float* ln2b   = (const float*)d_in[6];
  const float* x_r    = (const float*)d_in[7];
  const float* x_w    = (const float*)d_in[8];
  const float* x_k    = (const float*)d_in[9];
  const float* x_v    = (const float*)d_in[10];
  const float* x_a    = (const float*)d_in[11];
  const float* x_g    = (const float*)d_in[12];
  const float* w0     = (const float*)d_in[13];
  const float* w1     = (const float*)d_in[14];
  const float* w2     = (const float*)d_in[15];
  const float* a0     = (const float*)d_in[16];
  const float* a1     = (const float*)d_in[17];
  const float* a2     = (const float*)d_in[18];
  const float* v0     = (const float*)d_in[19];
  const float* v1     = (const float*)d_in[20];
  const float* v2     = (const float*)d_in[21];
  const float* g1     = (const float*)d_in[22];
  const float* g2     = (const float*)d_in[23];
  const float* k_k    = (const float*)d_in[24];
  const float* k_a    = (const float*)d_in[25];
  const float* r_k    = (const float*)d_in[26];
  const float* W_r    = (const float*)d_in[27];
  const float* W_k    = (const float*)d_in[28];
  const float* W_v    = (const float*)d_in[29];
  const float* W_o    = (const float*)d_in[30];
  const float* lnxw   = (const float*)d_in[31];
  const float* lnxb   = (const float*)d_in[32];
  const float* mixk   = (const float*)d_in[33];
  const float* Wkey   = (const float*)d_in[34];
  const float* Wval   = (const float*)d_in[35];
  float* out = (float*)d_out;
  float* ws  = (float*)d_ws;
  const size_t U = (size_t)BT * Cc;
  float* u[14];
  for (int i=0;i<14;++i) u[i] = ws + i*U;

  u16* bigA   = (u16*)u[0];
  u16* BigB   = (u16*)u[1];
  float* bigOut = u[2];     // [4096][3456] f32 (u2..u5)
  float* dwdavg = u[6];     // [4096][4096] f32 (u6..u9)
  u16* W2blk  = (u16*)u[10];
  u16* loraAct= (u16*)u[11];
  float* Bk   = u[0];
  float* y_   = u[1];
  u16* gnb    = (u16*)u[10];
  u16* Wob    = (u16*)u[13];
  float* xo   = u[0];
  u16* Wkeyb  = (u16*)u[6];
  u16* cmb    = (u16*)u[7];
  u16* Wvalb  = (u16*)u[8];
  u16* midb   = (u16*)u[2];

  dim3 b256(256);
  packW_kernel<<<dim3(Cc,3), b256, 0, stream>>>(W_r, W_k, W_v, x_r, x_k, x_v, BigB);
  packL_kernel<<<320, b256, 0, stream>>>(w1, a1, v1, g1, x_w, x_a, x_v, x_g, BigB);
  packW2_kernel<<<BIGW, dim3(320), 0, stream>>>(w2, a2, v2, g2, W2blk);
  lnmix1_kernel<<<BT, b256, 0, stream>>>(x, ln1w, ln1b, bigA);
  gemm_bf16<0><<<(BT/128)*(BIGN/128), b256, 0, stream>>>(bigA, BigB, bigOut, nullptr, BT, BIGN, BIGK);
  actcvt_kernel<<<BT, dim3(320), 0, stream>>>(bigOut, loraAct);
  gemm_bf16<0><<<(BT/128)*(BIGW/128), b256, 0, stream>>>(loraAct, W2blk, dwdavg, nullptr, BT, BIGW, LORAK);
  prep_kernel<<<BT, b256, 0, stream>>>(bigOut+1024, dwdavg, dwdavg+1024, dwdavg+2048,
      bigOut+2048, vfirst, w0, a0, v0, k_k, k_a, u[10], u[11], u[12], u[13], Bk);
  wkv_kernel<<<32*(Tt/CL), b256, 0, stream>>>(u[10], u[13], Bk, u[11], bigOut, u[12], S0, y_);
  gn_kernel<<<BT, b256, 0, stream>>>(y_, bigOut, u[11], u[12], dwdavg+3072, lnxw, lnxb, r_k, gnb);
  // all three weight converts in one dispatch (u13/u6/u8 free after wkv+gn)
  cvtall_kernel<<<(Cc*Cc + FFNd*Cc*2)/2048, b256, 0, stream>>>(W_o, Wob, Wkey, Wkeyb, Wval, Wvalb);
  gemm_bf16<1><<<(BT/128)*(Cc/128), b256, 0, stream>>>(gnb, Wob, xo, x, BT, Cc, Cc);
  lnmix2_kernel<<<BT, b256, 0, stream>>>(xo, ln2w, ln2b, mixk, cmb);
  gemm_bf16<2><<<(BT/128)*(FFNd/128), b256, 0, stream>>>(cmb, Wkeyb, midb, nullptr, BT, FFNd, Cc);
  gemm_bf16<1><<<(BT/128)*(Cc/128), b256, 0, stream>>>(midb, Wvalb, out, xo, BT, Cc, FFNd);
  copy_kernel<<<BT*Cc/1024, b256, 0, stream>>>(vfirst, out + (size_t)BT*Cc);
}

// Round 15
// 408.173 us; speedup vs baseline: 1.0775x; 1.0267x over previous
//
#include <hip/hip_runtime.h>
#include <math.h>

#define Bb 2
#define Tt 2048
#define Cc 1024
#define Hh 16
#define BT 4096
#define FFNd 4096
#define CH 16
#define CL 128
#define WU 32
#define BIGN 3456
#define BIGK 2048
#define LORAK 320
#define BIGW 4096
// big-B column layout: r@0 k@1024 v@2048 w@3072 a@3136 vl@3200 g@3232 (end 3392, pad->3456)
// dwdavg column layout: dw@0 da@1024 dv@2048 g@3072  (ld 4096)

typedef __attribute__((ext_vector_type(8))) short bf16x8;
typedef __attribute__((ext_vector_type(4))) float f32x4;
typedef unsigned short u16;

__device__ __forceinline__ float sgm(float x){ return 1.0f/(1.0f+expf(-x)); }

template<int MAXM>
__device__ __forceinline__ float redgrp(float v){
  #pragma unroll
  for (int m=1; m<=MAXM; m<<=1) v += __shfl_xor(v, m, 64);
  return v;
}

template<int CTRL>
__device__ __forceinline__ float dppadd(float v){
  union { float f; int i; } u, r;
  u.f = v;
  r.i = __builtin_amdgcn_update_dpp(u.i, u.i, CTRL, 0xf, 0xf, true);
  return v + r.f;
}
__device__ __forceinline__ float red16(float v){
  v = dppadd<0xB1>(v);
  v = dppadd<0x4E>(v);
  v = dppadd<0x141>(v);
  v = dppadd<0x140>(v);
  return v;
}

__device__ __forceinline__ unsigned pack_bf16(float a, float b){
  unsigned ua = __builtin_bit_cast(unsigned, a);
  unsigned ub = __builtin_bit_cast(unsigned, b);
  ua = (ua + 0x7FFFu + ((ua>>16)&1u)) >> 16;
  ub = (ub + 0x7FFFu + ((ub>>16)&1u)) >> 16;
  return ua | (ub<<16);
}
__device__ __forceinline__ u16 bf16_1(float a){
  unsigned ua = __builtin_bit_cast(unsigned, a);
  return (u16)((ua + 0x7FFFu + ((ua>>16)&1u)) >> 16);
}

__device__ __forceinline__ void gload16(const void* g, void* l){
  __builtin_amdgcn_global_load_lds(
    (const __attribute__((address_space(1))) unsigned int*)g,
    (__attribute__((address_space(3))) unsigned int*)l, 16, 0, 0);
}

// ------- fused f32->bf16 convert of three weights + v_first passthrough ------
__device__ __forceinline__ void cvt8(const float* __restrict__ in,
    u16* __restrict__ out, size_t i){
  float4 a = ((const float4*)in)[2*i];
  float4 b = ((const float4*)in)[2*i+1];
  uint4 o = {pack_bf16(a.x,a.y), pack_bf16(a.z,a.w),
             pack_bf16(b.x,b.y), pack_bf16(b.z,b.w)};
  ((uint4*)out)[i] = o;
}
__global__ __launch_bounds__(256) void cvtall_kernel(
    const float* __restrict__ wo, u16* __restrict__ wob,
    const float* __restrict__ wk, u16* __restrict__ wkb,
    const float* __restrict__ wv, u16* __restrict__ wvb,
    const float* __restrict__ csrc, float* __restrict__ cdst) {
  size_t i = (size_t)blockIdx.x*256 + threadIdx.x;
  const size_t NA = (size_t)Cc*Cc/8;       // 131072
  const size_t NB = (size_t)FFNd*Cc/8;     // 524288
  if (i < NA) cvt8(wo, wob, i);
  else if (i < NA+NB) cvt8(wk, wkb, i-NA);
  else if (i < NA+2*NB) cvt8(wv, wvb, i-NA-NB);
  else {
    size_t j = i - NA - 2*NB;              // 0..BT*Cc/8
    float4 a = ((const float4*)csrc)[2*j];
    float4 b = ((const float4*)csrc)[2*j+1];
    ((float4*)cdst)[2*j] = a;
    ((float4*)cdst)[2*j+1] = b;
  }
}

// ---------------- pack square weights into BigB rows: [W | diag(mix)W] -------
__global__ __launch_bounds__(256) void packW_kernel(const float* __restrict__ Wr,
    const float* __restrict__ Wk, const float* __restrict__ Wv,
    const float* __restrict__ xr, const float* __restrict__ xk,
    const float* __restrict__ xv, u16* __restrict__ out) {
  int which = blockIdx.y;
  const float* W   = which==0 ? Wr : (which==1 ? Wk : Wv);
  const float* mix = which==0 ? xr : (which==1 ? xk : xv);
  u16* o = out + (size_t)which*1024*BIGK;
  int n = blockIdx.x;             // 0..1023
  int c0 = threadIdx.x*8;         // 0..2040
  int ks = c0 & 1023;
  const float* src = W + (size_t)n*Cc + ks;
  float4 a = *(const float4*)src;
  float4 b = *(const float4*)(src+4);
  if (c0 >= 1024){
    float4 m0 = *(const float4*)(mix + ks);
    float4 m1 = *(const float4*)(mix + ks + 4);
    a.x*=m0.x; a.y*=m0.y; a.z*=m0.z; a.w*=m0.w;
    b.x*=m1.x; b.y*=m1.y; b.z*=m1.z; b.w*=m1.w;
  }
  uint4 ov = {pack_bf16(a.x,a.y), pack_bf16(a.z,a.w),
              pack_bf16(b.x,b.y), pack_bf16(b.z,b.w)};
  *(uint4*)(o + (size_t)n*BIGK + c0) = ov;
}

// ---------------- pack lora W1[C,D] (transposed) into BigB rows --------------
__global__ __launch_bounds__(256) void packL_kernel(const float* __restrict__ w1,
    const float* __restrict__ a1, const float* __restrict__ v1,
    const float* __restrict__ g1, const float* __restrict__ x_w,
    const float* __restrict__ x_a, const float* __restrict__ x_v,
    const float* __restrict__ x_g, u16* __restrict__ out) {
  int bid = blockIdx.x;           // 0..319
  const float* W1; const float* mix; int D, d, nbase;
  if (bid < 64)       { W1=w1; mix=x_w; D=64;  d=bid;     nbase=3072; }
  else if (bid < 128) { W1=a1; mix=x_a; D=64;  d=bid-64;  nbase=3136; }
  else if (bid < 160) { W1=v1; mix=x_v; D=32;  d=bid-128; nbase=3200; }
  else                { W1=g1; mix=x_g; D=160; d=bid-160; nbase=3232; }
  int k0 = threadIdx.x*8;
  float v[8];
  #pragma unroll
  for (int q=0;q<8;++q){
    int kk = k0+q;
    int ks = kk & 1023;
    float t = W1[(size_t)ks*D + d];
    if (kk >= 1024) t *= mix[ks];
    v[q] = t;
  }
  uint4 o = {pack_bf16(v[0],v[1]), pack_bf16(v[2],v[3]),
             pack_bf16(v[4],v[5]), pack_bf16(v[6],v[7])};
  *(uint4*)(out + (size_t)(nbase+d)*BIGK + k0) = o;
}

// --------- pack block-diagonal W2: out[n][k] bf16, n in [0,4096) k in [0,320)
__global__ __launch_bounds__(320) void packW2_kernel(const float* __restrict__ w2,
    const float* __restrict__ a2, const float* __restrict__ v2,
    const float* __restrict__ g2, u16* __restrict__ out) {
  int n = blockIdx.x; int k = threadIdx.x;
  int which = n >> 10, col = n & 1023;
  float v = 0.f;
  if (which==0)      { if (k < 64)              v = w2[(size_t)k*Cc + col]; }
  else if (which==1) { if (k >= 64 && k < 128)  v = a2[(size_t)(k-64)*Cc + col]; }
  else if (which==2) { if (k >= 128 && k < 160) v = v2[(size_t)(k-128)*Cc + col]; }
  else               { if (k >= 160)            v = g2[(size_t)(k-160)*Cc + col]; }
  out[(size_t)n*LORAK + k] = bf16_1(v);
}

// --------- act + cvt lora columns of bigOut -> loraAct bf16 [4096][320] ------
__global__ __launch_bounds__(320) void actcvt_kernel(const float* __restrict__ m,
    u16* __restrict__ loraAct) {
  int i = blockIdx.x; int cc = threadIdx.x;
  float v = m[(size_t)i*BIGN + 3072 + cc];
  if (cc < 64) v = tanhf(v);
  else if (cc >= 160) v = sgm(v);
  loraAct[(size_t)i*LORAK + cc] = bf16_1(v);
}

// ---------------- fused LN1 -> bigA = [xn | xx] bf16 -------------------------
__global__ __launch_bounds__(256) void lnmix1_kernel(const float* __restrict__ x,
    const float* __restrict__ w, const float* __restrict__ b,
    u16* __restrict__ bigA) {
  int rowg = blockIdx.x; int t = rowg & (Tt-1);
  int tid = threadIdx.x;
  size_t off = (size_t)rowg*Cc + tid*4;
  float4 vc = *(const float4*)(x + off);
  float4 vp = {0.f,0.f,0.f,0.f};
  if (t) vp = *(const float4*)(x + off - Cc);
  float sc = vc.x+vc.y+vc.z+vc.w;
  float qc = vc.x*vc.x+vc.y*vc.y+vc.z*vc.z+vc.w*vc.w;
  float sp = vp.x+vp.y+vp.z+vp.w;
  float qp = vp.x*vp.x+vp.y*vp.y+vp.z*vp.z+vp.w*vp.w;
  sc = redgrp<32>(sc); qc = redgrp<32>(qc);
  sp = redgrp<32>(sp); qp = redgrp<32>(qp);
  __shared__ float rbuf[4][4];
  int lane = tid & 63, wv = tid >> 6;
  if (lane==0){ rbuf[wv][0]=sc; rbuf[wv][1]=qc; rbuf[wv][2]=sp; rbuf[wv][3]=qp; }
  __syncthreads();
  sc = rbuf[0][0]+rbuf[1][0]+rbuf[2][0]+rbuf[3][0];
  qc = rbuf[0][1]+rbuf[1][1]+rbuf[2][1]+rbuf[3][1];
  sp = rbuf[0][2]+rbuf[1][2]+rbuf[2][2]+rbuf[3][2];
  qp = rbuf[0][3]+rbuf[1][3]+rbuf[2][3]+rbuf[3][3];
  float muc = sc*(1.0f/Cc), mup = sp*(1.0f/Cc);
  float rnc = rsqrtf(qc*(1.0f/Cc) - muc*muc + 1e-5f);
  float rnp = rsqrtf(qp*(1.0f/Cc) - mup*mup + 1e-5f);
  float4 w4 = *(const float4*)(w + tid*4);
  float4 b4 = *(const float4*)(b + tid*4);
  float vcl[4]={vc.x,vc.y,vc.z,vc.w};
  float vpl[4]={vp.x,vp.y,vp.z,vp.w};
  float wl[4]={w4.x,w4.y,w4.z,w4.w};
  float bl[4]={b4.x,b4.y,b4.z,b4.w};
  float xnc[4], xx[4];
  #pragma unroll
  for (int q=0;q<4;++q){
    xnc[q] = (vcl[q]-muc)*rnc*wl[q] + bl[q];
    float xnp = t ? ((vpl[q]-mup)*rnp*wl[q] + bl[q]) : 0.0f;
    xx[q] = xnp - xnc[q];
  }
  size_t ab = (size_t)rowg*BIGK + tid*4;
  uint2 p0 = {pack_bf16(xnc[0],xnc[1]), pack_bf16(xnc[2],xnc[3])};
  uint2 p1 = {pack_bf16(xx[0],xx[1]),   pack_bf16(xx[2],xx[3])};
  *(uint2*)(bigA + ab) = p0;
  *(uint2*)(bigA + ab + 1024) = p1;
}

// ---------------- fused LN2 + cmix -> bf16 -----------------------------------
__global__ __launch_bounds__(256) void lnmix2_kernel(const float* __restrict__ x,
    const float* __restrict__ w, const float* __restrict__ b,
    const float* __restrict__ mixk, u16* __restrict__ outb) {
  int rowg = blockIdx.x; int t = rowg & (Tt-1);
  int tid = threadIdx.x;
  size_t off = (size_t)rowg*Cc + tid*4;
  float4 vc = *(const float4*)(x + off);
  float4 vp = {0.f,0.f,0.f,0.f};
  if (t) vp = *(const float4*)(x + off - Cc);
  float sc = vc.x+vc.y+vc.z+vc.w;
  float qc = vc.x*vc.x+vc.y*vc.y+vc.z*vc.z+vc.w*vc.w;
  float sp = vp.x+vp.y+vp.z+vp.w;
  float qp = vp.x*vp.x+vp.y*vp.y+vp.z*vp.z+vp.w*vp.w;
  sc = redgrp<32>(sc); qc = redgrp<32>(qc);
  sp = redgrp<32>(sp); qp = redgrp<32>(qp);
  __shared__ float rbuf[4][4];
  int lane = tid & 63, wv = tid >> 6;
  if (lane==0){ rbuf[wv][0]=sc; rbuf[wv][1]=qc; rbuf[wv][2]=sp; rbuf[wv][3]=qp; }
  __syncthreads();
  sc = rbuf[0][0]+rbuf[1][0]+rbuf[2][0]+rbuf[3][0];
  qc = rbuf[0][1]+rbuf[1][1]+rbuf[2][1]+rbuf[3][1];
  sp = rbuf[0][2]+rbuf[1][2]+rbuf[2][2]+rbuf[3][2];
  qp = rbuf[0][3]+rbuf[1][3]+rbuf[2][3]+rbuf[3][3];
  float muc = sc*(1.0f/Cc), mup = sp*(1.0f/Cc);
  float rnc = rsqrtf(qc*(1.0f/Cc) - muc*muc + 1e-5f);
  float rnp = rsqrtf(qp*(1.0f/Cc) - mup*mup + 1e-5f);
  float4 w4 = *(const float4*)(w + tid*4);
  float4 b4 = *(const float4*)(b + tid*4);
  float4 m = *(const float4*)(mixk + tid*4);
  float vcl[4]={vc.x,vc.y,vc.z,vc.w};
  float vpl[4]={vp.x,vp.y,vp.z,vp.w};
  float wl[4]={w4.x,w4.y,w4.z,w4.w};
  float bl[4]={b4.x,b4.y,b4.z,b4.w};
  float ml[4]={m.x,m.y,m.z,m.w};
  float o[4];
  #pragma unroll
  for (int q=0;q<4;++q){
    float xnc = (vcl[q]-muc)*rnc*wl[q] + bl[q];
    float xnp = t ? ((vpl[q]-mup)*rnp*wl[q] + bl[q]) : 0.0f;
    o[q] = xnc + (xnp - xnc)*ml[q];
  }
  uint2 p = {pack_bf16(o[0],o[1]), pack_bf16(o[2],o[3])};
  *(uint2*)(outb + off) = p;
}

// ================= bf16 GEMM (m97 structure, 128x128 tile) ===================
// out = A[M,K] @ W[N,K]^T.  MODE 0: f32   1: f32 res+acc   2: bf16 relu(acc)^2
// T1 bijective XCD swizzle; T4 counted vmcnt(8); T2 both-sides XOR swizzle.
template<int MODE>
__global__ __launch_bounds__(256) void gemm_bf16(const u16* __restrict__ A,
    const u16* __restrict__ W, void* __restrict__ outv,
    const float* __restrict__ res, int M, int N, int K) {
  __shared__ u16 As[2][128*64];
  __shared__ u16 Bs[2][128*64];
  int tid = threadIdx.x;
  int nwg = gridDim.x;
  int q8 = nwg >> 3;
  int id = (blockIdx.x & 7)*q8 + (blockIdx.x >> 3);   // bijective (nwg%8==0)
  int nbx = N >> 7;
  int bm = id / nbx, bn = id - bm*nbx;                // bn fastest: A-panel per XCD
  int wave = tid >> 6, lane = tid & 63;
  int wm = wave >> 1, wn = wave & 1;
  int srow = wave*32 + (lane>>3);
  int scol = (((lane&7) ^ ((lane>>3)&7)))*8;          // T2 source pre-swizzle
  const u16* Ag = A + (size_t)(bm*128 + srow)*K + scol;
  const u16* Wg = W + (size_t)(bn*128 + srow)*K + scol;
  int nt = K >> 6;
  f32x4 acc[4][4];
  f32x4 zero = {0.f,0.f,0.f,0.f};
  #pragma unroll
  for (int i=0;i<4;++i)
    #pragma unroll
    for (int j=0;j<4;++j) acc[i][j] = zero;

  #define STAGE(buf, t) { \
    const u16* Ag2 = Ag + (size_t)(t)*64; \
    const u16* Wg2 = Wg + (size_t)(t)*64; \
    _Pragma("unroll") \
    for (int i_=0;i_<4;++i_){ \
      gload16(Ag2 + (size_t)i_*8*K, &As[buf][(wave*32+i_*8)*64]); \
      gload16(Wg2 + (size_t)i_*8*K, &Bs[buf][(wave*32+i_*8)*64]); \
    } }

  STAGE(0, 0);
  int lrow = lane & 15, lk8 = lane >> 4;
  int r7 = lrow & 7;
  for (int t = 0; t < nt; ++t) {
    int cur = t & 1;
    if (t+1 < nt) {
      STAGE(cur^1, t+1);
      asm volatile("s_waitcnt vmcnt(8)\n\ts_barrier" ::: "memory");
    } else {
      asm volatile("s_waitcnt vmcnt(0)\n\ts_barrier" ::: "memory");
    }
    #pragma unroll
    for (int kk2 = 0; kk2 < 2; ++kk2) {
      int sl = ((kk2*4 + lk8) ^ r7) * 8;
      bf16x8 af[4], bfr[4];
      #pragma unroll
      for (int i=0;i<4;++i)
        af[i] = *(const bf16x8*)&As[cur][(wm*64 + i*16 + lrow)*64 + sl];
      #pragma unroll
      for (int j=0;j<4;++j)
        bfr[j] = *(const bf16x8*)&Bs[cur][(wn*64 + j*16 + lrow)*64 + sl];
      #pragma unroll
      for (int i=0;i<4;++i)
        #pragma unroll
        for (int j=0;j<4;++j)
          acc[i][j] = __builtin_amdgcn_mfma_f32_16x16x32_bf16(af[i], bfr[j], acc[i][j], 0, 0, 0);
    }
    asm volatile("s_barrier" ::: "memory");
  }
  #undef STAGE
  float* outf = (float*)outv;
  u16* outb = (u16*)outv;
  int crow4 = (lane>>4)*4, ccol = lane & 15;
  #pragma unroll
  for (int i=0;i<4;++i){
    #pragma unroll
    for (int j=0;j<4;++j){
      int gr = bm*128 + wm*64 + i*16 + crow4;
      int gc = bn*128 + wn*64 + j*16 + ccol;
      #pragma unroll
      for (int q=0;q<4;++q){
        float v = acc[i][j][q];
        size_t o = (size_t)(gr+q)*N + gc;
        if (MODE==1) { v += res[o]; outf[o] = v; }
        else if (MODE==2) { v = fmaxf(v, 0.f); outb[o] = bf16_1(v*v); }
        else outf[o] = v;
      }
    }
  }
}

// ---------------- prep: dw/da/dv from dwdavg (ld 4096), k/v from bigOut ------
__global__ __launch_bounds__(256) void prep_kernel(
    const float* __restrict__ kraw, const float* __restrict__ dw,
    const float* __restrict__ da, const float* __restrict__ dv,
    const float* __restrict__ vraw, const float* __restrict__ vfirst,
    const float* __restrict__ w0, const float* __restrict__ a0,
    const float* __restrict__ v0, const float* __restrict__ k_k,
    const float* __restrict__ k_a,
    float* __restrict__ decay, float* __restrict__ kfin, float* __restrict__ vfin,
    float* __restrict__ Ak, float* __restrict__ Bk) {
  int row = blockIdx.x; int tid = threadIdx.x; int c = tid*4;
  size_t off = (size_t)row*Cc + c;
  size_t offw = (size_t)row*BIGN + c;
  size_t offd = (size_t)row*BIGW + c;
  float4 kr = *(const float4*)(kraw+offw);
  float4 vr = *(const float4*)(vraw+offw);
  float4 w4 = *(const float4*)(dw+offd);
  float4 A4 = *(const float4*)(da+offd);
  float4 V4 = *(const float4*)(dv+offd);
  float4 vf = *(const float4*)(vfirst+off);
  float4 w04 = *(const float4*)(w0+c);
  float4 a04 = *(const float4*)(a0+c);
  float4 v04 = *(const float4*)(v0+c);
  float4 kk4 = *(const float4*)(k_k+c);
  float4 ka4 = *(const float4*)(k_a+c);
  float krl[4]={kr.x,kr.y,kr.z,kr.w};
  float dwl[4]={w4.x,w4.y,w4.z,w4.w};
  float dal[4]={A4.x,A4.y,A4.z,A4.w};
  float dvl[4]={V4.x,V4.y,V4.z,V4.w};
  float vrl[4]={vr.x,vr.y,vr.z,vr.w};
  float vfl[4]={vf.x,vf.y,vf.z,vf.w};
  float w0l[4]={w04.x,w04.y,w04.z,w04.w};
  float a0l[4]={a04.x,a04.y,a04.z,a04.w};
  float v0l[4]={v04.x,v04.y,v04.z,v04.w};
  float kkl[4]={kk4.x,kk4.y,kk4.z,kk4.w};
  float kal[4]={ka4.x,ka4.y,ka4.z,ka4.w};
  float av[4], dec[4], vv[4], kp[4], kf[4];
  float ss = 0.f;
  #pragma unroll
  for (int q=0;q<4;++q){
    av[q] = sgm(a0l[q] + dal[q]);
    dec[q] = 0.60653065971263342f * sgm(w0l[q] + dwl[q]);   // exp(-softplus(-u)-0.5)
    float sv = sgm(v0l[q] + dvl[q]);
    vv[q] = vrl[q] + (vfl[q]-vrl[q])*sv;
    kp[q] = krl[q]*kkl[q];
    ss += kp[q]*kp[q];
    kf[q] = krl[q]*(1.0f + (av[q]-1.0f)*kal[q]);
  }
  ss = redgrp<8>(ss);
  float inv = 1.0f / fmaxf(sqrtf(ss), 1e-12f);
  float4 o;
  o.x=dec[0];o.y=dec[1];o.z=dec[2];o.w=dec[3];  *(float4*)(decay+off)=o;
  o.x=kf[0]; o.y=kf[1]; o.z=kf[2]; o.w=kf[3];   *(float4*)(kfin+off)=o;
  o.x=vv[0]; o.y=vv[1]; o.z=vv[2]; o.w=vv[3];   *(float4*)(vfin+off)=o;
  o.x=-kp[0]*inv; o.y=-kp[1]*inv; o.z=-kp[2]*inv; o.w=-kp[3]*inv; *(float4*)(Ak+off)=o;
  o.x=kp[0]*inv*av[0]; o.y=kp[1]*inv*av[1]; o.z=kp[2]*inv*av[2]; o.w=kp[3]*inv*av[3];
  *(float4*)(Bk+off)=o;
}

// ===== WKV-7 warmup-chunked scan (decay<=e^-0.5 => 32-step influence ~1e-7)
// 512 blocks (32 bh x 16 chunks), 512 thr = 8 waves; thread owns rows rg,rg+32.
__global__ __launch_bounds__(512) void wkv_kernel(
    const float* __restrict__ decay, const float* __restrict__ Ak,
    const float* __restrict__ Bk, const float* __restrict__ kfin,
    const float* __restrict__ r_, const float* __restrict__ vfin,
    const float* __restrict__ S0, float* __restrict__ y) {
  __shared__ float lds[2][6][CH][64];
  int bid = blockIdx.x;
  int bh = bid & 31, c = bid >> 5;
  int bb = bh >> 4, h = bh & 15;
  int tid = threadIdx.x;
  int wave = tid >> 6, lane = tid & 63;
  int rg = tid >> 4;                  // 0..31
  int bj = tid & 15, j0 = bj*4;
  int r0 = rg, r1 = rg + 32;
  float Sa_[4] = {0.f,0.f,0.f,0.f};
  float Sb_[4] = {0.f,0.f,0.f,0.f};
  if (c == 0) {
    float4 t0 = *(const float4*)(S0 + (size_t)bh*4096 + r0*64 + j0);
    float4 t1 = *(const float4*)(S0 + (size_t)bh*4096 + r1*64 + j0);
    Sa_[0]=t0.x; Sa_[1]=t0.y; Sa_[2]=t0.z; Sa_[3]=t0.w;
    Sb_[0]=t1.x; Sb_[1]=t1.y; Sb_[2]=t1.z; Sb_[3]=t1.w;
  }
  size_t seqb = (size_t)bb*Tt;
  int t0g = (c==0) ? 0 : (c*CL - WU);
  int NPH = (c==0) ? (CL/CH) : ((CL+WU)/CH);
  int phE = (c==0) ? 0 : (WU/CH);
  int lhi = lane >> 4, llo4 = (lane & 15)*4;

  #define WST1(buf, stepb, arr, base, ldv) { \
    const float* gp_ = (base) + (size_t)(seqb + (size_t)(stepb) + lhi)*(ldv) + h*64 + llo4; \
    _Pragma("unroll") \
    for (int p_=0; p_<4; ++p_) \
      gload16(gp_ + (size_t)p_*4*(ldv), &lds[buf][arr][p_*4][0]); }
  #define WSTAGE(buf, stepb) { \
    if (wave==0)      { WST1(buf, stepb, 0, decay, Cc) } \
    else if (wave==1) { WST1(buf, stepb, 1, Ak, Cc) } \
    else if (wave==2) { WST1(buf, stepb, 2, Bk, Cc) } \
    else if (wave==3) { WST1(buf, stepb, 3, kfin, Cc) } \
    else if (wave==4) { WST1(buf, stepb, 4, r_, BIGN) } \
    else if (wave==5) { WST1(buf, stepb, 5, vfin, Cc) } }

  WSTAGE(0, t0g);
  for (int ph = 0; ph < NPH; ++ph) {
    int cur = ph & 1;
    if (ph+1 < NPH) {
      WSTAGE(cur^1, t0g + (ph+1)*CH);
      asm volatile("s_waitcnt vmcnt(4)\n\ts_barrier" ::: "memory");
    } else {
      asm volatile("s_waitcnt vmcnt(0)\n\ts_barrier" ::: "memory");
    }
    bool emit = (ph >= phE);
    const float* L0 = &lds[cur][0][0][0];
    #pragma unroll
    for (int s = 0; s < CH; ++s) {
      const float* bp = L0 + s*64;
      float4 d4 = *(const float4*)(bp + 0*CH*64 + j0);
      float4 a4 = *(const float4*)(bp + 1*CH*64 + j0);
      float4 b4 = *(const float4*)(bp + 2*CH*64 + j0);
      float4 k4 = *(const float4*)(bp + 3*CH*64 + j0);
      float4 r4 = *(const float4*)(bp + 4*CH*64 + j0);
      float v0 = bp[5*CH*64 + r0];
      float v1 = bp[5*CH*64 + r1];
      Sa_[0]*=d4.x; Sa_[1]*=d4.y; Sa_[2]*=d4.z; Sa_[3]*=d4.w;
      Sb_[0]*=d4.x; Sb_[1]*=d4.y; Sb_[2]*=d4.z; Sb_[3]*=d4.w;
      float sa0 = fmaf(Sa_[0],a4.x, Sa_[1]*a4.y) + fmaf(Sa_[2],a4.z, Sa_[3]*a4.w);
      float sa1 = fmaf(Sb_[0],a4.x, Sb_[1]*a4.y) + fmaf(Sb_[2],a4.z, Sb_[3]*a4.w);
      sa0 = red16(sa0);
      sa1 = red16(sa1);
      Sa_[0]=fmaf(v0,k4.x,Sa_[0]); Sa_[1]=fmaf(v0,k4.y,Sa_[1]);
      Sa_[2]=fmaf(v0,k4.z,Sa_[2]); Sa_[3]=fmaf(v0,k4.w,Sa_[3]);
      Sa_[0]=fmaf(sa0,b4.x,Sa_[0]); Sa_[1]=fmaf(sa0,b4.y,Sa_[1]);
      Sa_[2]=fmaf(sa0,b4.z,Sa_[2]); Sa_[3]=fmaf(sa0,b4.w,Sa_[3]);
      Sb_[0]=fmaf(v1,k4.x,Sb_[0]); Sb_[1]=fmaf(v1,k4.y,Sb_[1]);
      Sb_[2]=fmaf(v1,k4.z,Sb_[2]); Sb_[3]=fmaf(v1,k4.w,Sb_[3]);
      Sb_[0]=fmaf(sa1,b4.x,Sb_[0]); Sb_[1]=fmaf(sa1,b4.y,Sb_[1]);
      Sb_[2]=fmaf(sa1,b4.z,Sb_[2]); Sb_[3]=fmaf(sa1,b4.w,Sb_[3]);
      if (emit) {
        float y0 = fmaf(Sa_[0],r4.x, Sa_[1]*r4.y) + fmaf(Sa_[2],r4.z, Sa_[3]*r4.w);
        float y1 = fmaf(Sb_[0],r4.x, Sb_[1]*r4.y) + fmaf(Sb_[2],r4.z, Sb_[3]*r4.w);
        y0 = red16(y0);
        y1 = red16(y1);
        if (bj == 0) {
          size_t yo = (seqb + (size_t)t0g + ph*CH + s)*Cc + h*64;
          y[yo + r0] = y0;
          y[yo + r1] = y1;
        }
      }
    }
    asm volatile("s_barrier" ::: "memory");
  }
  #undef WSTAGE
  #undef WST1
}

// ---------------- GroupNorm(head) + r.k.r_k bonus + *g -> bf16 ---------------
__global__ __launch_bounds__(256) void gn_kernel(
    const float* __restrict__ y, const float* __restrict__ r_,
    const float* __restrict__ kfin, const float* __restrict__ vfin,
    const float* __restrict__ g_, const float* __restrict__ lnxw,
    const float* __restrict__ lnxb, const float* __restrict__ r_k,
    u16* __restrict__ Ao) {
  int row = blockIdx.x; int tid = threadIdx.x; int c = tid*4;
  size_t off = (size_t)row*Cc + c;
  float4 y4 = *(const float4*)(y+off);
  float s = y4.x+y4.y+y4.z+y4.w;
  float q = y4.x*y4.x+y4.y*y4.y+y4.z*y4.z+y4.w*y4.w;
  s = redgrp<8>(s); q = redgrp<8>(q);
  float mu = s*(1.0f/64.0f);
  float var = q*(1.0f/64.0f) - mu*mu;
  float rn = rsqrtf(var + 64e-5f);
  float4 rr = *(const float4*)(r_ + (size_t)row*BIGN + c);
  float4 kk = *(const float4*)(kfin+off);
  float4 vv = *(const float4*)(vfin+off);
  float4 gg = *(const float4*)(g_ + (size_t)row*BIGW + c);
  int h = tid >> 4; int hs = (tid & 15)*4;
  float4 rk = *(const float4*)(r_k + h*64 + hs);
  float dp = rr.x*kk.x*rk.x + rr.y*kk.y*rk.y + rr.z*kk.z*rk.z + rr.w*kk.w*rk.w;
  dp = redgrp<8>(dp);
  float4 w4 = *(const float4*)(lnxw+c);
  float4 b4 = *(const float4*)(lnxb+c);
  float o0 = (((y4.x-mu)*rn)*w4.x + b4.x + dp*vv.x) * gg.x;
  float o1 = (((y4.y-mu)*rn)*w4.y + b4.y + dp*vv.y) * gg.y;
  float o2 = (((y4.z-mu)*rn)*w4.z + b4.z + dp*vv.z) * gg.z;
  float o3 = (((y4.w-mu)*rn)*w4.w + b4.w + dp*vv.w) * gg.w;
  uint2 p = {pack_bf16(o0,o1), pack_bf16(o2,o3)};
  *(uint2*)(Ao + off) = p;
}

extern "C" void kernel_launch(void* const* d_in, const int* in_sizes, int n_in,
                              void* d_out, int out_size, void* d_ws, size_t ws_size,
                              hipStream_t stream) {
  const float* x      = (const float*)d_in[0];
  const float* vfirst = (const float*)d_in[1];
  const float* S0     = (const float*)d_in[2];
  const float* ln1w   = (const float*)d_in[3];
  const float* ln1b   = (const float*)d_in[4];
  const float* ln2w   = (const float*)d_in[5];
  const float* ln2b   = (const float*)d_in[6];
  const float* x_r    = (const float*)d_in[7];
  const float* x_w    = (const float*)d_in[8];
  const float* x_k    = (const float*)d_in[9];
  const float* x_v    = (const float*)d_in[10];
  const float* x_a    = (const float*)d_in[11];
  const float* x_g    = (const float*)d_in[12];
  const float* w0     = (const float*)d_in[13];
  const float* w1     = (const float*)d_in[14];
  const float* w2     = (const float*)d_in[15];
  const float* a0     = (const float*)d_in[16];
  const float* a1     = (const float*)d_in[17];
  const float* a2     = (const float*)d_in[18];
  const float* v0     = (const float*)d_in[19];
  const float* v1     = (const float*)d_in[20];
  const float* v2     = (const float*)d_in[21];
  const float* g1     = (const float*)d_in[22];
  const float* g2     = (const float*)d_in[23];
  const float* k_k    = (const float*)d_in[24];
  const float* k_a    = (const float*)d_in[25];
  const float* r_k    = (const float*)d_in[26];
  const float* W_r    = (const float*)d_in[27];
  const float* W_k    = (const float*)d_in[28];
  const float* W_v    = (const float*)d_in[29];
  const float* W_o    = (const float*)d_in[30];
  const float* lnxw   = (const float*)d_in[31];
  const float* lnxb   = (const float*)d_in[32];
  const float* mixk   = (const float*)d_in[33];
  const float* Wkey   = (const float*)d_in[34];
  const float* Wval   = (const float*)d_in[35];
  float* out = (float*)d_out;
  float* ws  = (float*)d_ws;
  const size_t U = (size_t)BT * Cc;
  float* u[14];
  for (int i=0;i<14;++i) u[i] = ws + i*U;

  u16* bigA   = (u16*)u[0];
  u16* BigB   = (u16*)u[1];
  float* bigOut = u[2];     // [4096][3456] f32 (u2..u5)
  float* dwdavg = u[6];     // [4096][4096] f32 (u6..u9)
  u16* W2blk  = (u16*)u[10];
  u16* loraAct= (u16*)u[11];
  float* Bk   = u[0];
  float* y_   = u[1];
  u16* gnb    = (u16*)u[10];
  u16* Wob    = (u16*)u[13];
  float* xo   = u[0];
  u16* Wkeyb  = (u16*)u[6];
  u16* cmb    = (u16*)u[7];
  u16* Wvalb  = (u16*)u[8];
  u16* midb   = (u16*)u[2];

  dim3 b256(256);
  packW_kernel<<<dim3(Cc,3), b256, 0, stream>>>(W_r, W_k, W_v, x_r, x_k, x_v, BigB);
  packL_kernel<<<320, b256, 0, stream>>>(w1, a1, v1, g1, x_w, x_a, x_v, x_g, BigB);
  packW2_kernel<<<BIGW, dim3(320), 0, stream>>>(w2, a2, v2, g2, W2blk);
  lnmix1_kernel<<<BT, b256, 0, stream>>>(x, ln1w, ln1b, bigA);
  gemm_bf16<0><<<(BT/128)*(BIGN/128), b256, 0, stream>>>(bigA, BigB, bigOut, nullptr, BT, BIGN, BIGK);
  actcvt_kernel<<<BT, dim3(320), 0, stream>>>(bigOut, loraAct);
  gemm_bf16<0><<<(BT/128)*(BIGW/128), b256, 0, stream>>>(loraAct, W2blk, dwdavg, nullptr, BT, BIGW, LORAK);
  prep_kernel<<<BT, b256, 0, stream>>>(bigOut+1024, dwdavg, dwdavg+1024, dwdavg+2048,
      bigOut+2048, vfirst, w0, a0, v0, k_k, k_a, u[10], u[11], u[12], u[13], Bk);
  wkv_kernel<<<32*(Tt/CL), dim3(512), 0, stream>>>(u[10], u[13], Bk, u[11], bigOut, u[12], S0, y_);
  gn_kernel<<<BT, b256, 0, stream>>>(y_, bigOut, u[11], u[12], dwdavg+3072, lnxw, lnxb, r_k, gnb);
  // three weight converts + v_first passthrough in one dispatch
  cvtall_kernel<<<(Cc*Cc + FFNd*Cc*2 + BT*Cc)/2048, b256, 0, stream>>>(
      W_o, Wob, Wkey, Wkeyb, Wval, Wvalb, vfirst, out + (size_t)BT*Cc);
  gemm_bf16<1><<<(BT/128)*(Cc/128), b256, 0, stream>>>(gnb, Wob, xo, x, BT, Cc, Cc);
  lnmix2_kernel<<<BT, b256, 0, stream>>>(xo, ln2w, ln2b, mixk, cmb);
  gemm_bf16<2><<<(BT/128)*(FFNd/128), b256, 0, stream>>>(cmb, Wkeyb, midb, nullptr, BT, FFNd, Cc);
  gemm_bf16<1><<<(BT/128)*(Cc/128), b256, 0, stream>>>(midb, Wvalb, out, xo, BT, Cc, FFNd);
}

// Round 16
// 394.248 us; speedup vs baseline: 1.1155x; 1.0353x over previous
//
#include <hip/hip_runtime.h>
#include <math.h>

#define Bb 2
#define Tt 2048
#define Cc 1024
#define Hh 16
#define BT 4096
#define FFNd 4096
#define CH 16
#define CL 128
#define WU 32
#define BIGN 3456
#define BIGK 2048
#define LORAK 320
#define BIGW 4096
// big-B column layout: r@0 k@1024 v@2048 w@3072 a@3136 vl@3200 g@3232 (end 3392, pad->3456)
// dwdavg column layout: dw@0 da@1024 dv@2048 g@3072  (ld 4096)

typedef __attribute__((ext_vector_type(8))) short bf16x8;
typedef __attribute__((ext_vector_type(4))) float f32x4;
typedef unsigned short u16;

__device__ __forceinline__ float sgm(float x){ return 1.0f/(1.0f+expf(-x)); }

template<int MAXM>
__device__ __forceinline__ float redgrp(float v){
  #pragma unroll
  for (int m=1; m<=MAXM; m<<=1) v += __shfl_xor(v, m, 64);
  return v;
}

template<int CTRL>
__device__ __forceinline__ float dppadd(float v){
  union { float f; int i; } u, r;
  u.f = v;
  r.i = __builtin_amdgcn_update_dpp(u.i, u.i, CTRL, 0xf, 0xf, true);
  return v + r.f;
}
__device__ __forceinline__ float red16(float v){
  v = dppadd<0xB1>(v);
  v = dppadd<0x4E>(v);
  v = dppadd<0x141>(v);
  v = dppadd<0x140>(v);
  return v;
}

__device__ __forceinline__ unsigned pack_bf16(float a, float b){
  unsigned ua = __builtin_bit_cast(unsigned, a);
  unsigned ub = __builtin_bit_cast(unsigned, b);
  ua = (ua + 0x7FFFu + ((ua>>16)&1u)) >> 16;
  ub = (ub + 0x7FFFu + ((ub>>16)&1u)) >> 16;
  return ua | (ub<<16);
}
__device__ __forceinline__ u16 bf16_1(float a){
  unsigned ua = __builtin_bit_cast(unsigned, a);
  return (u16)((ua + 0x7FFFu + ((ua>>16)&1u)) >> 16);
}

__device__ __forceinline__ void gload16(const void* g, void* l){
  __builtin_amdgcn_global_load_lds(
    (const __attribute__((address_space(1))) unsigned int*)g,
    (__attribute__((address_space(3))) unsigned int*)l, 16, 0, 0);
}

// ------- fused f32->bf16 convert of three weights + v_first passthrough ------
__device__ __forceinline__ void cvt8(const float* __restrict__ in,
    u16* __restrict__ out, size_t i){
  float4 a = ((const float4*)in)[2*i];
  float4 b = ((const float4*)in)[2*i+1];
  uint4 o = {pack_bf16(a.x,a.y), pack_bf16(a.z,a.w),
             pack_bf16(b.x,b.y), pack_bf16(b.z,b.w)};
  ((uint4*)out)[i] = o;
}
__global__ __launch_bounds__(256) void cvtall_kernel(
    const float* __restrict__ wo, u16* __restrict__ wob,
    const float* __restrict__ wk, u16* __restrict__ wkb,
    const float* __restrict__ wv, u16* __restrict__ wvb,
    const float* __restrict__ csrc, float* __restrict__ cdst) {
  size_t i = (size_t)blockIdx.x*256 + threadIdx.x;
  const size_t NA = (size_t)Cc*Cc/8;       // 131072
  const size_t NB = (size_t)FFNd*Cc/8;     // 524288
  if (i < NA) cvt8(wo, wob, i);
  else if (i < NA+NB) cvt8(wk, wkb, i-NA);
  else if (i < NA+2*NB) cvt8(wv, wvb, i-NA-NB);
  else {
    size_t j = i - NA - 2*NB;              // 0..BT*Cc/8
    float4 a = ((const float4*)csrc)[2*j];
    float4 b = ((const float4*)csrc)[2*j+1];
    ((float4*)cdst)[2*j] = a;
    ((float4*)cdst)[2*j+1] = b;
  }
}

// ---------------- pack square weights into BigB rows: [W | diag(mix)W] -------
__global__ __launch_bounds__(256) void packW_kernel(const float* __restrict__ Wr,
    const float* __restrict__ Wk, const float* __restrict__ Wv,
    const float* __restrict__ xr, const float* __restrict__ xk,
    const float* __restrict__ xv, u16* __restrict__ out) {
  int which = blockIdx.y;
  const float* W   = which==0 ? Wr : (which==1 ? Wk : Wv);
  const float* mix = which==0 ? xr : (which==1 ? xk : xv);
  u16* o = out + (size_t)which*1024*BIGK;
  int n = blockIdx.x;             // 0..1023
  int c0 = threadIdx.x*8;         // 0..2040
  int ks = c0 & 1023;
  const float* src = W + (size_t)n*Cc + ks;
  float4 a = *(const float4*)src;
  float4 b = *(const float4*)(src+4);
  if (c0 >= 1024){
    float4 m0 = *(const float4*)(mix + ks);
    float4 m1 = *(const float4*)(mix + ks + 4);
    a.x*=m0.x; a.y*=m0.y; a.z*=m0.z; a.w*=m0.w;
    b.x*=m1.x; b.y*=m1.y; b.z*=m1.z; b.w*=m1.w;
  }
  uint4 ov = {pack_bf16(a.x,a.y), pack_bf16(a.z,a.w),
              pack_bf16(b.x,b.y), pack_bf16(b.z,b.w)};
  *(uint4*)(o + (size_t)n*BIGK + c0) = ov;
}

// ---------------- pack lora W1[C,D] (transposed) into BigB rows --------------
__global__ __launch_bounds__(256) void packL_kernel(const float* __restrict__ w1,
    const float* __restrict__ a1, const float* __restrict__ v1,
    const float* __restrict__ g1, const float* __restrict__ x_w,
    const float* __restrict__ x_a, const float* __restrict__ x_v,
    const float* __restrict__ x_g, u16* __restrict__ out) {
  int bid = blockIdx.x;           // 0..319
  const float* W1; const float* mix; int D, d, nbase;
  if (bid < 64)       { W1=w1; mix=x_w; D=64;  d=bid;     nbase=3072; }
  else if (bid < 128) { W1=a1; mix=x_a; D=64;  d=bid-64;  nbase=3136; }
  else if (bid < 160) { W1=v1; mix=x_v; D=32;  d=bid-128; nbase=3200; }
  else                { W1=g1; mix=x_g; D=160; d=bid-160; nbase=3232; }
  int k0 = threadIdx.x*8;
  float v[8];
  #pragma unroll
  for (int q=0;q<8;++q){
    int kk = k0+q;
    int ks = kk & 1023;
    float t = W1[(size_t)ks*D + d];
    if (kk >= 1024) t *= mix[ks];
    v[q] = t;
  }
  uint4 o = {pack_bf16(v[0],v[1]), pack_bf16(v[2],v[3]),
             pack_bf16(v[4],v[5]), pack_bf16(v[6],v[7])};
  *(uint4*)(out + (size_t)(nbase+d)*BIGK + k0) = o;
}

// --------- pack block-diagonal W2: out[n][k] bf16, n in [0,4096) k in [0,320)
__global__ __launch_bounds__(320) void packW2_kernel(const float* __restrict__ w2,
    const float* __restrict__ a2, const float* __restrict__ v2,
    const float* __restrict__ g2, u16* __restrict__ out) {
  int n = blockIdx.x; int k = threadIdx.x;
  int which = n >> 10, col = n & 1023;
  float v = 0.f;
  if (which==0)      { if (k < 64)              v = w2[(size_t)k*Cc + col]; }
  else if (which==1) { if (k >= 64 && k < 128)  v = a2[(size_t)(k-64)*Cc + col]; }
  else if (which==2) { if (k >= 128 && k < 160) v = v2[(size_t)(k-128)*Cc + col]; }
  else               { if (k >= 160)            v = g2[(size_t)(k-160)*Cc + col]; }
  out[(size_t)n*LORAK + k] = bf16_1(v);
}

// --------- act + cvt lora columns of bigOut -> loraAct bf16 [4096][320] ------
__global__ __launch_bounds__(320) void actcvt_kernel(const float* __restrict__ m,
    u16* __restrict__ loraAct) {
  int i = blockIdx.x; int cc = threadIdx.x;
  float v = m[(size_t)i*BIGN + 3072 + cc];
  if (cc < 64) v = tanhf(v);
  else if (cc >= 160) v = sgm(v);
  loraAct[(size_t)i*LORAK + cc] = bf16_1(v);
}

// ---------------- fused LN1 -> bigA = [xn | xx] bf16 -------------------------
__global__ __launch_bounds__(256) void lnmix1_kernel(const float* __restrict__ x,
    const float* __restrict__ w, const float* __restrict__ b,
    u16* __restrict__ bigA) {
  int rowg = blockIdx.x; int t = rowg & (Tt-1);
  int tid = threadIdx.x;
  size_t off = (size_t)rowg*Cc + tid*4;
  float4 vc = *(const float4*)(x + off);
  float4 vp = {0.f,0.f,0.f,0.f};
  if (t) vp = *(const float4*)(x + off - Cc);
  float sc = vc.x+vc.y+vc.z+vc.w;
  float qc = vc.x*vc.x+vc.y*vc.y+vc.z*vc.z+vc.w*vc.w;
  float sp = vp.x+vp.y+vp.z+vp.w;
  float qp = vp.x*vp.x+vp.y*vp.y+vp.z*vp.z+vp.w*vp.w;
  sc = redgrp<32>(sc); qc = redgrp<32>(qc);
  sp = redgrp<32>(sp); qp = redgrp<32>(qp);
  __shared__ float rbuf[4][4];
  int lane = tid & 63, wv = tid >> 6;
  if (lane==0){ rbuf[wv][0]=sc; rbuf[wv][1]=qc; rbuf[wv][2]=sp; rbuf[wv][3]=qp; }
  __syncthreads();
  sc = rbuf[0][0]+rbuf[1][0]+rbuf[2][0]+rbuf[3][0];
  qc = rbuf[0][1]+rbuf[1][1]+rbuf[2][1]+rbuf[3][1];
  sp = rbuf[0][2]+rbuf[1][2]+rbuf[2][2]+rbuf[3][2];
  qp = rbuf[0][3]+rbuf[1][3]+rbuf[2][3]+rbuf[3][3];
  float muc = sc*(1.0f/Cc), mup = sp*(1.0f/Cc);
  float rnc = rsqrtf(qc*(1.0f/Cc) - muc*muc + 1e-5f);
  float rnp = rsqrtf(qp*(1.0f/Cc) - mup*mup + 1e-5f);
  float4 w4 = *(const float4*)(w + tid*4);
  float4 b4 = *(const float4*)(b + tid*4);
  float vcl[4]={vc.x,vc.y,vc.z,vc.w};
  float vpl[4]={vp.x,vp.y,vp.z,vp.w};
  float wl[4]={w4.x,w4.y,w4.z,w4.w};
  float bl[4]={b4.x,b4.y,b4.z,b4.w};
  float xnc[4], xx[4];
  #pragma unroll
  for (int q=0;q<4;++q){
    xnc[q] = (vcl[q]-muc)*rnc*wl[q] + bl[q];
    float xnp = t ? ((vpl[q]-mup)*rnp*wl[q] + bl[q]) : 0.0f;
    xx[q] = xnp - xnc[q];
  }
  size_t ab = (size_t)rowg*BIGK + tid*4;
  uint2 p0 = {pack_bf16(xnc[0],xnc[1]), pack_bf16(xnc[2],xnc[3])};
  uint2 p1 = {pack_bf16(xx[0],xx[1]),   pack_bf16(xx[2],xx[3])};
  *(uint2*)(bigA + ab) = p0;
  *(uint2*)(bigA + ab + 1024) = p1;
}

// ---------------- fused LN2 + cmix -> bf16 -----------------------------------
__global__ __launch_bounds__(256) void lnmix2_kernel(const float* __restrict__ x,
    const float* __restrict__ w, const float* __restrict__ b,
    const float* __restrict__ mixk, u16* __restrict__ outb) {
  int rowg = blockIdx.x; int t = rowg & (Tt-1);
  int tid = threadIdx.x;
  size_t off = (size_t)rowg*Cc + tid*4;
  float4 vc = *(const float4*)(x + off);
  float4 vp = {0.f,0.f,0.f,0.f};
  if (t) vp = *(const float4*)(x + off - Cc);
  float sc = vc.x+vc.y+vc.z+vc.w;
  float qc = vc.x*vc.x+vc.y*vc.y+vc.z*vc.z+vc.w*vc.w;
  float sp = vp.x+vp.y+vp.z+vp.w;
  float qp = vp.x*vp.x+vp.y*vp.y+vp.z*vp.z+vp.w*vp.w;
  sc = redgrp<32>(sc); qc = redgrp<32>(qc);
  sp = redgrp<32>(sp); qp = redgrp<32>(qp);
  __shared__ float rbuf[4][4];
  int lane = tid & 63, wv = tid >> 6;
  if (lane==0){ rbuf[wv][0]=sc; rbuf[wv][1]=qc; rbuf[wv][2]=sp; rbuf[wv][3]=qp; }
  __syncthreads();
  sc = rbuf[0][0]+rbuf[1][0]+rbuf[2][0]+rbuf[3][0];
  qc = rbuf[0][1]+rbuf[1][1]+rbuf[2][1]+rbuf[3][1];
  sp = rbuf[0][2]+rbuf[1][2]+rbuf[2][2]+rbuf[3][2];
  qp = rbuf[0][3]+rbuf[1][3]+rbuf[2][3]+rbuf[3][3];
  float muc = sc*(1.0f/Cc), mup = sp*(1.0f/Cc);
  float rnc = rsqrtf(qc*(1.0f/Cc) - muc*muc + 1e-5f);
  float rnp = rsqrtf(qp*(1.0f/Cc) - mup*mup + 1e-5f);
  float4 w4 = *(const float4*)(w + tid*4);
  float4 b4 = *(const float4*)(b + tid*4);
  float4 m = *(const float4*)(mixk + tid*4);
  float vcl[4]={vc.x,vc.y,vc.z,vc.w};
  float vpl[4]={vp.x,vp.y,vp.z,vp.w};
  float wl[4]={w4.x,w4.y,w4.z,w4.w};
  float bl[4]={b4.x,b4.y,b4.z,b4.w};
  float ml[4]={m.x,m.y,m.z,m.w};
  float o[4];
  #pragma unroll
  for (int q=0;q<4;++q){
    float xnc = (vcl[q]-muc)*rnc*wl[q] + bl[q];
    float xnp = t ? ((vpl[q]-mup)*rnp*wl[q] + bl[q]) : 0.0f;
    o[q] = xnc + (xnp - xnc)*ml[q];
  }
  uint2 p = {pack_bf16(o[0],o[1]), pack_bf16(o[2],o[3])};
  *(uint2*)(outb + off) = p;
}

// ============ bf16 GEMM (m97 structure), tile 128 x BN (BN=128|64) ===========
// out = A[M,K] @ W[N,K]^T.  MODE 0: f32   1: f32 res+acc   2: bf16 relu(acc)^2
// T1 bijective XCD swizzle; T4 counted vmcnt; T2 both-sides XOR swizzle.
// BN=64 doubles the grid for N=1024 GEMMs (full-CU occupancy).
template<int MODE, int BN>
__global__ __launch_bounds__(256) void gemm_bf16(const u16* __restrict__ A,
    const u16* __restrict__ W, void* __restrict__ outv,
    const float* __restrict__ res, int M, int N, int K) {
  constexpr int NJ = BN/32;        // acc cols per wave (4 or 2)
  constexpr int NBCH = BN/32;      // B staging chunks per thread (4 or 2)
  __shared__ u16 As[2][128*64];
  __shared__ u16 Bs[2][BN*64];
  int tid = threadIdx.x;
  int nwg = gridDim.x;
  int q8 = nwg >> 3;
  int id = (blockIdx.x & 7)*q8 + (blockIdx.x >> 3);   // bijective (nwg%8==0)
  int nbx = N / BN;
  int bm = id / nbx, bn = id - bm*nbx;                // bn fastest: A-panel per XCD
  int wave = tid >> 6, lane = tid & 63;
  int wm = wave >> 1, wn = wave & 1;
  int srowA = wave*32 + (lane>>3);
  int srowB = wave*(BN/4) + (lane>>3);
  int scol = (((lane&7) ^ ((lane>>3)&7)))*8;          // T2 source pre-swizzle
  const u16* Ag = A + (size_t)(bm*128 + srowA)*K + scol;
  const u16* Wg = W + (size_t)(bn*BN + srowB)*K + scol;
  int nt = K >> 6;
  f32x4 acc[4][NJ];
  f32x4 zero = {0.f,0.f,0.f,0.f};
  #pragma unroll
  for (int i=0;i<4;++i)
    #pragma unroll
    for (int j=0;j<NJ;++j) acc[i][j] = zero;

  #define STAGE(buf, t) { \
    const u16* Ag2 = Ag + (size_t)(t)*64; \
    const u16* Wg2 = Wg + (size_t)(t)*64; \
    _Pragma("unroll") \
    for (int i_=0;i_<4;++i_) \
      gload16(Ag2 + (size_t)i_*8*K, &As[buf][(wave*32+i_*8)*64]); \
    _Pragma("unroll") \
    for (int i_=0;i_<NBCH;++i_) \
      gload16(Wg2 + (size_t)i_*8*K, &Bs[buf][(wave*(BN/4)+i_*8)*64]); }

  STAGE(0, 0);
  int lrow = lane & 15, lk8 = lane >> 4;
  int r7 = lrow & 7;
  for (int t = 0; t < nt; ++t) {
    int cur = t & 1;
    if (t+1 < nt) {
      STAGE(cur^1, t+1);
      if (BN == 128) asm volatile("s_waitcnt vmcnt(8)\n\ts_barrier" ::: "memory");
      else           asm volatile("s_waitcnt vmcnt(6)\n\ts_barrier" ::: "memory");
    } else {
      asm volatile("s_waitcnt vmcnt(0)\n\ts_barrier" ::: "memory");
    }
    #pragma unroll
    for (int kk2 = 0; kk2 < 2; ++kk2) {
      int sl = ((kk2*4 + lk8) ^ r7) * 8;
      bf16x8 af[4], bfr[NJ];
      #pragma unroll
      for (int i=0;i<4;++i)
        af[i] = *(const bf16x8*)&As[cur][(wm*64 + i*16 + lrow)*64 + sl];
      #pragma unroll
      for (int j=0;j<NJ;++j)
        bfr[j] = *(const bf16x8*)&Bs[cur][(wn*(BN/2) + j*16 + lrow)*64 + sl];
      #pragma unroll
      for (int i=0;i<4;++i)
        #pragma unroll
        for (int j=0;j<NJ;++j)
          acc[i][j] = __builtin_amdgcn_mfma_f32_16x16x32_bf16(af[i], bfr[j], acc[i][j], 0, 0, 0);
    }
    asm volatile("s_barrier" ::: "memory");
  }
  #undef STAGE
  float* outf = (float*)outv;
  u16* outb = (u16*)outv;
  int crow4 = (lane>>4)*4, ccol = lane & 15;
  #pragma unroll
  for (int i=0;i<4;++i){
    #pragma unroll
    for (int j=0;j<NJ;++j){
      int gr = bm*128 + wm*64 + i*16 + crow4;
      int gc = bn*BN + wn*(BN/2) + j*16 + ccol;
      #pragma unroll
      for (int q=0;q<4;++q){
        float v = acc[i][j][q];
        size_t o = (size_t)(gr+q)*N + gc;
        if (MODE==1) { v += res[o]; outf[o] = v; }
        else if (MODE==2) { v = fmaxf(v, 0.f); outb[o] = bf16_1(v*v); }
        else outf[o] = v;
      }
    }
  }
}

// ---------------- prep: dw/da/dv from dwdavg (ld 4096), k/v from bigOut ------
__global__ __launch_bounds__(256) void prep_kernel(
    const float* __restrict__ kraw, const float* __restrict__ dw,
    const float* __restrict__ da, const float* __restrict__ dv,
    const float* __restrict__ vraw, const float* __restrict__ vfirst,
    const float* __restrict__ w0, const float* __restrict__ a0,
    const float* __restrict__ v0, const float* __restrict__ k_k,
    const float* __restrict__ k_a,
    float* __restrict__ decay, float* __restrict__ kfin, float* __restrict__ vfin,
    float* __restrict__ Ak, float* __restrict__ Bk) {
  int row = blockIdx.x; int tid = threadIdx.x; int c = tid*4;
  size_t off = (size_t)row*Cc + c;
  size_t offw = (size_t)row*BIGN + c;
  size_t offd = (size_t)row*BIGW + c;
  float4 kr = *(const float4*)(kraw+offw);
  float4 vr = *(const float4*)(vraw+offw);
  float4 w4 = *(const float4*)(dw+offd);
  float4 A4 = *(const float4*)(da+offd);
  float4 V4 = *(const float4*)(dv+offd);
  float4 vf = *(const float4*)(vfirst+off);
  float4 w04 = *(const float4*)(w0+c);
  float4 a04 = *(const float4*)(a0+c);
  float4 v04 = *(const float4*)(v0+c);
  float4 kk4 = *(const float4*)(k_k+c);
  float4 ka4 = *(const float4*)(k_a+c);
  float krl[4]={kr.x,kr.y,kr.z,kr.w};
  float dwl[4]={w4.x,w4.y,w4.z,w4.w};
  float dal[4]={A4.x,A4.y,A4.z,A4.w};
  float dvl[4]={V4.x,V4.y,V4.z,V4.w};
  float vrl[4]={vr.x,vr.y,vr.z,vr.w};
  float vfl[4]={vf.x,vf.y,vf.z,vf.w};
  float w0l[4]={w04.x,w04.y,w04.z,w04.w};
  float a0l[4]={a04.x,a04.y,a04.z,a04.w};
  float v0l[4]={v04.x,v04.y,v04.z,v04.w};
  float kkl[4]={kk4.x,kk4.y,kk4.z,kk4.w};
  float kal[4]={ka4.x,ka4.y,ka4.z,ka4.w};
  float av[4], dec[4], vv[4], kp[4], kf[4];
  float ss = 0.f;
  #pragma unroll
  for (int q=0;q<4;++q){
    av[q] = sgm(a0l[q] + dal[q]);
    dec[q] = 0.60653065971263342f * sgm(w0l[q] + dwl[q]);   // exp(-softplus(-u)-0.5)
    float sv = sgm(v0l[q] + dvl[q]);
    vv[q] = vrl[q] + (vfl[q]-vrl[q])*sv;
    kp[q] = krl[q]*kkl[q];
    ss += kp[q]*kp[q];
    kf[q] = krl[q]*(1.0f + (av[q]-1.0f)*kal[q]);
  }
  ss = redgrp<8>(ss);
  float inv = 1.0f / fmaxf(sqrtf(ss), 1e-12f);
  float4 o;
  o.x=dec[0];o.y=dec[1];o.z=dec[2];o.w=dec[3];  *(float4*)(decay+off)=o;
  o.x=kf[0]; o.y=kf[1]; o.z=kf[2]; o.w=kf[3];   *(float4*)(kfin+off)=o;
  o.x=vv[0]; o.y=vv[1]; o.z=vv[2]; o.w=vv[3];   *(float4*)(vfin+off)=o;
  o.x=-kp[0]*inv; o.y=-kp[1]*inv; o.z=-kp[2]*inv; o.w=-kp[3]*inv; *(float4*)(Ak+off)=o;
  o.x=kp[0]*inv*av[0]; o.y=kp[1]*inv*av[1]; o.z=kp[2]*inv*av[2]; o.w=kp[3]*inv*av[3];
  *(float4*)(Bk+off)=o;
}

// ===== WKV-7 warmup-chunked scan (decay<=e^-0.5 => 32-step influence ~1e-7)
// 512 blocks (32 bh x 16 chunks), 512 thr = 8 waves; thread owns rows rg,rg+32.
__global__ __launch_bounds__(512) void wkv_kernel(
    const float* __restrict__ decay, const float* __restrict__ Ak,
    const float* __restrict__ Bk, const float* __restrict__ kfin,
    const float* __restrict__ r_, const float* __restrict__ vfin,
    const float* __restrict__ S0, float* __restrict__ y) {
  __shared__ float lds[2][6][CH][64];
  int bid = blockIdx.x;
  int bh = bid & 31, c = bid >> 5;
  int bb = bh >> 4, h = bh & 15;
  int tid = threadIdx.x;
  int wave = tid >> 6, lane = tid & 63;
  int rg = tid >> 4;                  // 0..31
  int bj = tid & 15, j0 = bj*4;
  int r0 = rg, r1 = rg + 32;
  float Sa_[4] = {0.f,0.f,0.f,0.f};
  float Sb_[4] = {0.f,0.f,0.f,0.f};
  if (c == 0) {
    float4 t0 = *(const float4*)(S0 + (size_t)bh*4096 + r0*64 + j0);
    float4 t1 = *(const float4*)(S0 + (size_t)bh*4096 + r1*64 + j0);
    Sa_[0]=t0.x; Sa_[1]=t0.y; Sa_[2]=t0.z; Sa_[3]=t0.w;
    Sb_[0]=t1.x; Sb_[1]=t1.y; Sb_[2]=t1.z; Sb_[3]=t1.w;
  }
  size_t seqb = (size_t)bb*Tt;
  int t0g = (c==0) ? 0 : (c*CL - WU);
  int NPH = (c==0) ? (CL/CH) : ((CL+WU)/CH);
  int phE = (c==0) ? 0 : (WU/CH);
  int lhi = lane >> 4, llo4 = (lane & 15)*4;

  #define WST1(buf, stepb, arr, base, ldv) { \
    const float* gp_ = (base) + (size_t)(seqb + (size_t)(stepb) + lhi)*(ldv) + h*64 + llo4; \
    _Pragma("unroll") \
    for (int p_=0; p_<4; ++p_) \
      gload16(gp_ + (size_t)p_*4*(ldv), &lds[buf][arr][p_*4][0]); }
  #define WSTAGE(buf, stepb) { \
    if (wave==0)      { WST1(buf, stepb, 0, decay, Cc) } \
    else if (wave==1) { WST1(buf, stepb, 1, Ak, Cc) } \
    else if (wave==2) { WST1(buf, stepb, 2, Bk, Cc) } \
    else if (wave==3) { WST1(buf, stepb, 3, kfin, Cc) } \
    else if (wave==4) { WST1(buf, stepb, 4, r_, BIGN) } \
    else if (wave==5) { WST1(buf, stepb, 5, vfin, Cc) } }

  WSTAGE(0, t0g);
  for (int ph = 0; ph < NPH; ++ph) {
    int cur = ph & 1;
    if (ph+1 < NPH) {
      WSTAGE(cur^1, t0g + (ph+1)*CH);
      asm volatile("s_waitcnt vmcnt(4)\n\ts_barrier" ::: "memory");
    } else {
      asm volatile("s_waitcnt vmcnt(0)\n\ts_barrier" ::: "memory");
    }
    bool emit = (ph >= phE);
    const float* L0 = &lds[cur][0][0][0];
    #pragma unroll
    for (int s = 0; s < CH; ++s) {
      const float* bp = L0 + s*64;
      float4 d4 = *(const float4*)(bp + 0*CH*64 + j0);
      float4 a4 = *(const float4*)(bp + 1*CH*64 + j0);
      float4 b4 = *(const float4*)(bp + 2*CH*64 + j0);
      float4 k4 = *(const float4*)(bp + 3*CH*64 + j0);
      float4 r4 = *(const float4*)(bp + 4*CH*64 + j0);
      float v0 = bp[5*CH*64 + r0];
      float v1 = bp[5*CH*64 + r1];
      Sa_[0]*=d4.x; Sa_[1]*=d4.y; Sa_[2]*=d4.z; Sa_[3]*=d4.w;
      Sb_[0]*=d4.x; Sb_[1]*=d4.y; Sb_[2]*=d4.z; Sb_[3]*=d4.w;
      float sa0 = fmaf(Sa_[0],a4.x, Sa_[1]*a4.y) + fmaf(Sa_[2],a4.z, Sa_[3]*a4.w);
      float sa1 = fmaf(Sb_[0],a4.x, Sb_[1]*a4.y) + fmaf(Sb_[2],a4.z, Sb_[3]*a4.w);
      sa0 = red16(sa0);
      sa1 = red16(sa1);
      Sa_[0]=fmaf(v0,k4.x,Sa_[0]); Sa_[1]=fmaf(v0,k4.y,Sa_[1]);
      Sa_[2]=fmaf(v0,k4.z,Sa_[2]); Sa_[3]=fmaf(v0,k4.w,Sa_[3]);
      Sa_[0]=fmaf(sa0,b4.x,Sa_[0]); Sa_[1]=fmaf(sa0,b4.y,Sa_[1]);
      Sa_[2]=fmaf(sa0,b4.z,Sa_[2]); Sa_[3]=fmaf(sa0,b4.w,Sa_[3]);
      Sb_[0]=fmaf(v1,k4.x,Sb_[0]); Sb_[1]=fmaf(v1,k4.y,Sb_[1]);
      Sb_[2]=fmaf(v1,k4.z,Sb_[2]); Sb_[3]=fmaf(v1,k4.w,Sb_[3]);
      Sb_[0]=fmaf(sa1,b4.x,Sb_[0]); Sb_[1]=fmaf(sa1,b4.y,Sb_[1]);
      Sb_[2]=fmaf(sa1,b4.z,Sb_[2]); Sb_[3]=fmaf(sa1,b4.w,Sb_[3]);
      if (emit) {
        float y0 = fmaf(Sa_[0],r4.x, Sa_[1]*r4.y) + fmaf(Sa_[2],r4.z, Sa_[3]*r4.w);
        float y1 = fmaf(Sb_[0],r4.x, Sb_[1]*r4.y) + fmaf(Sb_[2],r4.z, Sb_[3]*r4.w);
        y0 = red16(y0);
        y1 = red16(y1);
        if (bj == 0) {
          size_t yo = (seqb + (size_t)t0g + ph*CH + s)*Cc + h*64;
          y[yo + r0] = y0;
          y[yo + r1] = y1;
        }
      }
    }
    asm volatile("s_barrier" ::: "memory");
  }
  #undef WSTAGE
  #undef WST1
}

// ---------------- GroupNorm(head) + r.k.r_k bonus + *g -> bf16 ---------------
__global__ __launch_bounds__(256) void gn_kernel(
    const float* __restrict__ y, const float* __restrict__ r_,
    const float* __restrict__ kfin, const float* __restrict__ vfin,
    const float* __restrict__ g_, const float* __restrict__ lnxw,
    const float* __restrict__ lnxb, const float* __restrict__ r_k,
    u16* __restrict__ Ao) {
  int row = blockIdx.x; int tid = threadIdx.x; int c = tid*4;
  size_t off = (size_t)row*Cc + c;
  float4 y4 = *(const float4*)(y+off);
  float s = y4.x+y4.y+y4.z+y4.w;
  float q = y4.x*y4.x+y4.y*y4.y+y4.z*y4.z+y4.w*y4.w;
  s = redgrp<8>(s); q = redgrp<8>(q);
  float mu = s*(1.0f/64.0f);
  float var = q*(1.0f/64.0f) - mu*mu;
  float rn = rsqrtf(var + 64e-5f);
  float4 rr = *(const float4*)(r_ + (size_t)row*BIGN + c);
  float4 kk = *(const float4*)(kfin+off);
  float4 vv = *(const float4*)(vfin+off);
  float4 gg = *(const float4*)(g_ + (size_t)row*BIGW + c);
  int h = tid >> 4; int hs = (tid & 15)*4;
  float4 rk = *(const float4*)(r_k + h*64 + hs);
  float dp = rr.x*kk.x*rk.x + rr.y*kk.y*rk.y + rr.z*kk.z*rk.z + rr.w*kk.w*rk.w;
  dp = redgrp<8>(dp);
  float4 w4 = *(const float4*)(lnxw+c);
  float4 b4 = *(const float4*)(lnxb+c);
  float o0 = (((y4.x-mu)*rn)*w4.x + b4.x + dp*vv.x) * gg.x;
  float o1 = (((y4.y-mu)*rn)*w4.y + b4.y + dp*vv.y) * gg.y;
  float o2 = (((y4.z-mu)*rn)*w4.z + b4.z + dp*vv.z) * gg.z;
  float o3 = (((y4.w-mu)*rn)*w4.w + b4.w + dp*vv.w) * gg.w;
  uint2 p = {pack_bf16(o0,o1), pack_bf16(o2,o3)};
  *(uint2*)(Ao + off) = p;
}

extern "C" void kernel_launch(void* const* d_in, const int* in_sizes, int n_in,
                              void* d_out, int out_size, void* d_ws, size_t ws_size,
                              hipStream_t stream) {
  const float* x      = (const float*)d_in[0];
  const float* vfirst = (const float*)d_in[1];
  const float* S0     = (const float*)d_in[2];
  const float* ln1w   = (const float*)d_in[3];
  const float* ln1b   = (const float*)d_in[4];
  const float* ln2w   = (const float*)d_in[5];
  const float* ln2b   = (const float*)d_in[6];
  const float* x_r    = (const float*)d_in[7];
  const float* x_w    = (const float*)d_in[8];
  const float* x_k    = (const float*)d_in[9];
  const float* x_v    = (const float*)d_in[10];
  const float* x_a    = (const float*)d_in[11];
  const float* x_g    = (const float*)d_in[12];
  const float* w0     = (const float*)d_in[13];
  const float* w1     = (const float*)d_in[14];
  const float* w2     = (const float*)d_in[15];
  const float* a0     = (const float*)d_in[16];
  const float* a1     = (const float*)d_in[17];
  const float* a2     = (const float*)d_in[18];
  const float* v0     = (const float*)d_in[19];
  const float* v1     = (const float*)d_in[20];
  const float* v2     = (const float*)d_in[21];
  const float* g1     = (const float*)d_in[22];
  const float* g2     = (const float*)d_in[23];
  const float* k_k    = (const float*)d_in[24];
  const float* k_a    = (const float*)d_in[25];
  const float* r_k    = (const float*)d_in[26];
  const float* W_r    = (const float*)d_in[27];
  const float* W_k    = (const float*)d_in[28];
  const float* W_v    = (const float*)d_in[29];
  const float* W_o    = (const float*)d_in[30];
  const float* lnxw   = (const float*)d_in[31];
  const float* lnxb   = (const float*)d_in[32];
  const float* mixk   = (const float*)d_in[33];
  const float* Wkey   = (const float*)d_in[34];
  const float* Wval   = (const float*)d_in[35];
  float* out = (float*)d_out;
  float* ws  = (float*)d_ws;
  const size_t U = (size_t)BT * Cc;
  float* u[14];
  for (int i=0;i<14;++i) u[i] = ws + i*U;

  u16* bigA   = (u16*)u[0];
  u16* BigB   = (u16*)u[1];
  float* bigOut = u[2];     // [4096][3456] f32 (u2..u5)
  float* dwdavg = u[6];     // [4096][4096] f32 (u6..u9)
  u16* W2blk  = (u16*)u[10];
  u16* loraAct= (u16*)u[11];
  float* Bk   = u[0];
  float* y_   = u[1];
  u16* gnb    = (u16*)u[10];
  u16* Wob    = (u16*)u[13];
  float* xo   = u[0];
  u16* Wkeyb  = (u16*)u[6];
  u16* cmb    = (u16*)u[7];
  u16* Wvalb  = (u16*)u[8];
  u16* midb   = (u16*)u[2];

  dim3 b256(256);
  packW_kernel<<<dim3(Cc,3), b256, 0, stream>>>(W_r, W_k, W_v, x_r, x_k, x_v, BigB);
  packL_kernel<<<320, b256, 0, stream>>>(w1, a1, v1, g1, x_w, x_a, x_v, x_g, BigB);
  packW2_kernel<<<BIGW, dim3(320), 0, stream>>>(w2, a2, v2, g2, W2blk);
  lnmix1_kernel<<<BT, b256, 0, stream>>>(x, ln1w, ln1b, bigA);
  gemm_bf16<0,128><<<(BT/128)*(BIGN/128), b256, 0, stream>>>(bigA, BigB, bigOut, nullptr, BT, BIGN, BIGK);
  actcvt_kernel<<<BT, dim3(320), 0, stream>>>(bigOut, loraAct);
  gemm_bf16<0,128><<<(BT/128)*(BIGW/128), b256, 0, stream>>>(loraAct, W2blk, dwdavg, nullptr, BT, BIGW, LORAK);
  prep_kernel<<<BT, b256, 0, stream>>>(bigOut+1024, dwdavg, dwdavg+1024, dwdavg+2048,
      bigOut+2048, vfirst, w0, a0, v0, k_k, k_a, u[10], u[11], u[12], u[13], Bk);
  wkv_kernel<<<32*(Tt/CL), dim3(512), 0, stream>>>(u[10], u[13], Bk, u[11], bigOut, u[12], S0, y_);
  gn_kernel<<<BT, b256, 0, stream>>>(y_, bigOut, u[11], u[12], dwdavg+3072, lnxw, lnxb, r_k, gnb);
  // three weight converts + v_first passthrough in one dispatch
  cvtall_kernel<<<(Cc*Cc + FFNd*Cc*2 + BT*Cc)/2048, b256, 0, stream>>>(
      W_o, Wob, Wkey, Wkeyb, Wval, Wvalb, vfirst, out + (size_t)BT*Cc);
  // N=1024 GEMMs: BN=64 tile -> 512 blocks (full CU coverage)
  gemm_bf16<1,64><<<(BT/128)*(Cc/64), b256, 0, stream>>>(gnb, Wob, xo, x, BT, Cc, Cc);
  lnmix2_kernel<<<BT, b256, 0, stream>>>(xo, ln2w, ln2b, mixk, cmb);
  gemm_bf16<2,128><<<(BT/128)*(FFNd/128), b256, 0, stream>>>(cmb, Wkeyb, midb, nullptr, BT, FFNd, Cc);
  gemm_bf16<1,64><<<(BT/128)*(Cc/64), b256, 0, stream>>>(midb, Wvalb, out, xo, BT, Cc, FFNd);
}

// Round 18
// 377.067 us; speedup vs baseline: 1.1664x; 1.0456x over previous
//
#include <hip/hip_runtime.h>
#include <math.h>

#define Bb 2
#define Tt 2048
#define Cc 1024
#define Hh 16
#define BT 4096
#define FFNd 4096
#define CH 16
#define CL 128
#define WU 32
#define BIGN 3584
#define BIGK 2048
#define LORAK 320
#define BIGW 4096
// big-B column layout: r@0 k@1024 v@2048 w@3072 a@3136 vl@3200 g@3232 (end 3392, pad->3584)
// dwdavg column layout: dw@0 da@1024 dv@2048 g@3072  (ld 4096)

typedef __attribute__((ext_vector_type(8))) short bf16x8;
typedef __attribute__((ext_vector_type(4))) float f32x4;
typedef unsigned short u16;

__device__ __forceinline__ float sgm(float x){ return 1.0f/(1.0f+expf(-x)); }

template<int MAXM>
__device__ __forceinline__ float redgrp(float v){
  #pragma unroll
  for (int m=1; m<=MAXM; m<<=1) v += __shfl_xor(v, m, 64);
  return v;
}

template<int CTRL>
__device__ __forceinline__ float dppadd(float v){
  union { float f; int i; } u, r;
  u.f = v;
  r.i = __builtin_amdgcn_update_dpp(u.i, u.i, CTRL, 0xf, 0xf, true);
  return v + r.f;
}
__device__ __forceinline__ float red16(float v){
  v = dppadd<0xB1>(v);
  v = dppadd<0x4E>(v);
  v = dppadd<0x141>(v);
  v = dppadd<0x140>(v);
  return v;
}

__device__ __forceinline__ unsigned pack_bf16(float a, float b){
  unsigned ua = __builtin_bit_cast(unsigned, a);
  unsigned ub = __builtin_bit_cast(unsigned, b);
  ua = (ua + 0x7FFFu + ((ua>>16)&1u)) >> 16;
  ub = (ub + 0x7FFFu + ((ub>>16)&1u)) >> 16;
  return ua | (ub<<16);
}
__device__ __forceinline__ u16 bf16_1(float a){
  unsigned ua = __builtin_bit_cast(unsigned, a);
  return (u16)((ua + 0x7FFFu + ((ua>>16)&1u)) >> 16);
}

__device__ __forceinline__ void gload16(const void* g, void* l){
  __builtin_amdgcn_global_load_lds(
    (const __attribute__((address_space(1))) unsigned int*)g,
    (__attribute__((address_space(3))) unsigned int*)l, 16, 0, 0);
}

// ------- fused f32->bf16 convert of three weights + v_first passthrough ------
__device__ __forceinline__ void cvt8(const float* __restrict__ in,
    u16* __restrict__ out, size_t i){
  float4 a = ((const float4*)in)[2*i];
  float4 b = ((const float4*)in)[2*i+1];
  uint4 o = {pack_bf16(a.x,a.y), pack_bf16(a.z,a.w),
             pack_bf16(b.x,b.y), pack_bf16(b.z,b.w)};
  ((uint4*)out)[i] = o;
}
__global__ __launch_bounds__(256) void cvtall_kernel(
    const float* __restrict__ wo, u16* __restrict__ wob,
    const float* __restrict__ wk, u16* __restrict__ wkb,
    const float* __restrict__ wv, u16* __restrict__ wvb,
    const float* __restrict__ csrc, float* __restrict__ cdst) {
  size_t i = (size_t)blockIdx.x*256 + threadIdx.x;
  const size_t NA = (size_t)Cc*Cc/8;       // 131072
  const size_t NB = (size_t)FFNd*Cc/8;     // 524288
  if (i < NA) cvt8(wo, wob, i);
  else if (i < NA+NB) cvt8(wk, wkb, i-NA);
  else if (i < NA+2*NB) cvt8(wv, wvb, i-NA-NB);
  else {
    size_t j = i - NA - 2*NB;              // 0..BT*Cc/8
    float4 a = ((const float4*)csrc)[2*j];
    float4 b = ((const float4*)csrc)[2*j+1];
    ((float4*)cdst)[2*j] = a;
    ((float4*)cdst)[2*j+1] = b;
  }
}

// ---------------- pack square weights into BigB rows: [W | diag(mix)W] -------
__global__ __launch_bounds__(256) void packW_kernel(const float* __restrict__ Wr,
    const float* __restrict__ Wk, const float* __restrict__ Wv,
    const float* __restrict__ xr, const float* __restrict__ xk,
    const float* __restrict__ xv, u16* __restrict__ out) {
  int which = blockIdx.y;
  const float* W   = which==0 ? Wr : (which==1 ? Wk : Wv);
  const float* mix = which==0 ? xr : (which==1 ? xk : xv);
  u16* o = out + (size_t)which*1024*BIGK;
  int n = blockIdx.x;             // 0..1023
  int c0 = threadIdx.x*8;         // 0..2040
  int ks = c0 & 1023;
  const float* src = W + (size_t)n*Cc + ks;
  float4 a = *(const float4*)src;
  float4 b = *(const float4*)(src+4);
  if (c0 >= 1024){
    float4 m0 = *(const float4*)(mix + ks);
    float4 m1 = *(const float4*)(mix + ks + 4);
    a.x*=m0.x; a.y*=m0.y; a.z*=m0.z; a.w*=m0.w;
    b.x*=m1.x; b.y*=m1.y; b.z*=m1.z; b.w*=m1.w;
  }
  uint4 ov = {pack_bf16(a.x,a.y), pack_bf16(a.z,a.w),
              pack_bf16(b.x,b.y), pack_bf16(b.z,b.w)};
  *(uint4*)(o + (size_t)n*BIGK + c0) = ov;
}

// ---------------- pack lora W1[C,D] (transposed) into BigB rows --------------
__global__ __launch_bounds__(256) void packL_kernel(const float* __restrict__ w1,
    const float* __restrict__ a1, const float* __restrict__ v1,
    const float* __restrict__ g1, const float* __restrict__ x_w,
    const float* __restrict__ x_a, const float* __restrict__ x_v,
    const float* __restrict__ x_g, u16* __restrict__ out) {
  int bid = blockIdx.x;           // 0..319
  const float* W1; const float* mix; int D, d, nbase;
  if (bid < 64)       { W1=w1; mix=x_w; D=64;  d=bid;     nbase=3072; }
  else if (bid < 128) { W1=a1; mix=x_a; D=64;  d=bid-64;  nbase=3136; }
  else if (bid < 160) { W1=v1; mix=x_v; D=32;  d=bid-128; nbase=3200; }
  else                { W1=g1; mix=x_g; D=160; d=bid-160; nbase=3232; }
  int k0 = threadIdx.x*8;
  float v[8];
  #pragma unroll
  for (int q=0;q<8;++q){
    int kk = k0+q;
    int ks = kk & 1023;
    float t = W1[(size_t)ks*D + d];
    if (kk >= 1024) t *= mix[ks];
    v[q] = t;
  }
  uint4 o = {pack_bf16(v[0],v[1]), pack_bf16(v[2],v[3]),
             pack_bf16(v[4],v[5]), pack_bf16(v[6],v[7])};
  *(uint4*)(out + (size_t)(nbase+d)*BIGK + k0) = o;
}

// --------- pack block-diagonal W2: out[n][k] bf16, n in [0,4096) k in [0,320)
__global__ __launch_bounds__(320) void packW2_kernel(const float* __restrict__ w2,
    const float* __restrict__ a2, const float* __restrict__ v2,
    const float* __restrict__ g2, u16* __restrict__ out) {
  int n = blockIdx.x; int k = threadIdx.x;
  int which = n >> 10, col = n & 1023;
  float v = 0.f;
  if (which==0)      { if (k < 64)              v = w2[(size_t)k*Cc + col]; }
  else if (which==1) { if (k >= 64 && k < 128)  v = a2[(size_t)(k-64)*Cc + col]; }
  else if (which==2) { if (k >= 128 && k < 160) v = v2[(size_t)(k-128)*Cc + col]; }
  else               { if (k >= 160)            v = g2[(size_t)(k-160)*Cc + col]; }
  out[(size_t)n*LORAK + k] = bf16_1(v);
}

// --------- act + cvt lora columns of bigOut -> loraAct bf16 [4096][320] ------
__global__ __launch_bounds__(320) void actcvt_kernel(const float* __restrict__ m,
    u16* __restrict__ loraAct) {
  int i = blockIdx.x; int cc = threadIdx.x;
  float v = m[(size_t)i*BIGN + 3072 + cc];
  if (cc < 64) v = tanhf(v);
  else if (cc >= 160) v = sgm(v);
  loraAct[(size_t)i*LORAK + cc] = bf16_1(v);
}

// ---------------- fused LN1 -> bigA = [xn | xx] bf16 -------------------------
__global__ __launch_bounds__(256) void lnmix1_kernel(const float* __restrict__ x,
    const float* __restrict__ w, const float* __restrict__ b,
    u16* __restrict__ bigA) {
  int rowg = blockIdx.x; int t = rowg & (Tt-1);
  int tid = threadIdx.x;
  size_t off = (size_t)rowg*Cc + tid*4;
  float4 vc = *(const float4*)(x + off);
  float4 vp = {0.f,0.f,0.f,0.f};
  if (t) vp = *(const float4*)(x + off - Cc);
  float sc = vc.x+vc.y+vc.z+vc.w;
  float qc = vc.x*vc.x+vc.y*vc.y+vc.z*vc.z+vc.w*vc.w;
  float sp = vp.x+vp.y+vp.z+vp.w;
  float qp = vp.x*vp.x+vp.y*vp.y+vp.z*vp.z+vp.w*vp.w;
  sc = redgrp<32>(sc); qc = redgrp<32>(qc);
  sp = redgrp<32>(sp); qp = redgrp<32>(qp);
  __shared__ float rbuf[4][4];
  int lane = tid & 63, wv = tid >> 6;
  if (lane==0){ rbuf[wv][0]=sc; rbuf[wv][1]=qc; rbuf[wv][2]=sp; rbuf[wv][3]=qp; }
  __syncthreads();
  sc = rbuf[0][0]+rbuf[1][0]+rbuf[2][0]+rbuf[3][0];
  qc = rbuf[0][1]+rbuf[1][1]+rbuf[2][1]+rbuf[3][1];
  sp = rbuf[0][2]+rbuf[1][2]+rbuf[2][2]+rbuf[3][2];
  qp = rbuf[0][3]+rbuf[1][3]+rbuf[2][3]+rbuf[3][3];
  float muc = sc*(1.0f/Cc), mup = sp*(1.0f/Cc);
  float rnc = rsqrtf(qc*(1.0f/Cc) - muc*muc + 1e-5f);
  float rnp = rsqrtf(qp*(1.0f/Cc) - mup*mup + 1e-5f);
  float4 w4 = *(const float4*)(w + tid*4);
  float4 b4 = *(const float4*)(b + tid*4);
  float vcl[4]={vc.x,vc.y,vc.z,vc.w};
  float vpl[4]={vp.x,vp.y,vp.z,vp.w};
  float wl[4]={w4.x,w4.y,w4.z,w4.w};
  float bl[4]={b4.x,b4.y,b4.z,b4.w};
  float xnc[4], xx[4];
  #pragma unroll
  for (int q=0;q<4;++q){
    xnc[q] = (vcl[q]-muc)*rnc*wl[q] + bl[q];
    float xnp = t ? ((vpl[q]-mup)*rnp*wl[q] + bl[q]) : 0.0f;
    xx[q] = xnp - xnc[q];
  }
  size_t ab = (size_t)rowg*BIGK + tid*4;
  uint2 p0 = {pack_bf16(xnc[0],xnc[1]), pack_bf16(xnc[2],xnc[3])};
  uint2 p1 = {pack_bf16(xx[0],xx[1]),   pack_bf16(xx[2],xx[3])};
  *(uint2*)(bigA + ab) = p0;
  *(uint2*)(bigA + ab + 1024) = p1;
}

// ---------------- fused LN2 + cmix -> bf16 -----------------------------------
__global__ __launch_bounds__(256) void lnmix2_kernel(const float* __restrict__ x,
    const float* __restrict__ w, const float* __restrict__ b,
    const float* __restrict__ mixk, u16* __restrict__ outb) {
  int rowg = blockIdx.x; int t = rowg & (Tt-1);
  int tid = threadIdx.x;
  size_t off = (size_t)rowg*Cc + tid*4;
  float4 vc = *(const float4*)(x + off);
  float4 vp = {0.f,0.f,0.f,0.f};
  if (t) vp = *(const float4*)(x + off - Cc);
  float sc = vc.x+vc.y+vc.z+vc.w;
  float qc = vc.x*vc.x+vc.y*vc.y+vc.z*vc.z+vc.w*vc.w;
  float sp = vp.x+vp.y+vp.z+vp.w;
  float qp = vp.x*vp.x+vp.y*vp.y+vp.z*vp.z+vp.w*vp.w;
  sc = redgrp<32>(sc); qc = redgrp<32>(qc);
  sp = redgrp<32>(sp); qp = redgrp<32>(qp);
  __shared__ float rbuf[4][4];
  int lane = tid & 63, wv = tid >> 6;
  if (lane==0){ rbuf[wv][0]=sc; rbuf[wv][1]=qc; rbuf[wv][2]=sp; rbuf[wv][3]=qp; }
  __syncthreads();
  sc = rbuf[0][0]+rbuf[1][0]+rbuf[2][0]+rbuf[3][0];
  qc = rbuf[0][1]+rbuf[1][1]+rbuf[2][1]+rbuf[3][1];
  sp = rbuf[0][2]+rbuf[1][2]+rbuf[2][2]+rbuf[3][2];
  qp = rbuf[0][3]+rbuf[1][3]+rbuf[2][3]+rbuf[3][3];
  float muc = sc*(1.0f/Cc), mup = sp*(1.0f/Cc);
  float rnc = rsqrtf(qc*(1.0f/Cc) - muc*muc + 1e-5f);
  float rnp = rsqrtf(qp*(1.0f/Cc) - mup*mup + 1e-5f);
  float4 w4 = *(const float4*)(w + tid*4);
  float4 b4 = *(const float4*)(b + tid*4);
  float4 m = *(const float4*)(mixk + tid*4);
  float vcl[4]={vc.x,vc.y,vc.z,vc.w};
  float vpl[4]={vp.x,vp.y,vp.z,vp.w};
  float wl[4]={w4.x,w4.y,w4.z,w4.w};
  float bl[4]={b4.x,b4.y,b4.z,b4.w};
  float ml[4]={m.x,m.y,m.z,m.w};
  float o[4];
  #pragma unroll
  for (int q=0;q<4;++q){
    float xnc = (vcl[q]-muc)*rnc*wl[q] + bl[q];
    float xnp = t ? ((vpl[q]-mup)*rnp*wl[q] + bl[q]) : 0.0f;
    o[q] = xnc + (xnp - xnc)*ml[q];
  }
  uint2 p = {pack_bf16(o[0],o[1]), pack_bf16(o[2],o[3])};
  *(uint2*)(outb + off) = p;
}

// ===== 8-phase 256x256 bf16 GEMM, 8 waves (2Mx4N), BK=64 =====================
// out = A[M,K] @ W[N,K]^T.  MODE 0: f32 out   2: bf16 relu(acc)^2
// LDS 128KB = [parity][half][128][64] per operand. One 128x64 half-tile staged
// per phase by all 8 waves (wave-uniform dest = half_base + wave*2048; source
// pre-swizzled ((lane&7)^(lane>>3))*8 -> T2 involution slot=chunk^(row&7)).
// Counted vmcnt(2) at ph0/ph4 certifies current K-tile; vmcnt(0) last iter.
// 16 MFMA/phase under setprio (T5). Per-thread FIFO verified (see journal).
template<int MODE>
__global__ __launch_bounds__(512) void gemm8(const u16* __restrict__ A,
    const u16* __restrict__ W, void* __restrict__ outv, int M, int N, int K) {
  __shared__ u16 As[2*2*128*64];
  __shared__ u16 Bs[2*2*128*64];
  int tid = threadIdx.x;
  int nwg = gridDim.x;
  int q8 = nwg >> 3;
  int id = (blockIdx.x & 7)*q8 + (blockIdx.x >> 3);   // bijective (nwg%8==0)
  int nbx = N >> 8;
  int bm = id / nbx, bn = id - bm*nbx;
  int wave = tid >> 6, lane = tid & 63;
  int wm = wave >> 2, wn = wave & 3;                  // 2M x 4N waves
  int lrow = lane & 15, lk8 = lane >> 4;
  int r7 = lrow & 7;
  int bhlf = wn >> 1;                                 // B half this wave reads
  int chb = (wn & 1)*64;                              // col base within half
  // staging geometry (per wave: 16 rows = 2KB, 2 gload16/thread)
  int sw = wave*16;
  int sl8 = lane >> 3;                                // 0..7
  int schunk = ((lane & 7) ^ sl8) * 8;                // T2 pre-swizzled k-col
  int nt = K >> 6;
  int lastJ = (nt >> 1) - 1;
  f32x4 acc[8][4];
  f32x4 zero = {0.f,0.f,0.f,0.f};
  #pragma unroll
  for (int i=0;i<8;++i)
    #pragma unroll
    for (int j=0;j<4;++j) acc[i][j] = zero;

  #define STGA(T, h) { \
    const u16* s_ = A + (size_t)(bm*256 + (h)*128 + sw + sl8)*K + (size_t)(T)*64 + schunk; \
    char* d_ = (char*)As + (((T)&1)*32768 + (h)*16384) + wave*2048; \
    gload16(s_, d_); \
    gload16(s_ + (size_t)8*K, d_ + 1024); }
  #define STGB(T, h) { \
    const u16* s_ = W + (size_t)(bn*256 + (h)*128 + sw + sl8)*K + (size_t)(T)*64 + schunk; \
    char* d_ = (char*)Bs + (((T)&1)*32768 + (h)*16384) + wave*2048; \
    gload16(s_, d_); \
    gload16(s_ + (size_t)8*K, d_ + 1024); }
  #define RDA(T, mh) { \
    _Pragma("unroll") \
    for (int ii=0; ii<4; ++ii) \
      _Pragma("unroll") \
      for (int kk=0; kk<2; ++kk) \
        Am[ii][kk] = *(const bf16x8*)&As[((T)&1)*16384 + wm*8192 + \
          ((mh)*64 + ii*16 + lrow)*64 + ((kk*4 + lk8) ^ r7)*8]; }
  #define RDB(T, nh, Bd) { \
    _Pragma("unroll") \
    for (int jj=0; jj<2; ++jj) \
      _Pragma("unroll") \
      for (int kk=0; kk<2; ++kk) \
        Bd[jj][kk] = *(const bf16x8*)&Bs[((T)&1)*16384 + bhlf*8192 + \
          (chb + ((nh)*2+jj)*16 + lrow)*64 + ((kk*4 + lk8) ^ r7)*8]; }
  #define QMM(mh, nh, Bd) { \
    __builtin_amdgcn_s_setprio(1); \
    _Pragma("unroll") \
    for (int ii=0; ii<4; ++ii) \
      _Pragma("unroll") \
      for (int jj=0; jj<2; ++jj) \
        _Pragma("unroll") \
        for (int kk=0; kk<2; ++kk) \
          acc[(mh)*4+ii][(nh)*2+jj] = __builtin_amdgcn_mfma_f32_16x16x32_bf16( \
            Am[ii][kk], Bd[jj][kk], acc[(mh)*4+ii][(nh)*2+jj], 0, 0, 0); \
    __builtin_amdgcn_s_setprio(0); }

  bf16x8 Am[4][2], B0f[2][2], B1f[2][2];
  // prologue: 5 half-stages (10 loads/thread in flight)
  STGA(0,0); STGA(0,1); STGB(0,0); STGB(0,1); STGA(1,0);
  for (int J = 0; J <= lastJ; ++J) {
    int T0 = 2*J, T1 = 2*J+1;
    bool more = (J < lastJ);
    // ph0: certify tile T0; compute T0 (m0,n0); stage A(T1,h1)
    asm volatile("s_waitcnt vmcnt(2)\n\ts_barrier" ::: "memory");
    RDA(T0, 0); RDB(T0, 0, B0f);
    STGA(T1, 1);
    QMM(0, 0, B0f);
    // ph1: T0 (m0,n1); stage B(T1,h0)
    asm volatile("s_barrier" ::: "memory");
    RDB(T0, 1, B1f);
    STGB(T1, 0);
    QMM(0, 1, B1f);
    // ph2: T0 (m1,n0); stage B(T1,h1)
    asm volatile("s_barrier" ::: "memory");
    RDA(T0, 1);
    STGB(T1, 1);
    QMM(1, 0, B0f);
    // ph3: T0 (m1,n1); stage A(T0+2,h0)
    asm volatile("s_barrier" ::: "memory");
    if (more) STGA(T0+2, 0);
    QMM(1, 1, B1f);
    // ph4: certify tile T1; compute T1 (m0,n0); stage A(T0+2,h1)
    if (more) asm volatile("s_waitcnt vmcnt(2)\n\ts_barrier" ::: "memory");
    else      asm volatile("s_waitcnt vmcnt(0)\n\ts_barrier" ::: "memory");
    RDA(T1, 0); RDB(T1, 0, B0f);
    if (more) STGA(T0+2, 1);
    QMM(0, 0, B0f);
    // ph5: T1 (m0,n1); stage B(T0+2,h0)
    asm volatile("s_barrier" ::: "memory");
    RDB(T1, 1, B1f);
    if (more) STGB(T0+2, 0);
    QMM(0, 1, B1f);
    // ph6: T1 (m1,n0); stage B(T0+2,h1)
    asm volatile("s_barrier" ::: "memory");
    RDA(T1, 1);
    if (more) STGB(T0+2, 1);
    QMM(1, 0, B0f);
    // ph7: T1 (m1,n1); stage A(T0+3,h0)
    asm volatile("s_barrier" ::: "memory");
    if (more) STGA(T0+3, 0);
    QMM(1, 1, B1f);
  }
  #undef STGA
  #undef STGB
  #undef RDA
  #undef RDB
  #undef QMM
  float* outf = (float*)outv;
  u16* outb = (u16*)outv;
  int crow4 = (lane>>4)*4, ccol = lane & 15;
  #pragma unroll
  for (int i=0;i<8;++i){
    #pragma unroll
    for (int j=0;j<4;++j){
      int gr = bm*256 + wm*128 + i*16 + crow4;
      int gc = bn*256 + wn*64 + j*16 + ccol;
      #pragma unroll
      for (int q=0;q<4;++q){
        float v = acc[i][j][q];
        size_t o = (size_t)(gr+q)*N + gc;
        if (MODE==2) { v = fmaxf(v, 0.f); outb[o] = bf16_1(v*v); }
        else outf[o] = v;
      }
    }
  }
}

// ============ bf16 GEMM (m97 structure), tile 128 x BN (BN=128|64) ===========
// out = A[M,K] @ W[N,K]^T.  MODE 0: f32   1: f32 res+acc   2: bf16 relu(acc)^2
template<int MODE, int BN>
__global__ __launch_bounds__(256) void gemm_bf16(const u16* __restrict__ A,
    const u16* __restrict__ W, void* __restrict__ outv,
    const float* __restrict__ res, int M, int N, int K) {
  constexpr int NJ = BN/32;
  constexpr int NBCH = BN/32;
  __shared__ u16 As[2][128*64];
  __shared__ u16 Bs[2][BN*64];
  int tid = threadIdx.x;
  int nwg = gridDim.x;
  int q8 = nwg >> 3;
  int id = (blockIdx.x & 7)*q8 + (blockIdx.x >> 3);
  int nbx = N / BN;
  int bm = id / nbx, bn = id - bm*nbx;
  int wave = tid >> 6, lane = tid & 63;
  int wm = wave >> 1, wn = wave & 1;
  int srowA = wave*32 + (lane>>3);
  int srowB = wave*(BN/4) + (lane>>3);
  int scol = (((lane&7) ^ ((lane>>3)&7)))*8;
  const u16* Ag = A + (size_t)(bm*128 + srowA)*K + scol;
  const u16* Wg = W + (size_t)(bn*BN + srowB)*K + scol;
  int nt = K >> 6;
  f32x4 acc[4][NJ];
  f32x4 zero = {0.f,0.f,0.f,0.f};
  #pragma unroll
  for (int i=0;i<4;++i)
    #pragma unroll
    for (int j=0;j<NJ;++j) acc[i][j] = zero;

  #define STAGE(buf, t) { \
    const u16* Ag2 = Ag + (size_t)(t)*64; \
    const u16* Wg2 = Wg + (size_t)(t)*64; \
    _Pragma("unroll") \
    for (int i_=0;i_<4;++i_) \
      gload16(Ag2 + (size_t)i_*8*K, &As[buf][(wave*32+i_*8)*64]); \
    _Pragma("unroll") \
    for (int i_=0;i_<NBCH;++i_) \
      gload16(Wg2 + (size_t)i_*8*K, &Bs[buf][(wave*(BN/4)+i_*8)*64]); }

  STAGE(0, 0);
  int lrow = lane & 15, lk8 = lane >> 4;
  int r7 = lrow & 7;
  for (int t = 0; t < nt; ++t) {
    int cur = t & 1;
    if (t+1 < nt) {
      STAGE(cur^1, t+1);
      if (BN == 128) asm volatile("s_waitcnt vmcnt(8)\n\ts_barrier" ::: "memory");
      else           asm volatile("s_waitcnt vmcnt(6)\n\ts_barrier" ::: "memory");
    } else {
      asm volatile("s_waitcnt vmcnt(0)\n\ts_barrier" ::: "memory");
    }
    #pragma unroll
    for (int kk2 = 0; kk2 < 2; ++kk2) {
      int sl = ((kk2*4 + lk8) ^ r7) * 8;
      bf16x8 af[4], bfr[NJ];
      #pragma unroll
      for (int i=0;i<4;++i)
        af[i] = *(const bf16x8*)&As[cur][(wm*64 + i*16 + lrow)*64 + sl];
      #pragma unroll
      for (int j=0;j<NJ;++j)
        bfr[j] = *(const bf16x8*)&Bs[cur][(wn*(BN/2) + j*16 + lrow)*64 + sl];
      #pragma unroll
      for (int i=0;i<4;++i)
        #pragma unroll
        for (int j=0;j<NJ;++j)
          acc[i][j] = __builtin_amdgcn_mfma_f32_16x16x32_bf16(af[i], bfr[j], acc[i][j], 0, 0, 0);
    }
    asm volatile("s_barrier" ::: "memory");
  }
  #undef STAGE
  float* outf = (float*)outv;
  u16* outb = (u16*)outv;
  int crow4 = (lane>>4)*4, ccol = lane & 15;
  #pragma unroll
  for (int i=0;i<4;++i){
    #pragma unroll
    for (int j=0;j<NJ;++j){
      int gr = bm*128 + wm*64 + i*16 + crow4;
      int gc = bn*BN + wn*(BN/2) + j*16 + ccol;
      #pragma unroll
      for (int q=0;q<4;++q){
        float v = acc[i][j][q];
        size_t o = (size_t)(gr+q)*N + gc;
        if (MODE==1) { v += res[o]; outf[o] = v; }
        else if (MODE==2) { v = fmaxf(v, 0.f); outb[o] = bf16_1(v*v); }
        else outf[o] = v;
      }
    }
  }
}

// ---------------- prep: dw/da/dv from dwdavg (ld 4096), k/v from bigOut ------
__global__ __launch_bounds__(256) void prep_kernel(
    const float* __restrict__ kraw, const float* __restrict__ dw,
    const float* __restrict__ da, const float* __restrict__ dv,
    const float* __restrict__ vraw, const float* __restrict__ vfirst,
    const float* __restrict__ w0, const float* __restrict__ a0,
    const float* __restrict__ v0, const float* __restrict__ k_k,
    const float* __restrict__ k_a,
    float* __restrict__ decay, float* __restrict__ kfin, float* __restrict__ vfin,
    float* __restrict__ Ak, float* __restrict__ Bk) {
  int row = blockIdx.x; int tid = threadIdx.x; int c = tid*4;
  size_t off = (size_t)row*Cc + c;
  size_t offw = (size_t)row*BIGN + c;
  size_t offd = (size_t)row*BIGW + c;
  float4 kr = *(const float4*)(kraw+offw);
  float4 vr = *(const float4*)(vraw+offw);
  float4 w4 = *(const float4*)(dw+offd);
  float4 A4 = *(const float4*)(da+offd);
  float4 V4 = *(const float4*)(dv+offd);
  float4 vf = *(const float4*)(vfirst+off);
  float4 w04 = *(const float4*)(w0+c);
  float4 a04 = *(const float4*)(a0+c);
  float4 v04 = *(const float4*)(v0+c);
  float4 kk4 = *(const float4*)(k_k+c);
  float4 ka4 = *(const float4*)(k_a+c);
  float krl[4]={kr.x,kr.y,kr.z,kr.w};
  float dwl[4]={w4.x,w4.y,w4.z,w4.w};
  float dal[4]={A4.x,A4.y,A4.z,A4.w};
  float dvl[4]={V4.x,V4.y,V4.z,V4.w};
  float vrl[4]={vr.x,vr.y,vr.z,vr.w};
  float vfl[4]={vf.x,vf.y,vf.z,vf.w};
  float w0l[4]={w04.x,w04.y,w04.z,w04.w};
  float a0l[4]={a04.x,a04.y,a04.z,a04.w};
  float v0l[4]={v04.x,v04.y,v04.z,v04.w};
  float kkl[4]={kk4.x,kk4.y,kk4.z,kk4.w};
  float kal[4]={ka4.x,ka4.y,ka4.z,ka4.w};
  float av[4], dec[4], vv[4], kp[4], kf[4];
  float ss = 0.f;
  #pragma unroll
  for (int q=0;q<4;++q){
    av[q] = sgm(a0l[q] + dal[q]);
    dec[q] = 0.60653065971263342f * sgm(w0l[q] + dwl[q]);   // exp(-softplus(-u)-0.5)
    float sv = sgm(v0l[q] + dvl[q]);
    vv[q] = vrl[q] + (vfl[q]-vrl[q])*sv;
    kp[q] = krl[q]*kkl[q];
    ss += kp[q]*kp[q];
    kf[q] = krl[q]*(1.0f + (av[q]-1.0f)*kal[q]);
  }
  ss = redgrp<8>(ss);
  float inv = 1.0f / fmaxf(sqrtf(ss), 1e-12f);
  float4 o;
  o.x=dec[0];o.y=dec[1];o.z=dec[2];o.w=dec[3];  *(float4*)(decay+off)=o;
  o.x=kf[0]; o.y=kf[1]; o.z=kf[2]; o.w=kf[3];   *(float4*)(kfin+off)=o;
  o.x=vv[0]; o.y=vv[1]; o.z=vv[2]; o.w=vv[3];   *(float4*)(vfin+off)=o;
  o.x=-kp[0]*inv; o.y=-kp[1]*inv; o.z=-kp[2]*inv; o.w=-kp[3]*inv; *(float4*)(Ak+off)=o;
  o.x=kp[0]*inv*av[0]; o.y=kp[1]*inv*av[1]; o.z=kp[2]*inv*av[2]; o.w=kp[3]*inv*av[3];
  *(float4*)(Bk+off)=o;
}

// ===== WKV-7 warmup-chunked scan (decay<=e^-0.5 => 32-step influence ~1e-7)
__global__ __launch_bounds__(512) void wkv_kernel(
    const float* __restrict__ decay, const float* __restrict__ Ak,
    const float* __restrict__ Bk, const float* __restrict__ kfin,
    const float* __restrict__ r_, const float* __restrict__ vfin,
    const float* __restrict__ S0, float* __restrict__ y) {
  __shared__ float lds[2][6][CH][64];
  int bid = blockIdx.x;
  int bh = bid & 31, c = bid >> 5;
  int bb = bh >> 4, h = bh & 15;
  int tid = threadIdx.x;
  int wave = tid >> 6, lane = tid & 63;
  int rg = tid >> 4;                  // 0..31
  int bj = tid & 15, j0 = bj*4;
  int r0 = rg, r1 = rg + 32;
  float Sa_[4] = {0.f,0.f,0.f,0.f};
  float Sb_[4] = {0.f,0.f,0.f,0.f};
  if (c == 0) {
    float4 t0 = *(const float4*)(S0 + (size_t)bh*4096 + r0*64 + j0);
    float4 t1 = *(const float4*)(S0 + (size_t)bh*4096 + r1*64 + j0);
    Sa_[0]=t0.x; Sa_[1]=t0.y; Sa_[2]=t0.z; Sa_[3]=t0.w;
    Sb_[0]=t1.x; Sb_[1]=t1.y; Sb_[2]=t1.z; Sb_[3]=t1.w;
  }
  size_t seqb = (size_t)bb*Tt;
  int t0g = (c==0) ? 0 : (c*CL - WU);
  int NPH = (c==0) ? (CL/CH) : ((CL+WU)/CH);
  int phE = (c==0) ? 0 : (WU/CH);
  int lhi = lane >> 4, llo4 = (lane & 15)*4;

  #define WST1(buf, stepb, arr, base, ldv) { \
    const float* gp_ = (base) + (size_t)(seqb + (size_t)(stepb) + lhi)*(ldv) + h*64 + llo4; \
    _Pragma("unroll") \
    for (int p_=0; p_<4; ++p_) \
      gload16(gp_ + (size_t)p_*4*(ldv), &lds[buf][arr][p_*4][0]); }
  #define WSTAGE(buf, stepb) { \
    if (wave==0)      { WST1(buf, stepb, 0, decay, Cc) } \
    else if (wave==1) { WST1(buf, stepb, 1, Ak, Cc) } \
    else if (wave==2) { WST1(buf, stepb, 2, Bk, Cc) } \
    else if (wave==3) { WST1(buf, stepb, 3, kfin, Cc) } \
    else if (wave==4) { WST1(buf, stepb, 4, r_, BIGN) } \
    else if (wave==5) { WST1(buf, stepb, 5, vfin, Cc) } }

  WSTAGE(0, t0g);
  for (int ph = 0; ph < NPH; ++ph) {
    int cur = ph & 1;
    if (ph+1 < NPH) {
      WSTAGE(cur^1, t0g + (ph+1)*CH);
      asm volatile("s_waitcnt vmcnt(4)\n\ts_barrier" ::: "memory");
    } else {
      asm volatile("s_waitcnt vmcnt(0)\n\ts_barrier" ::: "memory");
    }
    bool emit = (ph >= phE);
    const float* L0 = &lds[cur][0][0][0];
    #pragma unroll
    for (int s = 0; s < CH; ++s) {
      const float* bp = L0 + s*64;
      float4 d4 = *(const float4*)(bp + 0*CH*64 + j0);
      float4 a4 = *(const float4*)(bp + 1*CH*64 + j0);
      float4 b4 = *(const float4*)(bp + 2*CH*64 + j0);
      float4 k4 = *(const float4*)(bp + 3*CH*64 + j0);
      float4 r4 = *(const float4*)(bp + 4*CH*64 + j0);
      float v0 = bp[5*CH*64 + r0];
      float v1 = bp[5*CH*64 + r1];
      Sa_[0]*=d4.x; Sa_[1]*=d4.y; Sa_[2]*=d4.z; Sa_[3]*=d4.w;
      Sb_[0]*=d4.x; Sb_[1]*=d4.y; Sb_[2]*=d4.z; Sb_[3]*=d4.w;
      float sa0 = fmaf(Sa_[0],a4.x, Sa_[1]*a4.y) + fmaf(Sa_[2],a4.z, Sa_[3]*a4.w);
      float sa1 = fmaf(Sb_[0],a4.x, Sb_[1]*a4.y) + fmaf(Sb_[2],a4.z, Sb_[3]*a4.w);
      sa0 = red16(sa0);
      sa1 = red16(sa1);
      Sa_[0]=fmaf(v0,k4.x,Sa_[0]); Sa_[1]=fmaf(v0,k4.y,Sa_[1]);
      Sa_[2]=fmaf(v0,k4.z,Sa_[2]); Sa_[3]=fmaf(v0,k4.w,Sa_[3]);
      Sa_[0]=fmaf(sa0,b4.x,Sa_[0]); Sa_[1]=fmaf(sa0,b4.y,Sa_[1]);
      Sa_[2]=fmaf(sa0,b4.z,Sa_[2]); Sa_[3]=fmaf(sa0,b4.w,Sa_[3]);
      Sb_[0]=fmaf(v1,k4.x,Sb_[0]); Sb_[1]=fmaf(v1,k4.y,Sb_[1]);
      Sb_[2]=fmaf(v1,k4.z,Sb_[2]); Sb_[3]=fmaf(v1,k4.w,Sb_[3]);
      Sb_[0]=fmaf(sa1,b4.x,Sb_[0]); Sb_[1]=fmaf(sa1,b4.y,Sb_[1]);
      Sb_[2]=fmaf(sa1,b4.z,Sb_[2]); Sb_[3]=fmaf(sa1,b4.w,Sb_[3]);
      if (emit) {
        float y0 = fmaf(Sa_[0],r4.x, Sa_[1]*r4.y) + fmaf(Sa_[2],r4.z, Sa_[3]*r4.w);
        float y1 = fmaf(Sb_[0],r4.x, Sb_[1]*r4.y) + fmaf(Sb_[2],r4.z, Sb_[3]*r4.w);
        y0 = red16(y0);
        y1 = red16(y1);
        if (bj == 0) {
          size_t yo = (seqb + (size_t)t0g + ph*CH + s)*Cc + h*64;
          y[yo + r0] = y0;
          y[yo + r1] = y1;
        }
      }
    }
    asm volatile("s_barrier" ::: "memory");
  }
  #undef WSTAGE
  #undef WST1
}

// ---------------- GroupNorm(head) + r.k.r_k bonus + *g -> bf16 ---------------
__global__ __launch_bounds__(256) void gn_kernel(
    const float* __restrict__ y, const float* __restrict__ r_,
    const float* __restrict__ kfin, const float* __restrict__ vfin,
    const float* __restrict__ g_, const float* __restrict__ lnxw,
    const float* __restrict__ lnxb, const float* __restrict__ r_k,
    u16* __restrict__ Ao) {
  int row = blockIdx.x; int tid = threadIdx.x; int c = tid*4;
  size_t off = (size_t)row*Cc + c;
  float4 y4 = *(const float4*)(y+off);
  float s = y4.x+y4.y+y4.z+y4.w;
  float q = y4.x*y4.x+y4.y*y4.y+y4.z*y4.z+y4.w*y4.w;
  s = redgrp<8>(s); q = redgrp<8>(q);
  float mu = s*(1.0f/64.0f);
  float var = q*(1.0f/64.0f) - mu*mu;
  float rn = rsqrtf(var + 64e-5f);
  float4 rr = *(const float4*)(r_ + (size_t)row*BIGN + c);
  float4 kk = *(const float4*)(kfin+off);
  float4 vv = *(const float4*)(vfin+off);
  float4 gg = *(const float4*)(g_ + (size_t)row*BIGW + c);
  int h = tid >> 4; int hs = (tid & 15)*4;
  float4 rk = *(const float4*)(r_k + h*64 + hs);
  float dp = rr.x*kk.x*rk.x + rr.y*kk.y*rk.y + rr.z*kk.z*rk.z + rr.w*kk.w*rk.w;
  dp = redgrp<8>(dp);
  float4 w4 = *(const float4*)(lnxw+c);
  float4 b4 = *(const float4*)(lnxb+c);
  float o0 = (((y4.x-mu)*rn)*w4.x + b4.x + dp*vv.x) * gg.x;
  float o1 = (((y4.y-mu)*rn)*w4.y + b4.y + dp*vv.y) * gg.y;
  float o2 = (((y4.z-mu)*rn)*w4.z + b4.z + dp*vv.z) * gg.z;
  float o3 = (((y4.w-mu)*rn)*w4.w + b4.w + dp*vv.w) * gg.w;
  uint2 p = {pack_bf16(o0,o1), pack_bf16(o2,o3)};
  *(uint2*)(Ao + off) = p;
}

extern "C" void kernel_launch(void* const* d_in, const int* in_sizes, int n_in,
                              void* d_out, int out_size, void* d_ws, size_t ws_size,
                              hipStream_t stream) {
  const float* x      = (const float*)d_in[0];
  const float* vfirst = (const float*)d_in[1];
  const float* S0     = (const float*)d_in[2];
  const float* ln1w   = (const float*)d_in[3];
  const float* ln1b   = (const float*)d_in[4];
  const float* ln2w   = (const float*)d_in[5];
  const float* ln2b   = (const float*)d_in[6];
  const float* x_r    = (const float*)d_in[7];
  const float* x_w    = (const float*)d_in[8];
  const float* x_k    = (const float*)d_in[9];
  const float* x_v    = (const float*)d_in[10];
  const float* x_a    = (const float*)d_in[11];
  const float* x_g    = (const float*)d_in[12];
  const float* w0     = (const float*)d_in[13];
  const float* w1     = (const float*)d_in[14];
  const float* w2     = (const float*)d_in[15];
  const float* a0     = (const float*)d_in[16];
  const float* a1     = (const float*)d_in[17];
  const float* a2     = (const float*)d_in[18];
  const float* v0     = (const float*)d_in[19];
  const float* v1     = (const float*)d_in[20];
  const float* v2     = (const float*)d_in[21];
  const float* g1     = (const float*)d_in[22];
  const float* g2     = (const float*)d_in[23];
  const float* k_k    = (const float*)d_in[24];
  const float* k_a    = (const float*)d_in[25];
  const float* r_k    = (const float*)d_in[26];
  const float* W_r    = (const float*)d_in[27];
  const float* W_k    = (const float*)d_in[28];
  const float* W_v    = (const float*)d_in[29];
  const float* W_o    = (const float*)d_in[30];
  const float* lnxw   = (const float*)d_in[31];
  const float* lnxb   = (const float*)d_in[32];
  const float* mixk   = (const float*)d_in[33];
  const float* Wkey   = (const float*)d_in[34];
  const float* Wval   = (const float*)d_in[35];
  float* out = (float*)d_out;
  float* ws  = (float*)d_ws;
  const size_t U = (size_t)BT * Cc;
  float* u[14];
  for (int i=0;i<14;++i) u[i] = ws + i*U;

  u16* bigA   = (u16*)u[0];
  u16* BigB   = (u16*)u[1];
  float* bigOut = u[2];     // [4096][3584] f32 (58.7MB, u2..u5)
  float* dwdavg = u[6];     // [4096][4096] f32 (u6..u9)
  u16* W2blk  = (u16*)u[10];
  u16* loraAct= (u16*)u[11];
  float* Bk   = u[0];
  float* y_   = u[1];
  u16* gnb    = (u16*)u[10];
  u16* Wob    = (u16*)u[13];
  float* xo   = u[0];
  u16* Wkeyb  = (u16*)u[6];
  u16* cmb    = (u16*)u[7];
  u16* Wvalb  = (u16*)u[8];
  u16* midb   = (u16*)u[2];

  dim3 b256(256);
  packW_kernel<<<dim3(Cc,3), b256, 0, stream>>>(W_r, W_k, W_v, x_r, x_k, x_v, BigB);
  packL_kernel<<<320, b256, 0, stream>>>(w1, a1, v1, g1, x_w, x_a, x_v, x_g, BigB);
  packW2_kernel<<<BIGW, dim3(320), 0, stream>>>(w2, a2, v2, g2, W2blk);
  lnmix1_kernel<<<BT, b256, 0, stream>>>(x, ln1w, ln1b, bigA);
  // 8-phase 256^2 GEMM (pad cols 3392..3583 are garbage, never read)
  gemm8<0><<<(BT/256)*(BIGN/256), dim3(512), 0, stream>>>(bigA, BigB, bigOut, BT, BIGN, BIGK);
  actcvt_kernel<<<BT, dim3(320), 0, stream>>>(bigOut, loraAct);
  gemm_bf16<0,128><<<(BT/128)*(BIGW/128), b256, 0, stream>>>(loraAct, W2blk, dwdavg, nullptr, BT, BIGW, LORAK);
  prep_kernel<<<BT, b256, 0, stream>>>(bigOut+1024, dwdavg, dwdavg+1024, dwdavg+2048,
      bigOut+2048, vfirst, w0, a0, v0, k_k, k_a, u[10], u[11], u[12], u[13], Bk);
  wkv_kernel<<<32*(Tt/CL), dim3(512), 0, stream>>>(u[10], u[13], Bk, u[11], bigOut, u[12], S0, y_);
  gn_kernel<<<BT, b256, 0, stream>>>(y_, bigOut, u[11], u[12], dwdavg+3072, lnxw, lnxb, r_k, gnb);
  cvtall_kernel<<<(Cc*Cc + FFNd*Cc*2 + BT*Cc)/2048, b256, 0, stream>>>(
      W_o, Wob, Wkey, Wkeyb, Wval, Wvalb, vfirst, out + (size_t)BT*Cc);
  gemm_bf16<1,64><<<(BT/128)*(Cc/64), b256, 0, stream>>>(gnb, Wob, xo, x, BT, Cc, Cc);
  lnmix2_kernel<<<BT, b256, 0, stream>>>(xo, ln2w, ln2b, mixk, cmb);
  // 8-phase for FFN-key (N=4096)
  gemm8<2><<<(BT/256)*(FFNd/256), dim3(512), 0, stream>>>(cmb, Wkeyb, midb, BT, FFNd, Cc);
  gemm_bf16<1,64><<<(BT/128)*(Cc/64), b256, 0, stream>>>(midb, Wvalb, out, xo, BT, Cc, FFNd);
}

// Round 19
// 373.351 us; speedup vs baseline: 1.1780x; 1.0100x over previous
//
#include <hip/hip_runtime.h>
#include <math.h>

#define Bb 2
#define Tt 2048
#define Cc 1024
#define Hh 16
#define BT 4096
#define FFNd 4096
#define CH 16
#define CL 128
#define WU 16
#define BIGN 3584
#define BIGK 2048
#define LORAK 384
#define BIGW 4096
// big-B column layout: r@0 k@1024 v@2048 w@3072 a@3136 vl@3200 g@3232 (end 3392, pad->3584)
// loraAct/W2blk K padded 320 -> 384 (zeros) so gemm8 (even nt) applies
// dwdavg column layout: dw@0 da@1024 dv@2048 g@3072  (ld 4096)

typedef __attribute__((ext_vector_type(8))) short bf16x8;
typedef __attribute__((ext_vector_type(4))) float f32x4;
typedef unsigned short u16;

__device__ __forceinline__ float sgm(float x){ return 1.0f/(1.0f+expf(-x)); }

template<int MAXM>
__device__ __forceinline__ float redgrp(float v){
  #pragma unroll
  for (int m=1; m<=MAXM; m<<=1) v += __shfl_xor(v, m, 64);
  return v;
}

template<int CTRL>
__device__ __forceinline__ float dppadd(float v){
  union { float f; int i; } u, r;
  u.f = v;
  r.i = __builtin_amdgcn_update_dpp(u.i, u.i, CTRL, 0xf, 0xf, true);
  return v + r.f;
}
__device__ __forceinline__ float red16(float v){
  v = dppadd<0xB1>(v);
  v = dppadd<0x4E>(v);
  v = dppadd<0x141>(v);
  v = dppadd<0x140>(v);
  return v;
}

__device__ __forceinline__ unsigned pack_bf16(float a, float b){
  unsigned ua = __builtin_bit_cast(unsigned, a);
  unsigned ub = __builtin_bit_cast(unsigned, b);
  ua = (ua + 0x7FFFu + ((ua>>16)&1u)) >> 16;
  ub = (ub + 0x7FFFu + ((ub>>16)&1u)) >> 16;
  return ua | (ub<<16);
}
__device__ __forceinline__ u16 bf16_1(float a){
  unsigned ua = __builtin_bit_cast(unsigned, a);
  return (u16)((ua + 0x7FFFu + ((ua>>16)&1u)) >> 16);
}

__device__ __forceinline__ void gload16(const void* g, void* l){
  __builtin_amdgcn_global_load_lds(
    (const __attribute__((address_space(1))) unsigned int*)g,
    (__attribute__((address_space(3))) unsigned int*)l, 16, 0, 0);
}

// ------- fused f32->bf16 convert of three weights + v_first passthrough ------
__device__ __forceinline__ void cvt8(const float* __restrict__ in,
    u16* __restrict__ out, size_t i){
  float4 a = ((const float4*)in)[2*i];
  float4 b = ((const float4*)in)[2*i+1];
  uint4 o = {pack_bf16(a.x,a.y), pack_bf16(a.z,a.w),
             pack_bf16(b.x,b.y), pack_bf16(b.z,b.w)};
  ((uint4*)out)[i] = o;
}
__global__ __launch_bounds__(256) void cvtall_kernel(
    const float* __restrict__ wo, u16* __restrict__ wob,
    const float* __restrict__ wk, u16* __restrict__ wkb,
    const float* __restrict__ wv, u16* __restrict__ wvb,
    const float* __restrict__ csrc, float* __restrict__ cdst) {
  size_t i = (size_t)blockIdx.x*256 + threadIdx.x;
  const size_t NA = (size_t)Cc*Cc/8;       // 131072
  const size_t NB = (size_t)FFNd*Cc/8;     // 524288
  if (i < NA) cvt8(wo, wob, i);
  else if (i < NA+NB) cvt8(wk, wkb, i-NA);
  else if (i < NA+2*NB) cvt8(wv, wvb, i-NA-NB);
  else {
    size_t j = i - NA - 2*NB;              // 0..BT*Cc/8
    float4 a = ((const float4*)csrc)[2*j];
    float4 b = ((const float4*)csrc)[2*j+1];
    ((float4*)cdst)[2*j] = a;
    ((float4*)cdst)[2*j+1] = b;
  }
}

// ---------------- pack square weights into BigB rows: [W | diag(mix)W] -------
__global__ __launch_bounds__(256) void packW_kernel(const float* __restrict__ Wr,
    const float* __restrict__ Wk, const float* __restrict__ Wv,
    const float* __restrict__ xr, const float* __restrict__ xk,
    const float* __restrict__ xv, u16* __restrict__ out) {
  int which = blockIdx.y;
  const float* W   = which==0 ? Wr : (which==1 ? Wk : Wv);
  const float* mix = which==0 ? xr : (which==1 ? xk : xv);
  u16* o = out + (size_t)which*1024*BIGK;
  int n = blockIdx.x;             // 0..1023
  int c0 = threadIdx.x*8;         // 0..2040
  int ks = c0 & 1023;
  const float* src = W + (size_t)n*Cc + ks;
  float4 a = *(const float4*)src;
  float4 b = *(const float4*)(src+4);
  if (c0 >= 1024){
    float4 m0 = *(const float4*)(mix + ks);
    float4 m1 = *(const float4*)(mix + ks + 4);
    a.x*=m0.x; a.y*=m0.y; a.z*=m0.z; a.w*=m0.w;
    b.x*=m1.x; b.y*=m1.y; b.z*=m1.z; b.w*=m1.w;
  }
  uint4 ov = {pack_bf16(a.x,a.y), pack_bf16(a.z,a.w),
              pack_bf16(b.x,b.y), pack_bf16(b.z,b.w)};
  *(uint4*)(o + (size_t)n*BIGK + c0) = ov;
}

// ---------------- pack lora W1[C,D] (transposed) into BigB rows --------------
__global__ __launch_bounds__(256) void packL_kernel(const float* __restrict__ w1,
    const float* __restrict__ a1, const float* __restrict__ v1,
    const float* __restrict__ g1, const float* __restrict__ x_w,
    const float* __restrict__ x_a, const float* __restrict__ x_v,
    const float* __restrict__ x_g, u16* __restrict__ out) {
  int bid = blockIdx.x;           // 0..319
  const float* W1; const float* mix; int D, d, nbase;
  if (bid < 64)       { W1=w1; mix=x_w; D=64;  d=bid;     nbase=3072; }
  else if (bid < 128) { W1=a1; mix=x_a; D=64;  d=bid-64;  nbase=3136; }
  else if (bid < 160) { W1=v1; mix=x_v; D=32;  d=bid-128; nbase=3200; }
  else                { W1=g1; mix=x_g; D=160; d=bid-160; nbase=3232; }
  int k0 = threadIdx.x*8;
  float v[8];
  #pragma unroll
  for (int q=0;q<8;++q){
    int kk = k0+q;
    int ks = kk & 1023;
    float t = W1[(size_t)ks*D + d];
    if (kk >= 1024) t *= mix[ks];
    v[q] = t;
  }
  uint4 o = {pack_bf16(v[0],v[1]), pack_bf16(v[2],v[3]),
             pack_bf16(v[4],v[5]), pack_bf16(v[6],v[7])};
  *(uint4*)(out + (size_t)(nbase+d)*BIGK + k0) = o;
}

// --- pack block-diagonal W2: out[n][k] bf16, n in [0,4096) k in [0,384) ------
__global__ __launch_bounds__(384) void packW2_kernel(const float* __restrict__ w2,
    const float* __restrict__ a2, const float* __restrict__ v2,
    const float* __restrict__ g2, u16* __restrict__ out) {
  int n = blockIdx.x; int k = threadIdx.x;
  int which = n >> 10, col = n & 1023;
  float v = 0.f;
  if (which==0)      { if (k < 64)              v = w2[(size_t)k*Cc + col]; }
  else if (which==1) { if (k >= 64 && k < 128)  v = a2[(size_t)(k-64)*Cc + col]; }
  else if (which==2) { if (k >= 128 && k < 160) v = v2[(size_t)(k-128)*Cc + col]; }
  else               { if (k >= 160 && k < 320) v = g2[(size_t)(k-160)*Cc + col]; }
  out[(size_t)n*LORAK + k] = bf16_1(v);
}

// --- act + cvt lora columns of bigOut -> loraAct bf16 [4096][384] (padded) ---
__global__ __launch_bounds__(384) void actcvt_kernel(const float* __restrict__ m,
    u16* __restrict__ loraAct) {
  int i = blockIdx.x; int cc = threadIdx.x;
  float v = 0.f;
  if (cc < 320) {
    v = m[(size_t)i*BIGN + 3072 + cc];
    if (cc < 64) v = tanhf(v);
    else if (cc >= 160) v = sgm(v);
  }
  loraAct[(size_t)i*LORAK + cc] = bf16_1(v);
}

// ---------------- fused LN1 -> bigA = [xn | xx] bf16 -------------------------
__global__ __launch_bounds__(256) void lnmix1_kernel(const float* __restrict__ x,
    const float* __restrict__ w, const float* __restrict__ b,
    u16* __restrict__ bigA) {
  int rowg = blockIdx.x; int t = rowg & (Tt-1);
  int tid = threadIdx.x;
  size_t off = (size_t)rowg*Cc + tid*4;
  float4 vc = *(const float4*)(x + off);
  float4 vp = {0.f,0.f,0.f,0.f};
  if (t) vp = *(const float4*)(x + off - Cc);
  float sc = vc.x+vc.y+vc.z+vc.w;
  float qc = vc.x*vc.x+vc.y*vc.y+vc.z*vc.z+vc.w*vc.w;
  float sp = vp.x+vp.y+vp.z+vp.w;
  float qp = vp.x*vp.x+vp.y*vp.y+vp.z*vp.z+vp.w*vp.w;
  sc = redgrp<32>(sc); qc = redgrp<32>(qc);
  sp = redgrp<32>(sp); qp = redgrp<32>(qp);
  __shared__ float rbuf[4][4];
  int lane = tid & 63, wv = tid >> 6;
  if (lane==0){ rbuf[wv][0]=sc; rbuf[wv][1]=qc; rbuf[wv][2]=sp; rbuf[wv][3]=qp; }
  __syncthreads();
  sc = rbuf[0][0]+rbuf[1][0]+rbuf[2][0]+rbuf[3][0];
  qc = rbuf[0][1]+rbuf[1][1]+rbuf[2][1]+rbuf[3][1];
  sp = rbuf[0][2]+rbuf[1][2]+rbuf[2][2]+rbuf[3][2];
  qp = rbuf[0][3]+rbuf[1][3]+rbuf[2][3]+rbuf[3][3];
  float muc = sc*(1.0f/Cc), mup = sp*(1.0f/Cc);
  float rnc = rsqrtf(qc*(1.0f/Cc) - muc*muc + 1e-5f);
  float rnp = rsqrtf(qp*(1.0f/Cc) - mup*mup + 1e-5f);
  float4 w4 = *(const float4*)(w + tid*4);
  float4 b4 = *(const float4*)(b + tid*4);
  float vcl[4]={vc.x,vc.y,vc.z,vc.w};
  float vpl[4]={vp.x,vp.y,vp.z,vp.w};
  float wl[4]={w4.x,w4.y,w4.z,w4.w};
  float bl[4]={b4.x,b4.y,b4.z,b4.w};
  float xnc[4], xx[4];
  #pragma unroll
  for (int q=0;q<4;++q){
    xnc[q] = (vcl[q]-muc)*rnc*wl[q] + bl[q];
    float xnp = t ? ((vpl[q]-mup)*rnp*wl[q] + bl[q]) : 0.0f;
    xx[q] = xnp - xnc[q];
  }
  size_t ab = (size_t)rowg*BIGK + tid*4;
  uint2 p0 = {pack_bf16(xnc[0],xnc[1]), pack_bf16(xnc[2],xnc[3])};
  uint2 p1 = {pack_bf16(xx[0],xx[1]),   pack_bf16(xx[2],xx[3])};
  *(uint2*)(bigA + ab) = p0;
  *(uint2*)(bigA + ab + 1024) = p1;
}

// ---------------- fused LN2 + cmix -> bf16 -----------------------------------
__global__ __launch_bounds__(256) void lnmix2_kernel(const float* __restrict__ x,
    const float* __restrict__ w, const float* __restrict__ b,
    const float* __restrict__ mixk, u16* __restrict__ outb) {
  int rowg = blockIdx.x; int t = rowg & (Tt-1);
  int tid = threadIdx.x;
  size_t off = (size_t)rowg*Cc + tid*4;
  float4 vc = *(const float4*)(x + off);
  float4 vp = {0.f,0.f,0.f,0.f};
  if (t) vp = *(const float4*)(x + off - Cc);
  float sc = vc.x+vc.y+vc.z+vc.w;
  float qc = vc.x*vc.x+vc.y*vc.y+vc.z*vc.z+vc.w*vc.w;
  float sp = vp.x+vp.y+vp.z+vp.w;
  float qp = vp.x*vp.x+vp.y*vp.y+vp.z*vp.z+vp.w*vp.w;
  sc = redgrp<32>(sc); qc = redgrp<32>(qc);
  sp = redgrp<32>(sp); qp = redgrp<32>(qp);
  __shared__ float rbuf[4][4];
  int lane = tid & 63, wv = tid >> 6;
  if (lane==0){ rbuf[wv][0]=sc; rbuf[wv][1]=qc; rbuf[wv][2]=sp; rbuf[wv][3]=qp; }
  __syncthreads();
  sc = rbuf[0][0]+rbuf[1][0]+rbuf[2][0]+rbuf[3][0];
  qc = rbuf[0][1]+rbuf[1][1]+rbuf[2][1]+rbuf[3][1];
  sp = rbuf[0][2]+rbuf[1][2]+rbuf[2][2]+rbuf[3][2];
  qp = rbuf[0][3]+rbuf[1][3]+rbuf[2][3]+rbuf[3][3];
  float muc = sc*(1.0f/Cc), mup = sp*(1.0f/Cc);
  float rnc = rsqrtf(qc*(1.0f/Cc) - muc*muc + 1e-5f);
  float rnp = rsqrtf(qp*(1.0f/Cc) - mup*mup + 1e-5f);
  float4 w4 = *(const float4*)(w + tid*4);
  float4 b4 = *(const float4*)(b + tid*4);
  float4 m = *(const float4*)(mixk + tid*4);
  float vcl[4]={vc.x,vc.y,vc.z,vc.w};
  float vpl[4]={vp.x,vp.y,vp.z,vp.w};
  float wl[4]={w4.x,w4.y,w4.z,w4.w};
  float bl[4]={b4.x,b4.y,b4.z,b4.w};
  float ml[4]={m.x,m.y,m.z,m.w};
  float o[4];
  #pragma unroll
  for (int q=0;q<4;++q){
    float xnc = (vcl[q]-muc)*rnc*wl[q] + bl[q];
    float xnp = t ? ((vpl[q]-mup)*rnp*wl[q] + bl[q]) : 0.0f;
    o[q] = xnc + (xnp - xnc)*ml[q];
  }
  uint2 p = {pack_bf16(o[0],o[1]), pack_bf16(o[2],o[3])};
  *(uint2*)(outb + off) = p;
}

// ===== 8-phase 256x256 bf16 GEMM, 8 waves (2Mx4N), BK=64 =====================
// out = A[M,K] @ W[N,K]^T.  MODE 0: f32 out   2: bf16 relu(acc)^2
// LDS 128KB = [parity][half][128][64] per operand. One 128x64 half-tile staged
// per phase (wave-uniform dest; source pre-swizzled -> T2 slot=chunk^(row&7)).
// Counted vmcnt(2) at ph0/ph4 certifies current K-tile; vmcnt(0) last iter.
// Requires nt = K/64 even.
template<int MODE>
__global__ __launch_bounds__(512) void gemm8(const u16* __restrict__ A,
    const u16* __restrict__ W, void* __restrict__ outv, int M, int N, int K) {
  __shared__ u16 As[2*2*128*64];
  __shared__ u16 Bs[2*2*128*64];
  int tid = threadIdx.x;
  int nwg = gridDim.x;
  int q8 = nwg >> 3;
  int id = (blockIdx.x & 7)*q8 + (blockIdx.x >> 3);   // bijective (nwg%8==0)
  int nbx = N >> 8;
  int bm = id / nbx, bn = id - bm*nbx;
  int wave = tid >> 6, lane = tid & 63;
  int wm = wave >> 2, wn = wave & 3;                  // 2M x 4N waves
  int lrow = lane & 15, lk8 = lane >> 4;
  int r7 = lrow & 7;
  int bhlf = wn >> 1;                                 // B half this wave reads
  int chb = (wn & 1)*64;                              // col base within half
  int sw = wave*16;
  int sl8 = lane >> 3;                                // 0..7
  int schunk = ((lane & 7) ^ sl8) * 8;                // T2 pre-swizzled k-col
  int nt = K >> 6;
  int lastJ = (nt >> 1) - 1;
  f32x4 acc[8][4];
  f32x4 zero = {0.f,0.f,0.f,0.f};
  #pragma unroll
  for (int i=0;i<8;++i)
    #pragma unroll
    for (int j=0;j<4;++j) acc[i][j] = zero;

  #define STGA(T, h) { \
    const u16* s_ = A + (size_t)(bm*256 + (h)*128 + sw + sl8)*K + (size_t)(T)*64 + schunk; \
    char* d_ = (char*)As + (((T)&1)*32768 + (h)*16384) + wave*2048; \
    gload16(s_, d_); \
    gload16(s_ + (size_t)8*K, d_ + 1024); }
  #define STGB(T, h) { \
    const u16* s_ = W + (size_t)(bn*256 + (h)*128 + sw + sl8)*K + (size_t)(T)*64 + schunk; \
    char* d_ = (char*)Bs + (((T)&1)*32768 + (h)*16384) + wave*2048; \
    gload16(s_, d_); \
    gload16(s_ + (size_t)8*K, d_ + 1024); }
  #define RDA(T, mh) { \
    _Pragma("unroll") \
    for (int ii=0; ii<4; ++ii) \
      _Pragma("unroll") \
      for (int kk=0; kk<2; ++kk) \
        Am[ii][kk] = *(const bf16x8*)&As[((T)&1)*16384 + wm*8192 + \
          ((mh)*64 + ii*16 + lrow)*64 + ((kk*4 + lk8) ^ r7)*8]; }
  #define RDB(T, nh, Bd) { \
    _Pragma("unroll") \
    for (int jj=0; jj<2; ++jj) \
      _Pragma("unroll") \
      for (int kk=0; kk<2; ++kk) \
        Bd[jj][kk] = *(const bf16x8*)&Bs[((T)&1)*16384 + bhlf*8192 + \
          (chb + ((nh)*2+jj)*16 + lrow)*64 + ((kk*4 + lk8) ^ r7)*8]; }
  #define QMM(mh, nh, Bd) { \
    __builtin_amdgcn_s_setprio(1); \
    _Pragma("unroll") \
    for (int ii=0; ii<4; ++ii) \
      _Pragma("unroll") \
      for (int jj=0; jj<2; ++jj) \
        _Pragma("unroll") \
        for (int kk=0; kk<2; ++kk) \
          acc[(mh)*4+ii][(nh)*2+jj] = __builtin_amdgcn_mfma_f32_16x16x32_bf16( \
            Am[ii][kk], Bd[jj][kk], acc[(mh)*4+ii][(nh)*2+jj], 0, 0, 0); \
    __builtin_amdgcn_s_setprio(0); }

  bf16x8 Am[4][2], B0f[2][2], B1f[2][2];
  STGA(0,0); STGA(0,1); STGB(0,0); STGB(0,1); STGA(1,0);
  for (int J = 0; J <= lastJ; ++J) {
    int T0 = 2*J, T1 = 2*J+1;
    bool more = (J < lastJ);
    asm volatile("s_waitcnt vmcnt(2)\n\ts_barrier" ::: "memory");
    RDA(T0, 0); RDB(T0, 0, B0f);
    STGA(T1, 1);
    QMM(0, 0, B0f);
    asm volatile("s_barrier" ::: "memory");
    RDB(T0, 1, B1f);
    STGB(T1, 0);
    QMM(0, 1, B1f);
    asm volatile("s_barrier" ::: "memory");
    RDA(T0, 1);
    STGB(T1, 1);
    QMM(1, 0, B0f);
    asm volatile("s_barrier" ::: "memory");
    if (more) STGA(T0+2, 0);
    QMM(1, 1, B1f);
    if (more) asm volatile("s_waitcnt vmcnt(2)\n\ts_barrier" ::: "memory");
    else      asm volatile("s_waitcnt vmcnt(0)\n\ts_barrier" ::: "memory");
    RDA(T1, 0); RDB(T1, 0, B0f);
    if (more) STGA(T0+2, 1);
    QMM(0, 0, B0f);
    asm volatile("s_barrier" ::: "memory");
    RDB(T1, 1, B1f);
    if (more) STGB(T0+2, 0);
    QMM(0, 1, B1f);
    asm volatile("s_barrier" ::: "memory");
    RDA(T1, 1);
    if (more) STGB(T0+2, 1);
    QMM(1, 0, B0f);
    asm volatile("s_barrier" ::: "memory");
    if (more) STGA(T0+3, 0);
    QMM(1, 1, B1f);
  }
  #undef STGA
  #undef STGB
  #undef RDA
  #undef RDB
  #undef QMM
  float* outf = (float*)outv;
  u16* outb = (u16*)outv;
  int crow4 = (lane>>4)*4, ccol = lane & 15;
  #pragma unroll
  for (int i=0;i<8;++i){
    #pragma unroll
    for (int j=0;j<4;++j){
      int gr = bm*256 + wm*128 + i*16 + crow4;
      int gc = bn*256 + wn*64 + j*16 + ccol;
      #pragma unroll
      for (int q=0;q<4;++q){
        float v = acc[i][j][q];
        size_t o = (size_t)(gr+q)*N + gc;
        if (MODE==2) { v = fmaxf(v, 0.f); outb[o] = bf16_1(v*v); }
        else outf[o] = v;
      }
    }
  }
}

// ============ bf16 GEMM (m97 structure), tile 128 x BN (BN=128|64) ===========
// out = A[M,K] @ W[N,K]^T.  MODE 0: f32   1: f32 res+acc   2: bf16 relu(acc)^2
template<int MODE, int BN>
__global__ __launch_bounds__(256) void gemm_bf16(const u16* __restrict__ A,
    const u16* __restrict__ W, void* __restrict__ outv,
    const float* __restrict__ res, int M, int N, int K) {
  constexpr int NJ = BN/32;
  constexpr int NBCH = BN/32;
  __shared__ u16 As[2][128*64];
  __shared__ u16 Bs[2][BN*64];
  int tid = threadIdx.x;
  int nwg = gridDim.x;
  int q8 = nwg >> 3;
  int id = (blockIdx.x & 7)*q8 + (blockIdx.x >> 3);
  int nbx = N / BN;
  int bm = id / nbx, bn = id - bm*nbx;
  int wave = tid >> 6, lane = tid & 63;
  int wm = wave >> 1, wn = wave & 1;
  int srowA = wave*32 + (lane>>3);
  int srowB = wave*(BN/4) + (lane>>3);
  int scol = (((lane&7) ^ ((lane>>3)&7)))*8;
  const u16* Ag = A + (size_t)(bm*128 + srowA)*K + scol;
  const u16* Wg = W + (size_t)(bn*BN + srowB)*K + scol;
  int nt = K >> 6;
  f32x4 acc[4][NJ];
  f32x4 zero = {0.f,0.f,0.f,0.f};
  #pragma unroll
  for (int i=0;i<4;++i)
    #pragma unroll
    for (int j=0;j<NJ;++j) acc[i][j] = zero;

  #define STAGE(buf, t) { \
    const u16* Ag2 = Ag + (size_t)(t)*64; \
    const u16* Wg2 = Wg + (size_t)(t)*64; \
    _Pragma("unroll") \
    for (int i_=0;i_<4;++i_) \
      gload16(Ag2 + (size_t)i_*8*K, &As[buf][(wave*32+i_*8)*64]); \
    _Pragma("unroll") \
    for (int i_=0;i_<NBCH;++i_) \
      gload16(Wg2 + (size_t)i_*8*K, &Bs[buf][(wave*(BN/4)+i_*8)*64]); }

  STAGE(0, 0);
  int lrow = lane & 15, lk8 = lane >> 4;
  int r7 = lrow & 7;
  for (int t = 0; t < nt; ++t) {
    int cur = t & 1;
    if (t+1 < nt) {
      STAGE(cur^1, t+1);
      if (BN == 128) asm volatile("s_waitcnt vmcnt(8)\n\ts_barrier" ::: "memory");
      else           asm volatile("s_waitcnt vmcnt(6)\n\ts_barrier" ::: "memory");
    } else {
      asm volatile("s_waitcnt vmcnt(0)\n\ts_barrier" ::: "memory");
    }
    #pragma unroll
    for (int kk2 = 0; kk2 < 2; ++kk2) {
      int sl = ((kk2*4 + lk8) ^ r7) * 8;
      bf16x8 af[4], bfr[NJ];
      #pragma unroll
      for (int i=0;i<4;++i)
        af[i] = *(const bf16x8*)&As[cur][(wm*64 + i*16 + lrow)*64 + sl];
      #pragma unroll
      for (int j=0;j<NJ;++j)
        bfr[j] = *(const bf16x8*)&Bs[cur][(wn*(BN/2) + j*16 + lrow)*64 + sl];
      #pragma unroll
      for (int i=0;i<4;++i)
        #pragma unroll
        for (int j=0;j<NJ;++j)
          acc[i][j] = __builtin_amdgcn_mfma_f32_16x16x32_bf16(af[i], bfr[j], acc[i][j], 0, 0, 0);
    }
    asm volatile("s_barrier" ::: "memory");
  }
  #undef STAGE
  float* outf = (float*)outv;
  u16* outb = (u16*)outv;
  int crow4 = (lane>>4)*4, ccol = lane & 15;
  #pragma unroll
  for (int i=0;i<4;++i){
    #pragma unroll
    for (int j=0;j<NJ;++j){
      int gr = bm*128 + wm*64 + i*16 + crow4;
      int gc = bn*BN + wn*(BN/2) + j*16 + ccol;
      #pragma unroll
      for (int q=0;q<4;++q){
        float v = acc[i][j][q];
        size_t o = (size_t)(gr+q)*N + gc;
        if (MODE==1) { v += res[o]; outf[o] = v; }
        else if (MODE==2) { v = fmaxf(v, 0.f); outb[o] = bf16_1(v*v); }
        else outf[o] = v;
      }
    }
  }
}

// ---------------- prep: dw/da/dv from dwdavg (ld 4096), k/v from bigOut ------
__global__ __launch_bounds__(256) void prep_kernel(
    const float* __restrict__ kraw, const float* __restrict__ dw,
    const float* __restrict__ da, const float* __restrict__ dv,
    const float* __restrict__ vraw, const float* __restrict__ vfirst,
    const float* __restrict__ w0, const float* __restrict__ a0,
    const float* __restrict__ v0, const float* __restrict__ k_k,
    const float* __restrict__ k_a,
    float* __restrict__ decay, float* __restrict__ kfin, float* __restrict__ vfin,
    float* __restrict__ Ak, float* __restrict__ Bk) {
  int row = blockIdx.x; int tid = threadIdx.x; int c = tid*4;
  size_t off = (size_t)row*Cc + c;
  size_t offw = (size_t)row*BIGN + c;
  size_t offd = (size_t)row*BIGW + c;
  float4 kr = *(const float4*)(kraw+offw);
  float4 vr = *(const float4*)(vraw+offw);
  float4 w4 = *(const float4*)(dw+offd);
  float4 A4 = *(const float4*)(da+offd);
  float4 V4 = *(const float4*)(dv+offd);
  float4 vf = *(const float4*)(vfirst+off);
  float4 w04 = *(const float4*)(w0+c);
  float4 a04 = *(const float4*)(a0+c);
  float4 v04 = *(const float4*)(v0+c);
  float4 kk4 = *(const float4*)(k_k+c);
  float4 ka4 = *(const float4*)(k_a+c);
  float krl[4]={kr.x,kr.y,kr.z,kr.w};
  float dwl[4]={w4.x,w4.y,w4.z,w4.w};
  float dal[4]={A4.x,A4.y,A4.z,A4.w};
  float dvl[4]={V4.x,V4.y,V4.z,V4.w};
  float vrl[4]={vr.x,vr.y,vr.z,vr.w};
  float vfl[4]={vf.x,vf.y,vf.z,vf.w};
  float w0l[4]={w04.x,w04.y,w04.z,w04.w};
  float a0l[4]={a04.x,a04.y,a04.z,a04.w};
  float v0l[4]={v04.x,v04.y,v04.z,v04.w};
  float kkl[4]={kk4.x,kk4.y,kk4.z,kk4.w};
  float kal[4]={ka4.x,ka4.y,ka4.z,ka4.w};
  float av[4], dec[4], vv[4], kp[4], kf[4];
  float ss = 0.f;
  #pragma unroll
  for (int q=0;q<4;++q){
    av[q] = sgm(a0l[q] + dal[q]);
    dec[q] = 0.60653065971263342f * sgm(w0l[q] + dwl[q]);   // exp(-softplus(-u)-0.5)
    float sv = sgm(v0l[q] + dvl[q]);
    vv[q] = vrl[q] + (vfl[q]-vrl[q])*sv;
    kp[q] = krl[q]*kkl[q];
    ss += kp[q]*kp[q];
    kf[q] = krl[q]*(1.0f + (av[q]-1.0f)*kal[q]);
  }
  ss = redgrp<8>(ss);
  float inv = 1.0f / fmaxf(sqrtf(ss), 1e-12f);
  float4 o;
  o.x=dec[0];o.y=dec[1];o.z=dec[2];o.w=dec[3];  *(float4*)(decay+off)=o;
  o.x=kf[0]; o.y=kf[1]; o.z=kf[2]; o.w=kf[3];   *(float4*)(kfin+off)=o;
  o.x=vv[0]; o.y=vv[1]; o.z=vv[2]; o.w=vv[3];   *(float4*)(vfin+off)=o;
  o.x=-kp[0]*inv; o.y=-kp[1]*inv; o.z=-kp[2]*inv; o.w=-kp[3]*inv; *(float4*)(Ak+off)=o;
  o.x=kp[0]*inv*av[0]; o.y=kp[1]*inv*av[1]; o.z=kp[2]*inv*av[2]; o.w=kp[3]*inv*av[3];
  *(float4*)(Bk+off)=o;
}

// ===== WKV-7 warmup-chunked scan (decay<=e^-0.5 => 16-step influence ~3e-4)
__global__ __launch_bounds__(512) void wkv_kernel(
    const float* __restrict__ decay, const float* __restrict__ Ak,
    const float* __restrict__ Bk, const float* __restrict__ kfin,
    const float* __restrict__ r_, const float* __restrict__ vfin,
    const float* __restrict__ S0, float* __restrict__ y) {
  __shared__ float lds[2][6][CH][64];
  int bid = blockIdx.x;
  int bh = bid & 31, c = bid >> 5;
  int bb = bh >> 4, h = bh & 15;
  int tid = threadIdx.x;
  int wave = tid >> 6, lane = tid & 63;
  int rg = tid >> 4;                  // 0..31
  int bj = tid & 15, j0 = bj*4;
  int r0 = rg, r1 = rg + 32;
  float Sa_[4] = {0.f,0.f,0.f,0.f};
  float Sb_[4] = {0.f,0.f,0.f,0.f};
  if (c == 0) {
    float4 t0 = *(const float4*)(S0 + (size_t)bh*4096 + r0*64 + j0);
    float4 t1 = *(const float4*)(S0 + (size_t)bh*4096 + r1*64 + j0);
    Sa_[0]=t0.x; Sa_[1]=t0.y; Sa_[2]=t0.z; Sa_[3]=t0.w;
    Sb_[0]=t1.x; Sb_[1]=t1.y; Sb_[2]=t1.z; Sb_[3]=t1.w;
  }
  size_t seqb = (size_t)bb*Tt;
  int t0g = (c==0) ? 0 : (c*CL - WU);
  int NPH = (c==0) ? (CL/CH) : ((CL+WU)/CH);
  int phE = (c==0) ? 0 : (WU/CH);
  int lhi = lane >> 4, llo4 = (lane & 15)*4;

  #define WST1(buf, stepb, arr, base, ldv) { \
    const float* gp_ = (base) + (size_t)(seqb + (size_t)(stepb) + lhi)*(ldv) + h*64 + llo4; \
    _Pragma("unroll") \
    for (int p_=0; p_<4; ++p_) \
      gload16(gp_ + (size_t)p_*4*(ldv), &lds[buf][arr][p_*4][0]); }
  #define WSTAGE(buf, stepb) { \
    if (wave==0)      { WST1(buf, stepb, 0, decay, Cc) } \
    else if (wave==1) { WST1(buf, stepb, 1, Ak, Cc) } \
    else if (wave==2) { WST1(buf, stepb, 2, Bk, Cc) } \
    else if (wave==3) { WST1(buf, stepb, 3, kfin, Cc) } \
    else if (wave==4) { WST1(buf, stepb, 4, r_, BIGN) } \
    else if (wave==5) { WST1(buf, stepb, 5, vfin, Cc) } }

  WSTAGE(0, t0g);
  for (int ph = 0; ph < NPH; ++ph) {
    int cur = ph & 1;
    if (ph+1 < NPH) {
      WSTAGE(cur^1, t0g + (ph+1)*CH);
      asm volatile("s_waitcnt vmcnt(4)\n\ts_barrier" ::: "memory");
    } else {
      asm volatile("s_waitcnt vmcnt(0)\n\ts_barrier" ::: "memory");
    }
    bool emit = (ph >= phE);
    const float* L0 = &lds[cur][0][0][0];
    #pragma unroll
    for (int s = 0; s < CH; ++s) {
      const float* bp = L0 + s*64;
      float4 d4 = *(const float4*)(bp + 0*CH*64 + j0);
      float4 a4 = *(const float4*)(bp + 1*CH*64 + j0);
      float4 b4 = *(const float4*)(bp + 2*CH*64 + j0);
      float4 k4 = *(const float4*)(bp + 3*CH*64 + j0);
      float4 r4 = *(const float4*)(bp + 4*CH*64 + j0);
      float v0 = bp[5*CH*64 + r0];
      float v1 = bp[5*CH*64 + r1];
      Sa_[0]*=d4.x; Sa_[1]*=d4.y; Sa_[2]*=d4.z; Sa_[3]*=d4.w;
      Sb_[0]*=d4.x; Sb_[1]*=d4.y; Sb_[2]*=d4.z; Sb_[3]*=d4.w;
      float sa0 = fmaf(Sa_[0],a4.x, Sa_[1]*a4.y) + fmaf(Sa_[2],a4.z, Sa_[3]*a4.w);
      float sa1 = fmaf(Sb_[0],a4.x, Sb_[1]*a4.y) + fmaf(Sb_[2],a4.z, Sb_[3]*a4.w);
      sa0 = red16(sa0);
      sa1 = red16(sa1);
      Sa_[0]=fmaf(v0,k4.x,Sa_[0]); Sa_[1]=fmaf(v0,k4.y,Sa_[1]);
      Sa_[2]=fmaf(v0,k4.z,Sa_[2]); Sa_[3]=fmaf(v0,k4.w,Sa_[3]);
      Sa_[0]=fmaf(sa0,b4.x,Sa_[0]); Sa_[1]=fmaf(sa0,b4.y,Sa_[1]);
      Sa_[2]=fmaf(sa0,b4.z,Sa_[2]); Sa_[3]=fmaf(sa0,b4.w,Sa_[3]);
      Sb_[0]=fmaf(v1,k4.x,Sb_[0]); Sb_[1]=fmaf(v1,k4.y,Sb_[1]);
      Sb_[2]=fmaf(v1,k4.z,Sb_[2]); Sb_[3]=fmaf(v1,k4.w,Sb_[3]);
      Sb_[0]=fmaf(sa1,b4.x,Sb_[0]); Sb_[1]=fmaf(sa1,b4.y,Sb_[1]);
      Sb_[2]=fmaf(sa1,b4.z,Sb_[2]); Sb_[3]=fmaf(sa1,b4.w,Sb_[3]);
      if (emit) {
        float y0 = fmaf(Sa_[0],r4.x, Sa_[1]*r4.y) + fmaf(Sa_[2],r4.z, Sa_[3]*r4.w);
        float y1 = fmaf(Sb_[0],r4.x, Sb_[1]*r4.y) + fmaf(Sb_[2],r4.z, Sb_[3]*r4.w);
        y0 = red16(y0);
        y1 = red16(y1);
        if (bj == 0) {
          size_t yo = (seqb + (size_t)t0g + ph*CH + s)*Cc + h*64;
          y[yo + r0] = y0;
          y[yo + r1] = y1;
        }
      }
    }
    asm volatile("s_barrier" ::: "memory");
  }
  #undef WSTAGE
  #undef WST1
}

// ---------------- GroupNorm(head) + r.k.r_k bonus + *g -> bf16 ---------------
__global__ __launch_bounds__(256) void gn_kernel(
    const float* __restrict__ y, const float* __restrict__ r_,
    const float* __restrict__ kfin, const float* __restrict__ vfin,
    const float* __restrict__ g_, const float* __restrict__ lnxw,
    const float* __restrict__ lnxb, const float* __restrict__ r_k,
    u16* __restrict__ Ao) {
  int row = blockIdx.x; int tid = threadIdx.x; int c = tid*4;
  size_t off = (size_t)row*Cc + c;
  float4 y4 = *(const float4*)(y+off);
  float s = y4.x+y4.y+y4.z+y4.w;
  float q = y4.x*y4.x+y4.y*y4.y+y4.z*y4.z+y4.w*y4.w;
  s = redgrp<8>(s); q = redgrp<8>(q);
  float mu = s*(1.0f/64.0f);
  float var = q*(1.0f/64.0f) - mu*mu;
  float rn = rsqrtf(var + 64e-5f);
  float4 rr = *(const float4*)(r_ + (size_t)row*BIGN + c);
  float4 kk = *(const float4*)(kfin+off);
  float4 vv = *(const float4*)(vfin+off);
  float4 gg = *(const float4*)(g_ + (size_t)row*BIGW + c);
  int h = tid >> 4; int hs = (tid & 15)*4;
  float4 rk = *(const float4*)(r_k + h*64 + hs);
  float dp = rr.x*kk.x*rk.x + rr.y*kk.y*rk.y + rr.z*kk.z*rk.z + rr.w*kk.w*rk.w;
  dp = redgrp<8>(dp);
  float4 w4 = *(const float4*)(lnxw+c);
  float4 b4 = *(const float4*)(lnxb+c);
  float o0 = (((y4.x-mu)*rn)*w4.x + b4.x + dp*vv.x) * gg.x;
  float o1 = (((y4.y-mu)*rn)*w4.y + b4.y + dp*vv.y) * gg.y;
  float o2 = (((y4.z-mu)*rn)*w4.z + b4.z + dp*vv.z) * gg.z;
  float o3 = (((y4.w-mu)*rn)*w4.w + b4.w + dp*vv.w) * gg.w;
  uint2 p = {pack_bf16(o0,o1), pack_bf16(o2,o3)};
  *(uint2*)(Ao + off) = p;
}

extern "C" void kernel_launch(void* const* d_in, const int* in_sizes, int n_in,
                              void* d_out, int out_size, void* d_ws, size_t ws_size,
                              hipStream_t stream) {
  const float* x      = (const float*)d_in[0];
  const float* vfirst = (const float*)d_in[1];
  const float* S0     = (const float*)d_in[2];
  const float* ln1w   = (const float*)d_in[3];
  const float* ln1b   = (const float*)d_in[4];
  const float* ln2w   = (const float*)d_in[5];
  const float* ln2b   = (const float*)d_in[6];
  const float* x_r    = (const float*)d_in[7];
  const float* x_w    = (const float*)d_in[8];
  const float* x_k    = (const float*)d_in[9];
  const float* x_v    = (const float*)d_in[10];
  const float* x_a    = (const float*)d_in[11];
  const float* x_g    = (const float*)d_in[12];
  const float* w0     = (const float*)d_in[13];
  const float* w1     = (const float*)d_in[14];
  const float* w2     = (const float*)d_in[15];
  const float* a0     = (const float*)d_in[16];
  const float* a1     = (const float*)d_in[17];
  const float* a2     = (const float*)d_in[18];
  const float* v0     = (const float*)d_in[19];
  const float* v1     = (const float*)d_in[20];
  const float* v2     = (const float*)d_in[21];
  const float* g1     = (const float*)d_in[22];
  const float* g2     = (const float*)d_in[23];
  const float* k_k    = (const float*)d_in[24];
  const float* k_a    = (const float*)d_in[25];
  const float* r_k    = (const float*)d_in[26];
  const float* W_r    = (const float*)d_in[27];
  const float* W_k    = (const float*)d_in[28];
  const float* W_v    = (const float*)d_in[29];
  const float* W_o    = (const float*)d_in[30];
  const float* lnxw   = (const float*)d_in[31];
  const float* lnxb   = (const float*)d_in[32];
  const float* mixk   = (const float*)d_in[33];
  const float* Wkey   = (const float*)d_in[34];
  const float* Wval   = (const float*)d_in[35];
  float* out = (float*)d_out;
  float* ws  = (float*)d_ws;
  const size_t U = (size_t)BT * Cc;
  float* u[14];
  for (int i=0;i<14;++i) u[i] = ws + i*U;

  u16* bigA   = (u16*)u[0];
  u16* BigB   = (u16*)u[1];
  float* bigOut = u[2];     // [4096][3584] f32 (58.7MB, u2..u5)
  float* dwdavg = u[6];     // [4096][4096] f32 (u6..u9)
  u16* W2blk  = (u16*)u[10];
  u16* loraAct= (u16*)u[11];
  float* Bk   = u[0];
  float* y_   = u[1];
  u16* gnb    = (u16*)u[10];
  u16* Wob    = (u16*)u[13];
  float* xo   = u[0];
  u16* Wkeyb  = (u16*)u[6];
  u16* cmb    = (u16*)u[7];
  u16* Wvalb  = (u16*)u[8];
  u16* midb   = (u16*)u[2];

  dim3 b256(256);
  packW_kernel<<<dim3(Cc,3), b256, 0, stream>>>(W_r, W_k, W_v, x_r, x_k, x_v, BigB);
  packL_kernel<<<320, b256, 0, stream>>>(w1, a1, v1, g1, x_w, x_a, x_v, x_g, BigB);
  packW2_kernel<<<BIGW, dim3(384), 0, stream>>>(w2, a2, v2, g2, W2blk);
  lnmix1_kernel<<<BT, b256, 0, stream>>>(x, ln1w, ln1b, bigA);
  // 8-phase 256^2 GEMM (pad cols 3392..3583 are garbage, never read)
  gemm8<0><<<(BT/256)*(BIGN/256), dim3(512), 0, stream>>>(bigA, BigB, bigOut, BT, BIGN, BIGK);
  actcvt_kernel<<<BT, dim3(384), 0, stream>>>(bigOut, loraAct);
  // lora2 via 8-phase (K padded to 384, nt=6 even)
  gemm8<0><<<(BT/256)*(BIGW/256), dim3(512), 0, stream>>>(loraAct, W2blk, dwdavg, BT, BIGW, LORAK);
  prep_kernel<<<BT, b256, 0, stream>>>(bigOut+1024, dwdavg, dwdavg+1024, dwdavg+2048,
      bigOut+2048, vfirst, w0, a0, v0, k_k, k_a, u[10], u[11], u[12], u[13], Bk);
  wkv_kernel<<<32*(Tt/CL), dim3(512), 0, stream>>>(u[10], u[13], Bk, u[11], bigOut, u[12], S0, y_);
  gn_kernel<<<BT, b256, 0, stream>>>(y_, bigOut, u[11], u[12], dwdavg+3072, lnxw, lnxb, r_k, gnb);
  cvtall_kernel<<<(Cc*Cc + FFNd*Cc*2 + BT*Cc)/2048, b256, 0, stream>>>(
      W_o, Wob, Wkey, Wkeyb, Wval, Wvalb, vfirst, out + (size_t)BT*Cc);
  gemm_bf16<1,64><<<(BT/128)*(Cc/64), b256, 0, stream>>>(gnb, Wob, xo, x, BT, Cc, Cc);
  lnmix2_kernel<<<BT, b256, 0, stream>>>(xo, ln2w, ln2b, mixk, cmb);
  // 8-phase for FFN-key (N=4096)
  gemm8<2><<<(BT/256)*(FFNd/256), dim3(512), 0, stream>>>(cmb, Wkeyb, midb, BT, FFNd, Cc);
  gemm_bf16<1,64><<<(BT/128)*(Cc/64), b256, 0, stream>>>(midb, Wvalb, out, xo, BT, Cc, FFNd);
}